// Round 1
// baseline (1094.299 us; speedup 1.0000x reference)
//
#include <hip/hip_runtime.h>
#include <cstdint>
#include <cstddef>

#define EPSC 0.001f

// ---------------------------------------------------------------- any-nonzero
__global__ void k_anynz(const float* __restrict__ x, int n4, int* __restrict__ flag) {
  int i = blockIdx.x * blockDim.x + threadIdx.x;
  int stride = gridDim.x * blockDim.x;
  int found = 0;
  for (; i < n4; i += stride) {
    float4 v = ((const float4*)x)[i];
    if (v.x != 0.f || v.y != 0.f || v.z != 0.f || v.w != 0.f) { found = 1; break; }
  }
  if (found) atomicOr(flag, 1);
}

// ---------------------------------------------------------------- diag init for Newton
__global__ void k_diag(const float* __restrict__ E, float* __restrict__ M0) {
  int i = threadIdx.x;  // 512 threads
  M0[(size_t)i * 512 + i] = 0.75f / E[(size_t)i * 512 + i];
}

// ---------------------------------------------------------------- X^T X block kernel
// 32x32 output tile of dot products between X columns (K = 1536 rows of X).
// mode 0: E = 0.5*(dot(p0)+dot(p1)+Y-Y^T)+EPS*I   (npass=2, passStep=1024)
// mode 1: C1 = -dot
// mode 2: D11 = -strict_lower(dot); Lam[r] = 0.5*(dot_rr + EPS)
// mode 3: plain dot (Fm, B1)
__global__ __launch_bounds__(256) void k_xtx(const float* __restrict__ X,
    const float* __restrict__ Y, float* __restrict__ out, float* __restrict__ lam,
    int aOff, int bOff, int npass, int passStep, int mode)
{
  __shared__ float As[32][36];
  __shared__ float Bs[32][36];
  const int tid = threadIdx.x;
  const int tx = tid & 15, ty = tid >> 4;
  const int i0 = blockIdx.y * 32, j0 = blockIdx.x * 32;
  float acc00 = 0.f, acc01 = 0.f, acc10 = 0.f, acc11 = 0.f;

  const int i2 = tid & 31;   // col within tile
  const int kr = tid >> 5;   // 0..7

  for (int p = 0; p < npass; ++p) {
    const int ao = aOff + p * passStep + i0;
    const int bo = bOff + p * passStep + j0;
    for (int k0 = 0; k0 < 1536; k0 += 32) {
      float ra[4], rb[4];
#pragma unroll
      for (int e = 0; e < 4; ++e) {
        int k = kr + 8 * e;
        ra[e] = X[(size_t)(k0 + k) * 1536 + ao + i2];
        rb[e] = X[(size_t)(k0 + k) * 1536 + bo + i2];
      }
      __syncthreads();
#pragma unroll
      for (int e = 0; e < 4; ++e) {
        int k = kr + 8 * e;
        As[k][i2] = ra[e];
        Bs[k][i2] = rb[e];
      }
      __syncthreads();
#pragma unroll
      for (int kk = 0; kk < 32; ++kk) {
        float2 a2 = *(const float2*)&As[kk][2 * ty];
        float2 b2 = *(const float2*)&Bs[kk][2 * tx];
        acc00 = fmaf(a2.x, b2.x, acc00);
        acc01 = fmaf(a2.x, b2.y, acc01);
        acc10 = fmaf(a2.y, b2.x, acc10);
        acc11 = fmaf(a2.y, b2.y, acc11);
      }
    }
  }

  float vals[2][2] = {{acc00, acc01}, {acc10, acc11}};
  int r = i0 + 2 * ty, c = j0 + 2 * tx;
#pragma unroll
  for (int i = 0; i < 2; ++i)
#pragma unroll
    for (int j = 0; j < 2; ++j) {
      int rr = r + i, cc = c + j;
      float d = vals[i][j];
      float o;
      if (mode == 0) {
        o = 0.5f * (d + Y[(size_t)rr * 512 + cc] - Y[(size_t)cc * 512 + rr]);
        if (rr == cc) o += EPSC;
      } else if (mode == 1) {
        o = -d;
      } else if (mode == 2) {
        o = (cc < rr) ? -d : 0.f;
        if (rr == cc && lam) lam[rr] = 0.5f * (d + EPSC);
      } else {
        o = d;
      }
      out[(size_t)rr * 512 + cc] = o;
    }
}

// ---------------------------------------------------------------- small NN GEMM
// C[M,N] = A[M,512] @ B[512,N]   (lda = 512, ldb = ldc = N)
// EPI 0: C = acc ; 1: C = 2*Aep - acc ; 2: C = acc + Aep
template <int EPI>
__global__ __launch_bounds__(256) void k_nn(const float* __restrict__ A,
    const float* __restrict__ B, const float* __restrict__ Aep,
    float* __restrict__ C, int N)
{
  __shared__ float As[32][36];
  __shared__ float Bs[32][36];
  const int tid = threadIdx.x;
  const int tx = tid & 15, ty = tid >> 4;
  const int m0 = blockIdx.y * 32, n0 = blockIdx.x * 32;
  const int lr = tid >> 3;          // 0..31
  const int lkq = (tid & 7) * 4;    // 0..28
  float acc00 = 0.f, acc01 = 0.f, acc10 = 0.f, acc11 = 0.f;

  for (int k0 = 0; k0 < 512; k0 += 32) {
    float4 av = *(const float4*)(A + (size_t)(m0 + lr) * 512 + k0 + lkq);
    float4 bv = *(const float4*)(B + (size_t)(k0 + lr) * N + n0 + lkq);
    __syncthreads();
    As[lkq + 0][lr] = av.x; As[lkq + 1][lr] = av.y;
    As[lkq + 2][lr] = av.z; As[lkq + 3][lr] = av.w;
    *(float4*)&Bs[lr][lkq] = bv;
    __syncthreads();
#pragma unroll
    for (int kk = 0; kk < 32; ++kk) {
      float2 a2 = *(const float2*)&As[kk][2 * ty];
      float2 b2 = *(const float2*)&Bs[kk][2 * tx];
      acc00 = fmaf(a2.x, b2.x, acc00);
      acc01 = fmaf(a2.x, b2.y, acc01);
      acc10 = fmaf(a2.y, b2.x, acc10);
      acc11 = fmaf(a2.y, b2.y, acc11);
    }
  }

  float vals[2][2] = {{acc00, acc01}, {acc10, acc11}};
  int r = m0 + 2 * ty, c = n0 + 2 * tx;
#pragma unroll
  for (int i = 0; i < 2; ++i)
#pragma unroll
    for (int j = 0; j < 2; ++j) {
      size_t idx = (size_t)(r + i) * N + (c + j);
      float d = vals[i][j];
      if (EPI == 0) C[idx] = d;
      else if (EPI == 1) C[idx] = 2.f * Aep[idx] - d;
      else C[idx] = d + Aep[idx];
    }
}

// ---------------------------------------------------------------- big NT GEMM (batch)
// C[m,n] = sum_ops sum_k A[m,k]*B[n,k]; ops with (condMask bit && *flag==0) skipped.
template <int NOPS>
__global__ __launch_bounds__(256) void k_nt(
    const float* A0, const float* B0, int K0,
    const float* A1, const float* B1, int K1,
    const float* A2, const float* B2, int K2,
    int condMask, const int* __restrict__ flag,
    float* __restrict__ C, int ldc)
{
  __shared__ float As[16][68];
  __shared__ float Bs[16][68];
  const int tid = threadIdx.x;
  const int tx = tid & 15, ty = tid >> 4;
  const int m0 = blockIdx.x * 64, n0 = blockIdx.y * 64;
  const int lr = tid >> 2;        // 0..63
  const int lk = (tid & 3) * 4;   // 0,4,8,12
  float acc[4][4];
#pragma unroll
  for (int i = 0; i < 4; ++i)
#pragma unroll
    for (int j = 0; j < 4; ++j) acc[i][j] = 0.f;

#pragma unroll
  for (int op = 0; op < NOPS; ++op) {
    const float* A = (op == 0) ? A0 : (op == 1) ? A1 : A2;
    const float* B = (op == 0) ? B0 : (op == 1) ? B1 : B2;
    const int K = (op == 0) ? K0 : (op == 1) ? K1 : K2;
    if ((condMask >> op) & 1) {
      if (*flag == 0) continue;
    }
    for (int k0 = 0; k0 < K; k0 += 16) {
      float4 av = *(const float4*)(A + (size_t)(m0 + lr) * K + k0 + lk);
      float4 bv = *(const float4*)(B + (size_t)(n0 + lr) * K + k0 + lk);
      __syncthreads();
      As[lk + 0][lr] = av.x; As[lk + 1][lr] = av.y;
      As[lk + 2][lr] = av.z; As[lk + 3][lr] = av.w;
      Bs[lk + 0][lr] = bv.x; Bs[lk + 1][lr] = bv.y;
      Bs[lk + 2][lr] = bv.z; Bs[lk + 3][lr] = bv.w;
      __syncthreads();
#pragma unroll
      for (int kk = 0; kk < 16; ++kk) {
        float4 a4 = *(const float4*)&As[kk][4 * ty];
        float4 b4 = *(const float4*)&Bs[kk][4 * tx];
        float ar[4] = {a4.x, a4.y, a4.z, a4.w};
        float br[4] = {b4.x, b4.y, b4.z, b4.w};
#pragma unroll
        for (int i = 0; i < 4; ++i)
#pragma unroll
          for (int j = 0; j < 4; ++j)
            acc[i][j] = fmaf(ar[i], br[j], acc[i][j]);
      }
    }
  }

#pragma unroll
  for (int i = 0; i < 4; ++i) {
    float4 v = make_float4(acc[i][0], acc[i][1], acc[i][2], acc[i][3]);
    *(float4*)(C + (size_t)(m0 + 4 * ty + i) * ldc + n0 + 4 * tx) = v;
  }
}

// ---------------------------------------------------------------- blocked tanh scan
// w[:,i] = tanh((a[:,i] + sum_{j<i} D11[i,j]*w[:,j]) / Lam[i]); 64 batch rows / WG.
__global__ __launch_bounds__(512) void k_scan(const float* __restrict__ a,
    const float* __restrict__ D11, const float* __restrict__ Lam,
    float* __restrict__ w)
{
  __shared__ float wt[512][68];    // [col j][row r]
  __shared__ float sblk[32][68];
  __shared__ float lam_s[512];
  const int tid = threadIdx.x;
  const int r = tid & 63;
  const int g = tid >> 6;          // wave id 0..7
  const int row0 = blockIdx.x * 64;
  if (tid < 512) lam_s[tid] = Lam[tid];
  __syncthreads();

  for (int t = 0; t < 16; ++t) {
    // stage a-block (coalesced) into sblk[col_local][row]
    {
      int row = tid >> 3;
      int cq = (tid & 7) * 4;
      float4 v = *(const float4*)(a + (size_t)(row0 + row) * 512 + 32 * t + cq);
      sblk[cq + 0][row] = v.x; sblk[cq + 1][row] = v.y;
      sblk[cq + 2][row] = v.z; sblk[cq + 3][row] = v.w;
    }
    __syncthreads();
    // phase A: history GEMM, j < 32t
    if (t > 0) {
      float accv[4] = {0.f, 0.f, 0.f, 0.f};
      const float* d0 = D11 + (size_t)(32 * t + g + 0) * 512;
      const float* d1 = D11 + (size_t)(32 * t + g + 8) * 512;
      const float* d2 = D11 + (size_t)(32 * t + g + 16) * 512;
      const float* d3 = D11 + (size_t)(32 * t + g + 24) * 512;
      const int jmax = 32 * t;
#pragma unroll 4
      for (int j = 0; j < jmax; ++j) {
        float wv = wt[j][r];
        accv[0] = fmaf(d0[j], wv, accv[0]);
        accv[1] = fmaf(d1[j], wv, accv[1]);
        accv[2] = fmaf(d2[j], wv, accv[2]);
        accv[3] = fmaf(d3[j], wv, accv[3]);
      }
      sblk[g + 0][r] += accv[0];
      sblk[g + 8][r] += accv[1];
      sblk[g + 16][r] += accv[2];
      sblk[g + 24][r] += accv[3];
    }
    __syncthreads();
    // phase B: in-block triangular sweep, wave 0, w block in registers
    if (tid < 64) {
      float wloc[32];
      const int ibase = 32 * t;
#pragma unroll
      for (int il = 0; il < 32; ++il) {
        float s = sblk[il][r];
        const float* drow = D11 + (size_t)(ibase + il) * 512 + ibase;
#pragma unroll
        for (int j = 0; j < il; ++j)
          s = fmaf(drow[j], wloc[j], s);
        wloc[il] = tanhf(s / lam_s[ibase + il]);
      }
#pragma unroll
      for (int il = 0; il < 32; ++il)
        wt[ibase + il][r] = wloc[il];
    }
    __syncthreads();
  }

  // write out (coalesced in global)
  for (int idx = tid; idx < 64 * 512; idx += 512) {
    int row = idx >> 9;
    int col = idx & 511;
    w[(size_t)(row0 + row) * 512 + col] = wt[col][row];
  }
}

// ---------------------------------------------------------------- launcher
extern "C" void kernel_launch(void* const* d_in, const int* in_sizes, int n_in,
                              void* d_out, int out_size, void* d_ws, size_t ws_size,
                              hipStream_t stream)
{
  const float* u   = (const float*)d_in[0];   // 8192 x 256
  const float* x0  = (const float*)d_in[1];   // 8192 x 512
  const float* X   = (const float*)d_in[2];   // 1536 x 1536
  const float* Y   = (const float*)d_in[3];   // 512 x 512
  const float* B2  = (const float*)d_in[4];   // 512 x 256
  const float* C2  = (const float*)d_in[5];   // 256 x 512
  const float* D21 = (const float*)d_in[6];   // 256 x 512
  const float* D22 = (const float*)d_in[7];   // 256 x 256
  const float* D12 = (const float*)d_in[8];   // 512 x 256
  float* out = (float*)d_out;
  float* ws = (float*)d_ws;

  float* E    = ws + 0;
  float* M0   = ws + 262144;
  float* M1   = ws + 524288;
  float* T    = ws + 786432;
  float* C1   = ws + 1048576;
  float* D11  = ws + 1310720;
  float* Fm   = ws + 1572864;
  float* B1   = ws + 1835008;
  float* Q    = ws + 2097152;   // 256x512
  float* P1   = ws + 2228224;   // 256x512
  float* P2   = ws + 2359296;   // 256x512
  float* P3   = ws + 2490368;   // 256x256
  float* Lam  = ws + 2555904;   // 512
  int*   flag = (int*)(ws + 2556416);
  float* abuf = ws + 2556928;   // 8192x512
  float* wbuf = ws + 6751232;   // 8192x512

  hipMemsetAsync(flag, 0, 4, stream);
  hipMemsetAsync(M0, 0, 512 * 512 * 4, stream);

  k_anynz<<<256, 256, 0, stream>>>(x0, 8192 * 512 / 4, flag);

  dim3 g16(16, 16);
  k_xtx<<<g16, 256, 0, stream>>>(X, Y, E,   nullptr, 0,    0,   2, 1024, 0);  // E
  k_xtx<<<g16, 256, 0, stream>>>(X, Y, C1,  nullptr, 512,  0,   1, 0,    1);  // C1 = -H21
  k_xtx<<<g16, 256, 0, stream>>>(X, Y, D11, Lam,     512,  512, 1, 0,    2);  // D11, Lam
  k_xtx<<<g16, 256, 0, stream>>>(X, Y, Fm,  nullptr, 1024, 0,   1, 0,    3);  // Fm = H31
  k_xtx<<<g16, 256, 0, stream>>>(X, Y, B1,  nullptr, 1024, 512, 1, 0,    3);  // B1 = H32

  k_diag<<<1, 512, 0, stream>>>(E, M0);

  // Newton-Schulz: M -> E^{-1}, 7 iterations
  float* src = M0; float* dst = M1;
  for (int it = 0; it < 7; ++it) {
    k_nn<0><<<dim3(16, 16), 256, 0, stream>>>(E, src, nullptr, T, 512);
    k_nn<1><<<dim3(16, 16), 256, 0, stream>>>(src, T, src, dst, 512);
    float* tmp = src; src = dst; dst = tmp;
  }
  float* M = src;

  // folds: Q = C2*M ; P1 = Q*Fm ; P2 = Q*B1 + D21 ; P3 = Q*B2 + D22
  k_nn<0><<<dim3(16, 8), 256, 0, stream>>>(C2, M,  nullptr, Q,  512);
  k_nn<0><<<dim3(16, 8), 256, 0, stream>>>(Q,  Fm, nullptr, P1, 512);
  k_nn<2><<<dim3(16, 8), 256, 0, stream>>>(Q,  B1, D21,     P2, 512);
  k_nn<2><<<dim3(8, 8),  256, 0, stream>>>(Q,  B2, D22,     P3, 256);

  // a = u @ D12^T (+ x0 @ C1^T if x0 != 0)
  k_nt<2><<<dim3(128, 8), 256, 0, stream>>>(u, D12, 256, x0, C1, 512,
                                            nullptr, nullptr, 0,
                                            0b10, flag, abuf, 512);
  // w scan
  k_scan<<<128, 512, 0, stream>>>(abuf, D11, Lam, wbuf);

  // y = w @ P2^T + u @ P3^T (+ x0 @ P1^T if x0 != 0)
  k_nt<3><<<dim3(128, 4), 256, 0, stream>>>(wbuf, P2, 512, u, P3, 256, x0, P1, 512,
                                            0b100, flag, out, 256);
}

// Round 2
// 705.260 us; speedup vs baseline: 1.5516x; 1.5516x over previous
//
#include <hip/hip_runtime.h>
#include <cstdint>
#include <cstddef>

#define EPSC 0.001f

// ---------------------------------------------------------------- any-nonzero
__global__ void k_anynz(const float* __restrict__ x, int n4, int* __restrict__ flag) {
  int i = blockIdx.x * blockDim.x + threadIdx.x;
  int stride = gridDim.x * blockDim.x;
  int found = 0;
  for (; i < n4; i += stride) {
    float4 v = ((const float4*)x)[i];
    if (v.x != 0.f || v.y != 0.f || v.z != 0.f || v.w != 0.f) { found = 1; break; }
  }
  if (found) atomicOr(flag, 1);
}

// ---------------------------------------------------------------- M0 init (zeros + 0.75/diag)
__global__ void k_initM0(const float* __restrict__ E, float* __restrict__ M0) {
  int g = blockIdx.x * 256 + threadIdx.x;     // 0..65535, 1 float4 each
  int row = g >> 7;
  int c4 = (g & 127) << 2;
  float4 v = make_float4(0.f, 0.f, 0.f, 0.f);
  if (row >= c4 && row < c4 + 4) ((float*)&v)[row - c4] = 0.75f / E[(size_t)row * 513];
  *(float4*)(M0 + (size_t)row * 512 + c4) = v;
}

// ---------------------------------------------------------------- fused X^T X blocks (5 outputs)
// z=0: E = 0.5*(H11+H33+Y-Y^T)+eps*I   z=1: C1=-H21   z=2: D11=-tril(H22,-1) (+D11T,+Lam)
// z=3: Fm=H31   z=4: B1=H32
__global__ __launch_bounds__(256) void k_xtx5(const float* __restrict__ X,
    const float* __restrict__ Y, float* __restrict__ E, float* __restrict__ C1,
    float* __restrict__ D11, float* __restrict__ D11T, float* __restrict__ Fm,
    float* __restrict__ B1, float* __restrict__ Lam)
{
  __shared__ float As[32][36];
  __shared__ float Bs[32][36];
  const int tid = threadIdx.x;
  const int tx = tid & 15, ty = tid >> 4;
  const int i0 = blockIdx.y * 32, j0 = blockIdx.x * 32;
  const int z = blockIdx.z;
  int aOff, bOff, npass, mode;
  float* out;
  switch (z) {
    case 0:  aOff = 0;    bOff = 0;   npass = 2; mode = 0; out = E;   break;
    case 1:  aOff = 512;  bOff = 0;   npass = 1; mode = 1; out = C1;  break;
    case 2:  aOff = 512;  bOff = 512; npass = 1; mode = 2; out = D11; break;
    case 3:  aOff = 1024; bOff = 0;   npass = 1; mode = 3; out = Fm;  break;
    default: aOff = 1024; bOff = 512; npass = 1; mode = 3; out = B1;  break;
  }
  const int i2 = tid & 31, kr = tid >> 5;
  const int NIT = npass * 48;
  float ra[4], rb[4], ra2[4], rb2[4];
  auto ld = [&](int n, float* pa, float* pb) {
    int p = n / 48;
    int k0 = (n - p * 48) * 32;
    int ao = aOff + p * 1024 + i0 + i2;
    int bo = bOff + p * 1024 + j0 + i2;
#pragma unroll
    for (int e = 0; e < 4; ++e) {
      int k = k0 + kr + 8 * e;
      pa[e] = X[(size_t)k * 1536 + ao];
      pb[e] = X[(size_t)k * 1536 + bo];
    }
  };
  ld(0, ra, rb);
  float acc00 = 0.f, acc01 = 0.f, acc10 = 0.f, acc11 = 0.f;
  for (int n = 0; n < NIT; ++n) {
    __syncthreads();
#pragma unroll
    for (int e = 0; e < 4; ++e) {
      As[kr + 8 * e][i2] = ra[e];
      Bs[kr + 8 * e][i2] = rb[e];
    }
    __syncthreads();
    if (n + 1 < NIT) ld(n + 1, ra2, rb2);
#pragma unroll
    for (int kk = 0; kk < 32; ++kk) {
      float2 a2 = *(const float2*)&As[kk][2 * ty];
      float2 b2 = *(const float2*)&Bs[kk][2 * tx];
      acc00 = fmaf(a2.x, b2.x, acc00);
      acc01 = fmaf(a2.x, b2.y, acc01);
      acc10 = fmaf(a2.y, b2.x, acc10);
      acc11 = fmaf(a2.y, b2.y, acc11);
    }
#pragma unroll
    for (int e = 0; e < 4; ++e) { ra[e] = ra2[e]; rb[e] = rb2[e]; }
  }
  float vals[2][2] = {{acc00, acc01}, {acc10, acc11}};
  int r = i0 + 2 * ty, c = j0 + 2 * tx;
#pragma unroll
  for (int i = 0; i < 2; ++i)
#pragma unroll
    for (int j = 0; j < 2; ++j) {
      int rr = r + i, cc = c + j;
      float d = vals[i][j];
      float o;
      if (mode == 0) {
        o = 0.5f * (d + Y[(size_t)rr * 512 + cc] - Y[(size_t)cc * 512 + rr]);
        if (rr == cc) o += EPSC;
      } else if (mode == 1) {
        o = -d;
      } else if (mode == 2) {
        o = (cc < rr) ? -d : 0.f;
        if (rr == cc) Lam[rr] = 0.5f * (d + EPSC);
      } else {
        o = d;
      }
      out[(size_t)rr * 512 + cc] = o;
      if (mode == 2) D11T[(size_t)cc * 512 + rr] = o;
    }
}

// ---------------------------------------------------------------- small NN GEMM (prefetched)
// C[M,N] = A[M,512] @ B[512,N];  EPI 0: C=acc ; 1: C=2*Aep-acc ; 2: C=acc+Aep
template <int EPI>
__global__ __launch_bounds__(256) void k_nn(const float* __restrict__ A,
    const float* __restrict__ B, const float* __restrict__ Aep,
    float* __restrict__ C, int N)
{
  __shared__ float As[32][36];
  __shared__ float Bs[32][36];
  const int tid = threadIdx.x;
  const int tx = tid & 15, ty = tid >> 4;
  const int m0 = blockIdx.y * 32, n0 = blockIdx.x * 32;
  const int lr = tid >> 3;
  const int lkq = (tid & 7) * 4;
  float4 av = *(const float4*)(A + (size_t)(m0 + lr) * 512 + lkq);
  float4 bv = *(const float4*)(B + (size_t)lr * N + n0 + lkq);
  float acc00 = 0.f, acc01 = 0.f, acc10 = 0.f, acc11 = 0.f;
  for (int k0 = 0; k0 < 512; k0 += 32) {
    __syncthreads();
    As[lkq + 0][lr] = av.x; As[lkq + 1][lr] = av.y;
    As[lkq + 2][lr] = av.z; As[lkq + 3][lr] = av.w;
    *(float4*)&Bs[lr][lkq] = bv;
    __syncthreads();
    if (k0 + 32 < 512) {
      av = *(const float4*)(A + (size_t)(m0 + lr) * 512 + k0 + 32 + lkq);
      bv = *(const float4*)(B + (size_t)(k0 + 32 + lr) * N + n0 + lkq);
    }
#pragma unroll
    for (int kk = 0; kk < 32; ++kk) {
      float2 a2 = *(const float2*)&As[kk][2 * ty];
      float2 b2 = *(const float2*)&Bs[kk][2 * tx];
      acc00 = fmaf(a2.x, b2.x, acc00);
      acc01 = fmaf(a2.x, b2.y, acc01);
      acc10 = fmaf(a2.y, b2.x, acc10);
      acc11 = fmaf(a2.y, b2.y, acc11);
    }
  }
  float vals[2][2] = {{acc00, acc01}, {acc10, acc11}};
  int r = m0 + 2 * ty, c = n0 + 2 * tx;
#pragma unroll
  for (int i = 0; i < 2; ++i)
#pragma unroll
    for (int j = 0; j < 2; ++j) {
      size_t idx = (size_t)(r + i) * N + (c + j);
      float d = vals[i][j];
      if (EPI == 0) C[idx] = d;
      else if (EPI == 1) C[idx] = 2.f * Aep[idx] - d;
      else C[idx] = d + Aep[idx];
    }
}

// ---------------------------------------------------------------- fused fold GEMMs (3 outputs)
// z=0: P1 = Q*Fm ; z=1: P2 = Q*B1 + D21 ; z=2: P3 = Q*B2 + D22 (N=256)
__global__ __launch_bounds__(256) void k_fold(const float* __restrict__ Q,
    const float* __restrict__ Fm, const float* __restrict__ B1,
    const float* __restrict__ B2, const float* __restrict__ D21,
    const float* __restrict__ D22, float* __restrict__ P1,
    float* __restrict__ P2, float* __restrict__ P3)
{
  const int z = blockIdx.z;
  const float* B; const float* Aep; float* C; int N;
  if (z == 0)      { B = Fm; Aep = nullptr; C = P1; N = 512; }
  else if (z == 1) { B = B1; Aep = D21;     C = P2; N = 512; }
  else             { B = B2; Aep = D22;     C = P3; N = 256; }
  const int n0 = blockIdx.x * 32;
  if (n0 >= N) return;
  __shared__ float As[32][36];
  __shared__ float Bs[32][36];
  const int tid = threadIdx.x;
  const int tx = tid & 15, ty = tid >> 4;
  const int m0 = blockIdx.y * 32;
  const int lr = tid >> 3;
  const int lkq = (tid & 7) * 4;
  float4 av = *(const float4*)(Q + (size_t)(m0 + lr) * 512 + lkq);
  float4 bv = *(const float4*)(B + (size_t)lr * N + n0 + lkq);
  float acc00 = 0.f, acc01 = 0.f, acc10 = 0.f, acc11 = 0.f;
  for (int k0 = 0; k0 < 512; k0 += 32) {
    __syncthreads();
    As[lkq + 0][lr] = av.x; As[lkq + 1][lr] = av.y;
    As[lkq + 2][lr] = av.z; As[lkq + 3][lr] = av.w;
    *(float4*)&Bs[lr][lkq] = bv;
    __syncthreads();
    if (k0 + 32 < 512) {
      av = *(const float4*)(Q + (size_t)(m0 + lr) * 512 + k0 + 32 + lkq);
      bv = *(const float4*)(B + (size_t)(k0 + 32 + lr) * N + n0 + lkq);
    }
#pragma unroll
    for (int kk = 0; kk < 32; ++kk) {
      float2 a2 = *(const float2*)&As[kk][2 * ty];
      float2 b2 = *(const float2*)&Bs[kk][2 * tx];
      acc00 = fmaf(a2.x, b2.x, acc00);
      acc01 = fmaf(a2.x, b2.y, acc01);
      acc10 = fmaf(a2.y, b2.x, acc10);
      acc11 = fmaf(a2.y, b2.y, acc11);
    }
  }
  float vals[2][2] = {{acc00, acc01}, {acc10, acc11}};
  int r = m0 + 2 * ty, c = n0 + 2 * tx;
#pragma unroll
  for (int i = 0; i < 2; ++i)
#pragma unroll
    for (int j = 0; j < 2; ++j) {
      size_t idx = (size_t)(r + i) * N + (c + j);
      float d = vals[i][j];
      if (Aep) C[idx] = d + Aep[idx];
      else C[idx] = d;
    }
}

// ---------------------------------------------------------------- big NT GEMM (batch, prefetched)
template <int NOPS>
__global__ __launch_bounds__(256) void k_nt(
    const float* A0, const float* B0, int K0,
    const float* A1, const float* B1, int K1,
    const float* A2, const float* B2, int K2,
    int condMask, const int* __restrict__ flag,
    float* __restrict__ C, int ldc)
{
  __shared__ float As[16][68];
  __shared__ float Bs[16][68];
  const int tid = threadIdx.x;
  const int tx = tid & 15, ty = tid >> 4;
  const int m0 = blockIdx.x * 64, n0 = blockIdx.y * 64;
  const int lr = tid >> 2;
  const int lk = (tid & 3) * 4;
  float acc[4][4];
#pragma unroll
  for (int i = 0; i < 4; ++i)
#pragma unroll
    for (int j = 0; j < 4; ++j) acc[i][j] = 0.f;

#pragma unroll
  for (int op = 0; op < NOPS; ++op) {
    const float* A = (op == 0) ? A0 : (op == 1) ? A1 : A2;
    const float* B = (op == 0) ? B0 : (op == 1) ? B1 : B2;
    const int K = (op == 0) ? K0 : (op == 1) ? K1 : K2;
    if ((condMask >> op) & 1) {
      if (*flag == 0) continue;
    }
    float4 av = *(const float4*)(A + (size_t)(m0 + lr) * K + lk);
    float4 bv = *(const float4*)(B + (size_t)(n0 + lr) * K + lk);
    for (int k0 = 0; k0 < K; k0 += 16) {
      __syncthreads();
      As[lk + 0][lr] = av.x; As[lk + 1][lr] = av.y;
      As[lk + 2][lr] = av.z; As[lk + 3][lr] = av.w;
      Bs[lk + 0][lr] = bv.x; Bs[lk + 1][lr] = bv.y;
      Bs[lk + 2][lr] = bv.z; Bs[lk + 3][lr] = bv.w;
      __syncthreads();
      if (k0 + 16 < K) {
        av = *(const float4*)(A + (size_t)(m0 + lr) * K + k0 + 16 + lk);
        bv = *(const float4*)(B + (size_t)(n0 + lr) * K + k0 + 16 + lk);
      }
#pragma unroll
      for (int kk = 0; kk < 16; ++kk) {
        float4 a4 = *(const float4*)&As[kk][4 * ty];
        float4 b4 = *(const float4*)&Bs[kk][4 * tx];
        float ar[4] = {a4.x, a4.y, a4.z, a4.w};
        float br[4] = {b4.x, b4.y, b4.z, b4.w};
#pragma unroll
        for (int i = 0; i < 4; ++i)
#pragma unroll
          for (int j = 0; j < 4; ++j)
            acc[i][j] = fmaf(ar[i], br[j], acc[i][j]);
      }
    }
  }

#pragma unroll
  for (int i = 0; i < 4; ++i) {
    float4 v = make_float4(acc[i][0], acc[i][1], acc[i][2], acc[i][3]);
    *(float4*)(C + (size_t)(m0 + 4 * ty + i) * ldc + n0 + 4 * tx) = v;
  }
}

// ---------------------------------------------------------------- blocked tanh scan (v2)
// 512 blocks x 16 batch rows; 512 threads. All serial-chain operands in LDS/regs.
// thread decomposition: r = tid&15 (batch row), ilq = (tid>>4)&7 (il quad), ks = tid>>7 (K quarter)
__global__ __launch_bounds__(512, 4) void k_scan(const float* __restrict__ a,
    const float* __restrict__ D11, const float* __restrict__ D11T,
    const float* __restrict__ Lam, float* __restrict__ w)
{
  __shared__ float wt[512][17];      // [col][row]
  __shared__ float sblk[32][17];     // S(t) [il][row]
  __shared__ float sred[4][32][17];  // K-quarter partials
  __shared__ float dblk[2][32][36];  // D11 diagonal blocks (cur/next)
  __shared__ float rlam[512];
  const int tid = threadIdx.x;
  const int r = tid & 15;
  const int ilq = (tid >> 4) & 7;
  const int il0 = ilq * 4;
  const int ks = tid >> 7;
  const int row0 = blockIdx.x * 16;

  rlam[tid] = 1.0f / Lam[tid];
  if (tid < 256) {
    int il = tid >> 3, j4 = (tid & 7) * 4;
    *(float4*)&dblk[0][il][j4] = *(const float4*)(D11 + (size_t)il * 512 + j4);
  }
  if (ks == 0) {
    float4 av = *(const float4*)(a + (size_t)(row0 + r) * 512 + il0);
    sblk[il0 + 0][r] = av.x; sblk[il0 + 1][r] = av.y;
    sblk[il0 + 2][r] = av.z; sblk[il0 + 3][r] = av.w;
  }
  __syncthreads();

  int cur = 0;
  for (int t = 0; t < 16; ++t) {
    // ---- phase B: 16 lanes, in-register triangle; only LDS broadcasts in the chain
    if (tid < 16) {
      float wloc[32];
      const int base = 32 * t;
#pragma unroll
      for (int il = 0; il < 32; ++il) {
        float s = sblk[il][tid];
#pragma unroll
        for (int j = 0; j < il; ++j)
          s = fmaf(dblk[cur][il][j], wloc[j], s);
        float x2 = 2.f * s * rlam[base + il];
        float e = __expf(x2);                 // overflow-safe: inf -> tanh=1, 0 -> -1
        wloc[il] = 1.f - 2.f / (e + 1.f);
      }
#pragma unroll
      for (int il = 0; il < 32; ++il)
        wt[base + il][tid] = wloc[il];
    }
    __syncthreads();
    if (t == 15) break;

    // ---- phase A: S(t+1)[il][r] = a(t+1) + sum_{j<32(t+1)} D11T[j][32(t+1)+il] * wt[j][r]
    const int jend = 32 * (t + 1);
    const int q = jend >> 2;
    float4 sacc = make_float4(0.f, 0.f, 0.f, 0.f);
    const int jlo = ks * q, jhi = jlo + q;
#pragma unroll 4
    for (int j = jlo; j < jhi; ++j) {
      float wv = wt[j][r];
      float4 d4 = *(const float4*)(D11T + (size_t)j * 512 + jend + il0);
      sacc.x = fmaf(d4.x, wv, sacc.x);
      sacc.y = fmaf(d4.y, wv, sacc.y);
      sacc.z = fmaf(d4.z, wv, sacc.z);
      sacc.w = fmaf(d4.w, wv, sacc.w);
    }
    if (ks == 0) {
      float4 av = *(const float4*)(a + (size_t)(row0 + r) * 512 + jend + il0);
      sacc.x += av.x; sacc.y += av.y; sacc.z += av.z; sacc.w += av.w;
    }
    sred[ks][il0 + 0][r] = sacc.x;
    sred[ks][il0 + 1][r] = sacc.y;
    sred[ks][il0 + 2][r] = sacc.z;
    sred[ks][il0 + 3][r] = sacc.w;
    // stage next diagonal block
    if (tid < 256) {
      int il = tid >> 3, j4 = (tid & 7) * 4;
      *(float4*)&dblk[cur ^ 1][il][j4] =
          *(const float4*)(D11 + (size_t)(jend + il) * 512 + jend + j4);
    }
    __syncthreads();
    {
      int il = tid >> 4;
      int rr = tid & 15;
      sblk[il][rr] = sred[0][il][rr] + sred[1][il][rr] + sred[2][il][rr] + sred[3][il][rr];
    }
    cur ^= 1;
    __syncthreads();
  }

  // write out (coalesced)
  for (int idx = tid; idx < 16 * 512; idx += 512) {
    int row = idx >> 9;
    int col = idx & 511;
    w[(size_t)(row0 + row) * 512 + col] = wt[col][row];
  }
}

// ---------------------------------------------------------------- launcher
extern "C" void kernel_launch(void* const* d_in, const int* in_sizes, int n_in,
                              void* d_out, int out_size, void* d_ws, size_t ws_size,
                              hipStream_t stream)
{
  const float* u   = (const float*)d_in[0];   // 8192 x 256
  const float* x0  = (const float*)d_in[1];   // 8192 x 512
  const float* X   = (const float*)d_in[2];   // 1536 x 1536
  const float* Y   = (const float*)d_in[3];   // 512 x 512
  const float* B2  = (const float*)d_in[4];   // 512 x 256
  const float* C2  = (const float*)d_in[5];   // 256 x 512
  const float* D21 = (const float*)d_in[6];   // 256 x 512
  const float* D22 = (const float*)d_in[7];   // 256 x 256
  const float* D12 = (const float*)d_in[8];   // 512 x 256
  float* out = (float*)d_out;
  float* ws = (float*)d_ws;

  float* E    = ws + 0;
  float* M0   = ws + 262144;
  float* M1   = ws + 524288;
  float* T    = ws + 786432;
  float* C1   = ws + 1048576;
  float* D11  = ws + 1310720;
  float* Fm   = ws + 1572864;
  float* B1   = ws + 1835008;
  float* Q    = ws + 2097152;   // 256x512
  float* P1   = ws + 2228224;   // 256x512
  float* P2   = ws + 2359296;   // 256x512
  float* P3   = ws + 2490368;   // 256x256
  float* Lam  = ws + 2555904;   // 512
  int*   flag = (int*)(ws + 2556416);
  float* abuf = ws + 2556928;   // 8192x512
  float* wbuf = ws + 6751232;   // 8192x512
  float* D11T = ws + 10945536;  // 512x512

  hipMemsetAsync(flag, 0, 4, stream);
  k_anynz<<<256, 256, 0, stream>>>(x0, 8192 * 512 / 4, flag);

  // all 6 needed blocks of H = X^T X in one launch (5 z-slices; z=0 has 2 passes)
  k_xtx5<<<dim3(16, 16, 5), 256, 0, stream>>>(X, Y, E, C1, D11, D11T, Fm, B1, Lam);

  k_initM0<<<256, 256, 0, stream>>>(E, M0);

  // Newton-Schulz: M -> E^{-1}, 6 iterations (rho^(2^6) ~ 4e-9)
  float* src = M0; float* dst = M1;
  for (int it = 0; it < 6; ++it) {
    k_nn<0><<<dim3(16, 16), 256, 0, stream>>>(E, src, nullptr, T, 512);
    k_nn<1><<<dim3(16, 16), 256, 0, stream>>>(src, T, src, dst, 512);
    float* tmp = src; src = dst; dst = tmp;
  }

  // folds: Q = C2*M ; then P1 = Q*Fm ; P2 = Q*B1 + D21 ; P3 = Q*B2 + D22
  k_nn<0><<<dim3(16, 8), 256, 0, stream>>>(C2, src, nullptr, Q, 512);
  k_fold<<<dim3(16, 8, 3), 256, 0, stream>>>(Q, Fm, B1, B2, D21, D22, P1, P2, P3);

  // a = u @ D12^T (+ x0 @ C1^T if x0 != 0)
  k_nt<2><<<dim3(128, 8), 256, 0, stream>>>(u, D12, 256, x0, C1, 512,
                                            nullptr, nullptr, 0,
                                            0b10, flag, abuf, 512);
  // w scan
  k_scan<<<512, 512, 0, stream>>>(abuf, D11, D11T, Lam, wbuf);

  // y = w @ P2^T + u @ P3^T (+ x0 @ P1^T if x0 != 0)
  k_nt<3><<<dim3(128, 4), 256, 0, stream>>>(wbuf, P2, 512, u, P3, 256, x0, P1, 512,
                                            0b100, flag, out, 256);
}

// Round 3
// 662.746 us; speedup vs baseline: 1.6512x; 1.0641x over previous
//
#include <hip/hip_runtime.h>
#include <cstdint>
#include <cstddef>

#define EPSC 0.001f

// ---------------------------------------------------------------- any-nonzero
__global__ void k_anynz(const float* __restrict__ x, int n4, int* __restrict__ flag) {
  int i = blockIdx.x * blockDim.x + threadIdx.x;
  int stride = gridDim.x * blockDim.x;
  int found = 0;
  for (; i < n4; i += stride) {
    float4 v = ((const float4*)x)[i];
    if (v.x != 0.f || v.y != 0.f || v.z != 0.f || v.w != 0.f) { found = 1; break; }
  }
  if (found) atomicOr(flag, 1);
}

// ---------------------------------------------------------------- fused X^T X blocks (5 outputs)
__global__ __launch_bounds__(256) void k_xtx5(const float* __restrict__ X,
    const float* __restrict__ Y, float* __restrict__ E, float* __restrict__ C1,
    float* __restrict__ D11, float* __restrict__ D11T, float* __restrict__ Fm,
    float* __restrict__ B1, float* __restrict__ Lam)
{
  __shared__ float As[32][36];
  __shared__ float Bs[32][36];
  const int tid = threadIdx.x;
  const int tx = tid & 15, ty = tid >> 4;
  const int i0 = blockIdx.y * 32, j0 = blockIdx.x * 32;
  const int z = blockIdx.z;
  int aOff, bOff, npass, mode;
  float* out;
  switch (z) {
    case 0:  aOff = 0;    bOff = 0;   npass = 2; mode = 0; out = E;   break;
    case 1:  aOff = 512;  bOff = 0;   npass = 1; mode = 1; out = C1;  break;
    case 2:  aOff = 512;  bOff = 512; npass = 1; mode = 2; out = D11; break;
    case 3:  aOff = 1024; bOff = 0;   npass = 1; mode = 3; out = Fm;  break;
    default: aOff = 1024; bOff = 512; npass = 1; mode = 3; out = B1;  break;
  }
  const int i2 = tid & 31, kr = tid >> 5;
  const int NIT = npass * 48;
  float ra[4], rb[4], ra2[4], rb2[4];
  auto ld = [&](int n, float* pa, float* pb) {
    int p = n / 48;
    int k0 = (n - p * 48) * 32;
    int ao = aOff + p * 1024 + i0 + i2;
    int bo = bOff + p * 1024 + j0 + i2;
#pragma unroll
    for (int e = 0; e < 4; ++e) {
      int k = k0 + kr + 8 * e;
      pa[e] = X[(size_t)k * 1536 + ao];
      pb[e] = X[(size_t)k * 1536 + bo];
    }
  };
  ld(0, ra, rb);
  float acc00 = 0.f, acc01 = 0.f, acc10 = 0.f, acc11 = 0.f;
  for (int n = 0; n < NIT; ++n) {
    __syncthreads();
#pragma unroll
    for (int e = 0; e < 4; ++e) {
      As[kr + 8 * e][i2] = ra[e];
      Bs[kr + 8 * e][i2] = rb[e];
    }
    __syncthreads();
    if (n + 1 < NIT) ld(n + 1, ra2, rb2);
#pragma unroll
    for (int kk = 0; kk < 32; ++kk) {
      float2 a2 = *(const float2*)&As[kk][2 * ty];
      float2 b2 = *(const float2*)&Bs[kk][2 * tx];
      acc00 = fmaf(a2.x, b2.x, acc00);
      acc01 = fmaf(a2.x, b2.y, acc01);
      acc10 = fmaf(a2.y, b2.x, acc10);
      acc11 = fmaf(a2.y, b2.y, acc11);
    }
#pragma unroll
    for (int e = 0; e < 4; ++e) { ra[e] = ra2[e]; rb[e] = rb2[e]; }
  }
  float vals[2][2] = {{acc00, acc01}, {acc10, acc11}};
  int r = i0 + 2 * ty, c = j0 + 2 * tx;
#pragma unroll
  for (int i = 0; i < 2; ++i)
#pragma unroll
    for (int j = 0; j < 2; ++j) {
      int rr = r + i, cc = c + j;
      float d = vals[i][j];
      float o;
      if (mode == 0) {
        o = 0.5f * (d + Y[(size_t)rr * 512 + cc] - Y[(size_t)cc * 512 + rr]);
        if (rr == cc) o += EPSC;
      } else if (mode == 1) {
        o = -d;
      } else if (mode == 2) {
        o = (cc < rr) ? -d : 0.f;
        if (rr == cc) Lam[rr] = 0.5f * (d + EPSC);
      } else {
        o = d;
      }
      out[(size_t)rr * 512 + cc] = o;
      if (mode == 2) D11T[(size_t)cc * 512 + rr] = o;
    }
}

// ---------------------------------------------------------------- NS init: T0 = E*diag(w/dE), Q0 = C2*diag(w/dE)
__global__ void k_nsinit(const float* __restrict__ E, const float* __restrict__ C2,
                         float* __restrict__ T0, float* __restrict__ Q0) {
  int g = blockIdx.x * 256 + threadIdx.x;   // 768 rows x 128 quads
  int row = g >> 7;
  int c4 = (g & 127) << 2;
  float id0 = 0.85f / E[(size_t)(c4 + 0) * 513];
  float id1 = 0.85f / E[(size_t)(c4 + 1) * 513];
  float id2 = 0.85f / E[(size_t)(c4 + 2) * 513];
  float id3 = 0.85f / E[(size_t)(c4 + 3) * 513];
  if (row < 512) {
    float4 v = *(const float4*)(E + (size_t)row * 512 + c4);
    v.x *= id0; v.y *= id1; v.z *= id2; v.w *= id3;
    *(float4*)(T0 + (size_t)row * 512 + c4) = v;
  } else {
    int qr = row - 512;
    float4 v = *(const float4*)(C2 + (size_t)qr * 512 + c4);
    v.x *= id0; v.y *= id1; v.z *= id2; v.w *= id3;
    *(float4*)(Q0 + (size_t)qr * 512 + c4) = v;
  }
}

// ---------------------------------------------------------------- fused NS step: Tn = 2T - T*T ; Qn = 2Q - Q*T
template <bool WITH_T>
__global__ __launch_bounds__(256) void k_ns(const float* __restrict__ Tm,
    const float* __restrict__ Qm, float* __restrict__ Tn, float* __restrict__ Qn)
{
  __shared__ float As[32][36];
  __shared__ float Bs[32][36];
  const int tid = threadIdx.x;
  const int tx = tid & 15, ty = tid >> 4;
  const int yy = blockIdx.y;
  const bool isT = WITH_T && (yy < 16);
  const float* A = isT ? Tm : Qm;
  float* C = isT ? Tn : Qn;
  const int m0 = (isT ? yy : (yy - (WITH_T ? 16 : 0))) * 32;
  const int n0 = blockIdx.x * 32;
  const int lr = tid >> 3;
  const int lkq = (tid & 7) * 4;
  float4 av = *(const float4*)(A + (size_t)(m0 + lr) * 512 + lkq);
  float4 bv = *(const float4*)(Tm + (size_t)lr * 512 + n0 + lkq);
  float acc00 = 0.f, acc01 = 0.f, acc10 = 0.f, acc11 = 0.f;
  for (int k0 = 0; k0 < 512; k0 += 32) {
    __syncthreads();
    As[lkq + 0][lr] = av.x; As[lkq + 1][lr] = av.y;
    As[lkq + 2][lr] = av.z; As[lkq + 3][lr] = av.w;
    *(float4*)&Bs[lr][lkq] = bv;
    __syncthreads();
    if (k0 + 32 < 512) {
      av = *(const float4*)(A + (size_t)(m0 + lr) * 512 + k0 + 32 + lkq);
      bv = *(const float4*)(Tm + (size_t)(k0 + 32 + lr) * 512 + n0 + lkq);
    }
#pragma unroll
    for (int kk = 0; kk < 32; ++kk) {
      float2 a2 = *(const float2*)&As[kk][2 * ty];
      float2 b2 = *(const float2*)&Bs[kk][2 * tx];
      acc00 = fmaf(a2.x, b2.x, acc00);
      acc01 = fmaf(a2.x, b2.y, acc01);
      acc10 = fmaf(a2.y, b2.x, acc10);
      acc11 = fmaf(a2.y, b2.y, acc11);
    }
  }
  float vals[2][2] = {{acc00, acc01}, {acc10, acc11}};
  int r = m0 + 2 * ty, c = n0 + 2 * tx;
#pragma unroll
  for (int i = 0; i < 2; ++i)
#pragma unroll
    for (int j = 0; j < 2; ++j) {
      size_t idx = (size_t)(r + i) * 512 + (c + j);
      C[idx] = 2.f * A[idx] - vals[i][j];
    }
}

// ---------------------------------------------------------------- fused fold GEMMs (3 outputs)
__global__ __launch_bounds__(256) void k_fold(const float* __restrict__ Q,
    const float* __restrict__ Fm, const float* __restrict__ B1,
    const float* __restrict__ B2, const float* __restrict__ D21,
    const float* __restrict__ D22, float* __restrict__ P1,
    float* __restrict__ P2, float* __restrict__ P3)
{
  const int z = blockIdx.z;
  const float* B; const float* Aep; float* C; int N;
  if (z == 0)      { B = Fm; Aep = nullptr; C = P1; N = 512; }
  else if (z == 1) { B = B1; Aep = D21;     C = P2; N = 512; }
  else             { B = B2; Aep = D22;     C = P3; N = 256; }
  const int n0 = blockIdx.x * 32;
  if (n0 >= N) return;
  __shared__ float As[32][36];
  __shared__ float Bs[32][36];
  const int tid = threadIdx.x;
  const int tx = tid & 15, ty = tid >> 4;
  const int m0 = blockIdx.y * 32;
  const int lr = tid >> 3;
  const int lkq = (tid & 7) * 4;
  float4 av = *(const float4*)(Q + (size_t)(m0 + lr) * 512 + lkq);
  float4 bv = *(const float4*)(B + (size_t)lr * N + n0 + lkq);
  float acc00 = 0.f, acc01 = 0.f, acc10 = 0.f, acc11 = 0.f;
  for (int k0 = 0; k0 < 512; k0 += 32) {
    __syncthreads();
    As[lkq + 0][lr] = av.x; As[lkq + 1][lr] = av.y;
    As[lkq + 2][lr] = av.z; As[lkq + 3][lr] = av.w;
    *(float4*)&Bs[lr][lkq] = bv;
    __syncthreads();
    if (k0 + 32 < 512) {
      av = *(const float4*)(Q + (size_t)(m0 + lr) * 512 + k0 + 32 + lkq);
      bv = *(const float4*)(B + (size_t)(k0 + 32 + lr) * N + n0 + lkq);
    }
#pragma unroll
    for (int kk = 0; kk < 32; ++kk) {
      float2 a2 = *(const float2*)&As[kk][2 * ty];
      float2 b2 = *(const float2*)&Bs[kk][2 * tx];
      acc00 = fmaf(a2.x, b2.x, acc00);
      acc01 = fmaf(a2.x, b2.y, acc01);
      acc10 = fmaf(a2.y, b2.x, acc10);
      acc11 = fmaf(a2.y, b2.y, acc11);
    }
  }
  float vals[2][2] = {{acc00, acc01}, {acc10, acc11}};
  int r = m0 + 2 * ty, c = n0 + 2 * tx;
#pragma unroll
  for (int i = 0; i < 2; ++i)
#pragma unroll
    for (int j = 0; j < 2; ++j) {
      size_t idx = (size_t)(r + i) * N + (c + j);
      float d = vals[i][j];
      if (Aep) C[idx] = d + Aep[idx];
      else C[idx] = d;
    }
}

// ---------------------------------------------------------------- big NT GEMM (batch, prefetched)
template <int NOPS>
__global__ __launch_bounds__(256) void k_nt(
    const float* A0, const float* B0, int K0,
    const float* A1, const float* B1, int K1,
    const float* A2, const float* B2, int K2,
    int condMask, const int* __restrict__ flag,
    float* __restrict__ C, int ldc)
{
  __shared__ float As[16][68];
  __shared__ float Bs[16][68];
  const int tid = threadIdx.x;
  const int tx = tid & 15, ty = tid >> 4;
  const int m0 = blockIdx.x * 64, n0 = blockIdx.y * 64;
  const int lr = tid >> 2;
  const int lk = (tid & 3) * 4;
  float acc[4][4];
#pragma unroll
  for (int i = 0; i < 4; ++i)
#pragma unroll
    for (int j = 0; j < 4; ++j) acc[i][j] = 0.f;

#pragma unroll
  for (int op = 0; op < NOPS; ++op) {
    const float* A = (op == 0) ? A0 : (op == 1) ? A1 : A2;
    const float* B = (op == 0) ? B0 : (op == 1) ? B1 : B2;
    const int K = (op == 0) ? K0 : (op == 1) ? K1 : K2;
    if ((condMask >> op) & 1) {
      if (*flag == 0) continue;
    }
    float4 av = *(const float4*)(A + (size_t)(m0 + lr) * K + lk);
    float4 bv = *(const float4*)(B + (size_t)(n0 + lr) * K + lk);
    for (int k0 = 0; k0 < K; k0 += 16) {
      __syncthreads();
      As[lk + 0][lr] = av.x; As[lk + 1][lr] = av.y;
      As[lk + 2][lr] = av.z; As[lk + 3][lr] = av.w;
      Bs[lk + 0][lr] = bv.x; Bs[lk + 1][lr] = bv.y;
      Bs[lk + 2][lr] = bv.z; Bs[lk + 3][lr] = bv.w;
      __syncthreads();
      if (k0 + 16 < K) {
        av = *(const float4*)(A + (size_t)(m0 + lr) * K + k0 + 16 + lk);
        bv = *(const float4*)(B + (size_t)(n0 + lr) * K + k0 + 16 + lk);
      }
#pragma unroll
      for (int kk = 0; kk < 16; ++kk) {
        float4 a4 = *(const float4*)&As[kk][4 * ty];
        float4 b4 = *(const float4*)&Bs[kk][4 * tx];
        float ar[4] = {a4.x, a4.y, a4.z, a4.w};
        float br[4] = {b4.x, b4.y, b4.z, b4.w};
#pragma unroll
        for (int i = 0; i < 4; ++i)
#pragma unroll
          for (int j = 0; j < 4; ++j)
            acc[i][j] = fmaf(ar[i], br[j], acc[i][j]);
      }
    }
  }

#pragma unroll
  for (int i = 0; i < 4; ++i) {
    float4 v = make_float4(acc[i][0], acc[i][1], acc[i][2], acc[i][3]);
    *(float4*)(C + (size_t)(m0 + 4 * ty + i) * ldc + n0 + 4 * tx) = v;
  }
}

// ---------------------------------------------------------------- blocked tanh scan (v3: overlapped)
// 512 blocks x 16 rows; 512 threads (8 waves).
// wave 0 : serial tanh triangle for block t (deferred-update form, v_rcp)
// waves 1-6: history GEMM partials for step t+1 (j < 32t)
// wave 7 : stage doff(t), dblkT(t+1), ablk(t+1)
// then all: sblk(t+1) = ablk + sum(hist) + doff * w-block-t
__global__ __launch_bounds__(512, 4) void k_scan(const float* __restrict__ a,
    const float* __restrict__ D11, const float* __restrict__ D11T,
    const float* __restrict__ Lam, float* __restrict__ w)
{
  __shared__ float wt[512][17];       // [col][row]
  __shared__ float sblk[32][17];      // S(t)
  __shared__ float shist[6][32][17];  // hist partials
  __shared__ float dblkT[2][32][33];  // diag block, transposed: [col][row]
  __shared__ float doff[32][33];      // off-diag block rows t+1, cols t
  __shared__ float ablk[32][17];      // a block t+1
  __shared__ float rl2[512];          // 2/Lam
  const int tid = threadIdx.x;
  const int row0 = blockIdx.x * 16;

  rl2[tid] = 2.f / Lam[tid];
  if (tid < 128) {
    int rr = tid >> 3, cq = (tid & 7) * 4;
    float4 v = *(const float4*)(a + (size_t)(row0 + rr) * 512 + cq);
    sblk[cq + 0][rr] = v.x; sblk[cq + 1][rr] = v.y;
    sblk[cq + 2][rr] = v.z; sblk[cq + 3][rr] = v.w;
  } else if (tid < 384) {
    int f = tid - 128;
    int rr = f >> 3, cq = (f & 7) * 4;
    float4 v = *(const float4*)(D11 + (size_t)rr * 512 + cq);
    dblkT[0][cq + 0][rr] = v.x; dblkT[0][cq + 1][rr] = v.y;
    dblkT[0][cq + 2][rr] = v.z; dblkT[0][cq + 3][rr] = v.w;
  }
  __syncthreads();

  for (int t = 0; t < 16; ++t) {
    const int wv = tid >> 6;
    const int lane = tid & 63;
    const int c0 = 32 * t;
    const int jend2 = 32 * (t + 1);
    if (wv == 0) {
      // ---- phase B: serial triangle, 16 active lanes, deferred updates
      if (lane < 16) {
        float s[32];
#pragma unroll
        for (int il = 0; il < 32; ++il) s[il] = sblk[il][lane];
#pragma unroll
        for (int il = 0; il < 32; ++il) {
          float x2 = s[il] * rl2[c0 + il];
          float e = __expf(x2);
          float wv2 = 1.f - 2.f * __builtin_amdgcn_rcpf(e + 1.f);
          wt[c0 + il][lane] = wv2;
#pragma unroll
          for (int j2 = il + 1; j2 < 32; ++j2)
            s[j2] = fmaf(dblkT[t & 1][il][j2], wv2, s[j2]);
        }
      }
    } else if (wv <= 6) {
      // ---- history partials for S(t+1), j in [0, 32t) split 6 ways
      if (t < 15) {
        const int r = lane & 15;
        const int il0 = (lane >> 4) * 8;
        const int n = c0;
        int jlo = (n * (wv - 1)) / 6, jhi = (n * wv) / 6;
        float acc[8] = {0.f, 0.f, 0.f, 0.f, 0.f, 0.f, 0.f, 0.f};
        for (int j = jlo; j < jhi; ++j) {
          float wj = wt[j][r];
          float4 d0 = *(const float4*)(D11T + (size_t)j * 512 + jend2 + il0);
          float4 d1 = *(const float4*)(D11T + (size_t)j * 512 + jend2 + il0 + 4);
          acc[0] = fmaf(d0.x, wj, acc[0]); acc[1] = fmaf(d0.y, wj, acc[1]);
          acc[2] = fmaf(d0.z, wj, acc[2]); acc[3] = fmaf(d0.w, wj, acc[3]);
          acc[4] = fmaf(d1.x, wj, acc[4]); acc[5] = fmaf(d1.y, wj, acc[5]);
          acc[6] = fmaf(d1.z, wj, acc[6]); acc[7] = fmaf(d1.w, wj, acc[7]);
        }
#pragma unroll
        for (int k = 0; k < 8; ++k) shist[wv - 1][il0 + k][r] = acc[k];
      }
    } else {
      // ---- wave 7: stage next-step operands
      if (t < 15) {
#pragma unroll
        for (int e = 0; e < 4; ++e) {
          int f = lane + 64 * e;
          int rr = f >> 3, cq = (f & 7) * 4;
          float4 v = *(const float4*)(D11 + (size_t)(jend2 + rr) * 512 + c0 + cq);
          doff[rr][cq + 0] = v.x; doff[rr][cq + 1] = v.y;
          doff[rr][cq + 2] = v.z; doff[rr][cq + 3] = v.w;
          float4 v2 = *(const float4*)(D11 + (size_t)(jend2 + rr) * 512 + jend2 + cq);
          dblkT[(t + 1) & 1][cq + 0][rr] = v2.x; dblkT[(t + 1) & 1][cq + 1][rr] = v2.y;
          dblkT[(t + 1) & 1][cq + 2][rr] = v2.z; dblkT[(t + 1) & 1][cq + 3][rr] = v2.w;
        }
#pragma unroll
        for (int e = 0; e < 2; ++e) {
          int f = lane + 64 * e;
          int rr = f >> 3, cq = (f & 7) * 4;
          float4 v = *(const float4*)(a + (size_t)(row0 + rr) * 512 + jend2 + cq);
          ablk[cq + 0][rr] = v.x; ablk[cq + 1][rr] = v.y;
          ablk[cq + 2][rr] = v.z; ablk[cq + 3][rr] = v.w;
        }
      }
    }
    __syncthreads();
    if (t < 15) {
      // ---- fresh combine: S(t+1) = ablk + sum(shist) + doff * w-block(t)
      const int il = tid >> 4, r2 = tid & 15;
      float s = ablk[il][r2];
#pragma unroll
      for (int k = 0; k < 6; ++k) s += shist[k][il][r2];
#pragma unroll 8
      for (int j = 0; j < 32; ++j)
        s = fmaf(doff[il][j], wt[c0 + j][r2], s);
      sblk[il][r2] = s;
      __syncthreads();
    }
  }

  // write out (coalesced in global)
  for (int k = 0; k < 16; ++k) {
    w[(size_t)(row0 + k) * 512 + tid] = wt[tid][k];
  }
}

// ---------------------------------------------------------------- launcher
extern "C" void kernel_launch(void* const* d_in, const int* in_sizes, int n_in,
                              void* d_out, int out_size, void* d_ws, size_t ws_size,
                              hipStream_t stream)
{
  const float* u   = (const float*)d_in[0];   // 8192 x 256
  const float* x0  = (const float*)d_in[1];   // 8192 x 512
  const float* X   = (const float*)d_in[2];   // 1536 x 1536
  const float* Y   = (const float*)d_in[3];   // 512 x 512
  const float* B2  = (const float*)d_in[4];   // 512 x 256
  const float* C2  = (const float*)d_in[5];   // 256 x 512
  const float* D21 = (const float*)d_in[6];   // 256 x 512
  const float* D22 = (const float*)d_in[7];   // 256 x 256
  const float* D12 = (const float*)d_in[8];   // 512 x 256
  float* out = (float*)d_out;
  float* ws = (float*)d_ws;

  float* E    = ws + 0;
  float* T0   = ws + 262144;
  float* T1   = ws + 524288;
  float* Q0   = ws + 786432;    // 256x512
  float* Q1   = ws + 917504;    // 256x512
  float* C1   = ws + 1048576;
  float* D11  = ws + 1310720;
  float* Fm   = ws + 1572864;
  float* B1   = ws + 1835008;
  float* P1   = ws + 2097152;
  float* P2   = ws + 2359296;
  float* P3   = ws + 2621440;   // 256x256
  float* Lam  = ws + 2686976;   // 512
  int*   flag = (int*)(ws + 2687488);
  float* abuf = ws + 2687616;   // 8192x512
  float* wbuf = ws + 6881920;   // 8192x512
  float* D11T = ws + 11076224;  // 512x512

  hipMemsetAsync(flag, 0, 4, stream);
  k_anynz<<<256, 256, 0, stream>>>(x0, 8192 * 512 / 4, flag);

  // H = X^T X needed blocks, one launch
  k_xtx5<<<dim3(16, 16, 5), 256, 0, stream>>>(X, Y, E, C1, D11, D11T, Fm, B1, Lam);

  // Newton-Schulz on (T = E*M, Q = C2*M): T0/Q0 by column scaling, then
  // 5 x {T' = 2T - T*T ; Q' = 2Q - Q*T} + 1 final Q-only. Residual ~ rho^64.
  k_nsinit<<<384, 256, 0, stream>>>(E, C2, T0, Q0);
  float *Ta = T0, *Tb = T1, *Qa = Q0, *Qb = Q1;
  for (int it = 0; it < 5; ++it) {
    k_ns<true><<<dim3(16, 24), 256, 0, stream>>>(Ta, Qa, Tb, Qb);
    float* tp = Ta; Ta = Tb; Tb = tp;
    float* qp = Qa; Qa = Qb; Qb = qp;
  }
  k_ns<false><<<dim3(16, 8), 256, 0, stream>>>(Ta, Qa, nullptr, Qb);
  float* Q = Qb;

  // folds: P1 = Q*Fm ; P2 = Q*B1 + D21 ; P3 = Q*B2 + D22
  k_fold<<<dim3(16, 8, 3), 256, 0, stream>>>(Q, Fm, B1, B2, D21, D22, P1, P2, P3);

  // a = u @ D12^T (+ x0 @ C1^T if x0 != 0)
  k_nt<2><<<dim3(128, 8), 256, 0, stream>>>(u, D12, 256, x0, C1, 512,
                                            nullptr, nullptr, 0,
                                            0b10, flag, abuf, 512);
  // w scan
  k_scan<<<512, 512, 0, stream>>>(abuf, D11, D11T, Lam, wbuf);

  // y = w @ P2^T + u @ P3^T (+ x0 @ P1^T if x0 != 0)
  k_nt<3><<<dim3(128, 4), 256, 0, stream>>>(wbuf, P2, 512, u, P3, 256, x0, P1, 512,
                                            0b100, flag, out, 256);
}

// Round 4
// 558.739 us; speedup vs baseline: 1.9585x; 1.1861x over previous
//
#include <hip/hip_runtime.h>
#include <cstdint>
#include <cstddef>

#define EPSC 0.001f

typedef __attribute__((ext_vector_type(8))) short short8;
typedef __attribute__((ext_vector_type(4))) float f32x4;

// ---------------------------------------------------------------- any-nonzero
__global__ void k_anynz(const float* __restrict__ x, int n4, int* __restrict__ flag) {
  int i = blockIdx.x * blockDim.x + threadIdx.x;
  int stride = gridDim.x * blockDim.x;
  int found = 0;
  for (; i < n4; i += stride) {
    float4 v = ((const float4*)x)[i];
    if (v.x != 0.f || v.y != 0.f || v.z != 0.f || v.w != 0.f) { found = 1; break; }
  }
  if (found) atomicOr(flag, 1);
}

// ---------------------------------------------------------------- fused X^T X blocks (5 outputs)
__global__ __launch_bounds__(256) void k_xtx5(const float* __restrict__ X,
    const float* __restrict__ Y, float* __restrict__ E, float* __restrict__ C1,
    float* __restrict__ D11, float* __restrict__ D11T, float* __restrict__ Fm,
    float* __restrict__ B1, float* __restrict__ Lam)
{
  __shared__ float As[32][36];
  __shared__ float Bs[32][36];
  const int tid = threadIdx.x;
  const int tx = tid & 15, ty = tid >> 4;
  const int i0 = blockIdx.y * 32, j0 = blockIdx.x * 32;
  const int z = blockIdx.z;
  int aOff, bOff, npass, mode;
  float* out;
  switch (z) {
    case 0:  aOff = 0;    bOff = 0;   npass = 2; mode = 0; out = E;   break;
    case 1:  aOff = 512;  bOff = 0;   npass = 1; mode = 1; out = C1;  break;
    case 2:  aOff = 512;  bOff = 512; npass = 1; mode = 2; out = D11; break;
    case 3:  aOff = 1024; bOff = 0;   npass = 1; mode = 3; out = Fm;  break;
    default: aOff = 1024; bOff = 512; npass = 1; mode = 3; out = B1;  break;
  }
  const int i2 = tid & 31, kr = tid >> 5;
  const int NIT = npass * 48;
  float ra[4], rb[4], ra2[4], rb2[4];
  auto ld = [&](int n, float* pa, float* pb) {
    int p = n / 48;
    int k0 = (n - p * 48) * 32;
    int ao = aOff + p * 1024 + i0 + i2;
    int bo = bOff + p * 1024 + j0 + i2;
#pragma unroll
    for (int e = 0; e < 4; ++e) {
      int k = k0 + kr + 8 * e;
      pa[e] = X[(size_t)k * 1536 + ao];
      pb[e] = X[(size_t)k * 1536 + bo];
    }
  };
  ld(0, ra, rb);
  float acc00 = 0.f, acc01 = 0.f, acc10 = 0.f, acc11 = 0.f;
  for (int n = 0; n < NIT; ++n) {
    __syncthreads();
#pragma unroll
    for (int e = 0; e < 4; ++e) {
      As[kr + 8 * e][i2] = ra[e];
      Bs[kr + 8 * e][i2] = rb[e];
    }
    __syncthreads();
    if (n + 1 < NIT) ld(n + 1, ra2, rb2);
#pragma unroll
    for (int kk = 0; kk < 32; ++kk) {
      float2 a2 = *(const float2*)&As[kk][2 * ty];
      float2 b2 = *(const float2*)&Bs[kk][2 * tx];
      acc00 = fmaf(a2.x, b2.x, acc00);
      acc01 = fmaf(a2.x, b2.y, acc01);
      acc10 = fmaf(a2.y, b2.x, acc10);
      acc11 = fmaf(a2.y, b2.y, acc11);
    }
#pragma unroll
    for (int e = 0; e < 4; ++e) { ra[e] = ra2[e]; rb[e] = rb2[e]; }
  }
  float vals[2][2] = {{acc00, acc01}, {acc10, acc11}};
  int r = i0 + 2 * ty, c = j0 + 2 * tx;
#pragma unroll
  for (int i = 0; i < 2; ++i)
#pragma unroll
    for (int j = 0; j < 2; ++j) {
      int rr = r + i, cc = c + j;
      float d = vals[i][j];
      float o;
      if (mode == 0) {
        o = 0.5f * (d + Y[(size_t)rr * 512 + cc] - Y[(size_t)cc * 512 + rr]);
        if (rr == cc) o += EPSC;
      } else if (mode == 1) {
        o = -d;
      } else if (mode == 2) {
        o = (cc < rr) ? -d : 0.f;
        if (rr == cc) Lam[rr] = 0.5f * (d + EPSC);
      } else {
        o = d;
      }
      out[(size_t)rr * 512 + cc] = o;
      if (mode == 2) D11T[(size_t)cc * 512 + rr] = o;
    }
}

// ---------------------------------------------------------------- NS init
__global__ void k_nsinit(const float* __restrict__ E, const float* __restrict__ C2,
                         float* __restrict__ T0, float* __restrict__ Q0) {
  int g = blockIdx.x * 256 + threadIdx.x;
  int row = g >> 7;
  int c4 = (g & 127) << 2;
  float id0 = 0.85f / E[(size_t)(c4 + 0) * 513];
  float id1 = 0.85f / E[(size_t)(c4 + 1) * 513];
  float id2 = 0.85f / E[(size_t)(c4 + 2) * 513];
  float id3 = 0.85f / E[(size_t)(c4 + 3) * 513];
  if (row < 512) {
    float4 v = *(const float4*)(E + (size_t)row * 512 + c4);
    v.x *= id0; v.y *= id1; v.z *= id2; v.w *= id3;
    *(float4*)(T0 + (size_t)row * 512 + c4) = v;
  } else {
    int qr = row - 512;
    float4 v = *(const float4*)(C2 + (size_t)qr * 512 + c4);
    v.x *= id0; v.y *= id1; v.z *= id2; v.w *= id3;
    *(float4*)(Q0 + (size_t)qr * 512 + c4) = v;
  }
}

// ---------------------------------------------------------------- fused NS step
template <bool WITH_T>
__global__ __launch_bounds__(256) void k_ns(const float* __restrict__ Tm,
    const float* __restrict__ Qm, float* __restrict__ Tn, float* __restrict__ Qn)
{
  __shared__ float As[32][36];
  __shared__ float Bs[32][36];
  const int tid = threadIdx.x;
  const int tx = tid & 15, ty = tid >> 4;
  const int yy = blockIdx.y;
  const bool isT = WITH_T && (yy < 16);
  const float* A = isT ? Tm : Qm;
  float* C = isT ? Tn : Qn;
  const int m0 = (isT ? yy : (yy - (WITH_T ? 16 : 0))) * 32;
  const int n0 = blockIdx.x * 32;
  const int lr = tid >> 3;
  const int lkq = (tid & 7) * 4;
  float4 av = *(const float4*)(A + (size_t)(m0 + lr) * 512 + lkq);
  float4 bv = *(const float4*)(Tm + (size_t)lr * 512 + n0 + lkq);
  float acc00 = 0.f, acc01 = 0.f, acc10 = 0.f, acc11 = 0.f;
  for (int k0 = 0; k0 < 512; k0 += 32) {
    __syncthreads();
    As[lkq + 0][lr] = av.x; As[lkq + 1][lr] = av.y;
    As[lkq + 2][lr] = av.z; As[lkq + 3][lr] = av.w;
    *(float4*)&Bs[lr][lkq] = bv;
    __syncthreads();
    if (k0 + 32 < 512) {
      av = *(const float4*)(A + (size_t)(m0 + lr) * 512 + k0 + 32 + lkq);
      bv = *(const float4*)(Tm + (size_t)(k0 + 32 + lr) * 512 + n0 + lkq);
    }
#pragma unroll
    for (int kk = 0; kk < 32; ++kk) {
      float2 a2 = *(const float2*)&As[kk][2 * ty];
      float2 b2 = *(const float2*)&Bs[kk][2 * tx];
      acc00 = fmaf(a2.x, b2.x, acc00);
      acc01 = fmaf(a2.x, b2.y, acc01);
      acc10 = fmaf(a2.y, b2.x, acc10);
      acc11 = fmaf(a2.y, b2.y, acc11);
    }
  }
  float vals[2][2] = {{acc00, acc01}, {acc10, acc11}};
  int r = m0 + 2 * ty, c = n0 + 2 * tx;
#pragma unroll
  for (int i = 0; i < 2; ++i)
#pragma unroll
    for (int j = 0; j < 2; ++j) {
      size_t idx = (size_t)(r + i) * 512 + (c + j);
      C[idx] = 2.f * A[idx] - vals[i][j];
    }
}

// ---------------------------------------------------------------- fused fold GEMMs
__global__ __launch_bounds__(256) void k_fold(const float* __restrict__ Q,
    const float* __restrict__ Fm, const float* __restrict__ B1,
    const float* __restrict__ B2, const float* __restrict__ D21,
    const float* __restrict__ D22, float* __restrict__ P1,
    float* __restrict__ P2, float* __restrict__ P3)
{
  const int z = blockIdx.z;
  const float* B; const float* Aep; float* C; int N;
  if (z == 0)      { B = Fm; Aep = nullptr; C = P1; N = 512; }
  else if (z == 1) { B = B1; Aep = D21;     C = P2; N = 512; }
  else             { B = B2; Aep = D22;     C = P3; N = 256; }
  const int n0 = blockIdx.x * 32;
  if (n0 >= N) return;
  __shared__ float As[32][36];
  __shared__ float Bs[32][36];
  const int tid = threadIdx.x;
  const int tx = tid & 15, ty = tid >> 4;
  const int m0 = blockIdx.y * 32;
  const int lr = tid >> 3;
  const int lkq = (tid & 7) * 4;
  float4 av = *(const float4*)(Q + (size_t)(m0 + lr) * 512 + lkq);
  float4 bv = *(const float4*)(B + (size_t)lr * N + n0 + lkq);
  float acc00 = 0.f, acc01 = 0.f, acc10 = 0.f, acc11 = 0.f;
  for (int k0 = 0; k0 < 512; k0 += 32) {
    __syncthreads();
    As[lkq + 0][lr] = av.x; As[lkq + 1][lr] = av.y;
    As[lkq + 2][lr] = av.z; As[lkq + 3][lr] = av.w;
    *(float4*)&Bs[lr][lkq] = bv;
    __syncthreads();
    if (k0 + 32 < 512) {
      av = *(const float4*)(Q + (size_t)(m0 + lr) * 512 + k0 + 32 + lkq);
      bv = *(const float4*)(B + (size_t)(k0 + 32 + lr) * N + n0 + lkq);
    }
#pragma unroll
    for (int kk = 0; kk < 32; ++kk) {
      float2 a2 = *(const float2*)&As[kk][2 * ty];
      float2 b2 = *(const float2*)&Bs[kk][2 * tx];
      acc00 = fmaf(a2.x, b2.x, acc00);
      acc01 = fmaf(a2.x, b2.y, acc01);
      acc10 = fmaf(a2.y, b2.x, acc10);
      acc11 = fmaf(a2.y, b2.y, acc11);
    }
  }
  float vals[2][2] = {{acc00, acc01}, {acc10, acc11}};
  int r = m0 + 2 * ty, c = n0 + 2 * tx;
#pragma unroll
  for (int i = 0; i < 2; ++i)
#pragma unroll
    for (int j = 0; j < 2; ++j) {
      size_t idx = (size_t)(r + i) * N + (c + j);
      float d = vals[i][j];
      if (Aep) C[idx] = d + Aep[idx];
      else C[idx] = d;
    }
}

// ---------------------------------------------------------------- bf16 hi/lo split (2 segments)
__global__ void k_split2(const float* __restrict__ s0, ushort* __restrict__ h0,
                         ushort* __restrict__ l0, int c0,
                         const float* __restrict__ s1, ushort* __restrict__ h1,
                         ushort* __restrict__ l1, int c1)
{
  int i = blockIdx.x * 256 + threadIdx.x;
  int tot = c0 + c1;
  int stride = gridDim.x * 256;
  for (; i < tot; i += stride) {
    const float* s; ushort* h; ushort* l; int k;
    if (i < c0) { s = s0; h = h0; l = l0; k = i; }
    else        { s = s1; h = h1; l = l1; k = i - c0; }
    float4 v = ((const float4*)s)[k];
    ushort4 hv, lv;
    uint b;
    b = __float_as_uint(v.x); hv.x = (ushort)(b >> 16);
    lv.x = (ushort)(__float_as_uint(v.x - __uint_as_float(b & 0xFFFF0000u)) >> 16);
    b = __float_as_uint(v.y); hv.y = (ushort)(b >> 16);
    lv.y = (ushort)(__float_as_uint(v.y - __uint_as_float(b & 0xFFFF0000u)) >> 16);
    b = __float_as_uint(v.z); hv.z = (ushort)(b >> 16);
    lv.z = (ushort)(__float_as_uint(v.z - __uint_as_float(b & 0xFFFF0000u)) >> 16);
    b = __float_as_uint(v.w); hv.w = (ushort)(b >> 16);
    lv.w = (ushort)(__float_as_uint(v.w - __uint_as_float(b & 0xFFFF0000u)) >> 16);
    ((ushort4*)h)[k] = hv;
    ((ushort4*)l)[k] = lv;
  }
}

// ---------------------------------------------------------------- MFMA NT GEMM, split-bf16 3-pass
// C[8192 x ldc] = sum_ops Aop @ Bop^T, operands pre-split bf16 hi/lo, row-major [M][K]/[N][K].
template <int NOPS>
__global__ __launch_bounds__(256) void k_ntm(
    const ushort* __restrict__ Ah0, const ushort* __restrict__ Al0,
    const ushort* __restrict__ Bh0, const ushort* __restrict__ Bl0, int K0,
    const ushort* __restrict__ Ah1, const ushort* __restrict__ Al1,
    const ushort* __restrict__ Bh1, const ushort* __restrict__ Bl1, int K1,
    float* __restrict__ C, int ldc)
{
  __shared__ ushort sAh[64][40], sAl[64][40], sBh[64][40], sBl[64][40];
  const int tid = threadIdx.x;
  const int m0 = blockIdx.x * 64, n0 = blockIdx.y * 64;
  const int wid = tid >> 6, lane = tid & 63;
  const int wr = wid >> 1, wc = wid & 1;
  const int fr = lane & 15, fg = lane >> 4;
  const int srow = tid >> 2;
  const int sko = (tid & 3) * 8;
  f32x4 acc[2][2] = {};

#pragma unroll
  for (int op = 0; op < NOPS; ++op) {
    const ushort* Ah = (op == 0) ? Ah0 : Ah1;
    const ushort* Al = (op == 0) ? Al0 : Al1;
    const ushort* Bh = (op == 0) ? Bh0 : Bh1;
    const ushort* Bl = (op == 0) ? Bl0 : Bl1;
    const int K = (op == 0) ? K0 : K1;
    uint4 pah = *(const uint4*)(Ah + (size_t)(m0 + srow) * K + sko);
    uint4 pal = *(const uint4*)(Al + (size_t)(m0 + srow) * K + sko);
    uint4 pbh = *(const uint4*)(Bh + (size_t)(n0 + srow) * K + sko);
    uint4 pbl = *(const uint4*)(Bl + (size_t)(n0 + srow) * K + sko);
    for (int k0 = 0; k0 < K; k0 += 32) {
      __syncthreads();
      *(uint4*)&sAh[srow][sko] = pah;
      *(uint4*)&sAl[srow][sko] = pal;
      *(uint4*)&sBh[srow][sko] = pbh;
      *(uint4*)&sBl[srow][sko] = pbl;
      __syncthreads();
      if (k0 + 32 < K) {
        pah = *(const uint4*)(Ah + (size_t)(m0 + srow) * K + k0 + 32 + sko);
        pal = *(const uint4*)(Al + (size_t)(m0 + srow) * K + k0 + 32 + sko);
        pbh = *(const uint4*)(Bh + (size_t)(n0 + srow) * K + k0 + 32 + sko);
        pbl = *(const uint4*)(Bl + (size_t)(n0 + srow) * K + k0 + 32 + sko);
      }
      short8 fah[2], fal[2], fbh[2], fbl[2];
#pragma unroll
      for (int s = 0; s < 2; ++s) {
        fah[s] = *(const short8*)&sAh[wr * 32 + s * 16 + fr][fg * 8];
        fal[s] = *(const short8*)&sAl[wr * 32 + s * 16 + fr][fg * 8];
        fbh[s] = *(const short8*)&sBh[wc * 32 + s * 16 + fr][fg * 8];
        fbl[s] = *(const short8*)&sBl[wc * 32 + s * 16 + fr][fg * 8];
      }
#pragma unroll
      for (int i = 0; i < 2; ++i)
#pragma unroll
        for (int j = 0; j < 2; ++j) {
          acc[i][j] = __builtin_amdgcn_mfma_f32_16x16x32_bf16(fah[i], fbh[j], acc[i][j], 0, 0, 0);
          acc[i][j] = __builtin_amdgcn_mfma_f32_16x16x32_bf16(fah[i], fbl[j], acc[i][j], 0, 0, 0);
          acc[i][j] = __builtin_amdgcn_mfma_f32_16x16x32_bf16(fal[i], fbh[j], acc[i][j], 0, 0, 0);
        }
    }
  }

#pragma unroll
  for (int i = 0; i < 2; ++i)
#pragma unroll
    for (int j = 0; j < 2; ++j) {
      int rr = m0 + wr * 32 + i * 16 + fg * 4;
      int cc = n0 + wc * 32 + j * 16 + fr;
#pragma unroll
      for (int q = 0; q < 4; ++q)
        C[(size_t)(rr + q) * ldc + cc] = acc[i][j][q];
    }
}

// ---------------------------------------------------------------- flag-gated fp32 NT accumulate (x0 terms)
__global__ __launch_bounds__(256) void k_ntadd(const float* __restrict__ A,
    const float* __restrict__ B, int K, const int* __restrict__ flag,
    float* __restrict__ C, int ldc)
{
  if (*flag == 0) return;
  __shared__ float As[16][68];
  __shared__ float Bs[16][68];
  const int tid = threadIdx.x;
  const int tx = tid & 15, ty = tid >> 4;
  const int m0 = blockIdx.x * 64, n0 = blockIdx.y * 64;
  const int lr = tid >> 2;
  const int lk = (tid & 3) * 4;
  float acc[4][4];
#pragma unroll
  for (int i = 0; i < 4; ++i)
#pragma unroll
    for (int j = 0; j < 4; ++j) acc[i][j] = 0.f;
  float4 av = *(const float4*)(A + (size_t)(m0 + lr) * K + lk);
  float4 bv = *(const float4*)(B + (size_t)(n0 + lr) * K + lk);
  for (int k0 = 0; k0 < K; k0 += 16) {
    __syncthreads();
    As[lk + 0][lr] = av.x; As[lk + 1][lr] = av.y;
    As[lk + 2][lr] = av.z; As[lk + 3][lr] = av.w;
    Bs[lk + 0][lr] = bv.x; Bs[lk + 1][lr] = bv.y;
    Bs[lk + 2][lr] = bv.z; Bs[lk + 3][lr] = bv.w;
    __syncthreads();
    if (k0 + 16 < K) {
      av = *(const float4*)(A + (size_t)(m0 + lr) * K + k0 + 16 + lk);
      bv = *(const float4*)(B + (size_t)(n0 + lr) * K + k0 + 16 + lk);
    }
#pragma unroll
    for (int kk = 0; kk < 16; ++kk) {
      float4 a4 = *(const float4*)&As[kk][4 * ty];
      float4 b4 = *(const float4*)&Bs[kk][4 * tx];
      float ar[4] = {a4.x, a4.y, a4.z, a4.w};
      float br[4] = {b4.x, b4.y, b4.z, b4.w};
#pragma unroll
      for (int i = 0; i < 4; ++i)
#pragma unroll
        for (int j = 0; j < 4; ++j)
          acc[i][j] = fmaf(ar[i], br[j], acc[i][j]);
    }
  }
#pragma unroll
  for (int i = 0; i < 4; ++i) {
    float* p = C + (size_t)(m0 + 4 * ty + i) * ldc + n0 + 4 * tx;
    float4 v = *(float4*)p;
    v.x += acc[i][0]; v.y += acc[i][1]; v.z += acc[i][2]; v.w += acc[i][3];
    *(float4*)p = v;
  }
}

// ---------------------------------------------------------------- blocked tanh scan (v4: pipelined history)
__global__ __launch_bounds__(512, 4) void k_scan(const float* __restrict__ a,
    const float* __restrict__ D11, const float* __restrict__ D11T,
    const float* __restrict__ Lam, ushort* __restrict__ wh, ushort* __restrict__ wl)
{
  __shared__ float wt[512][17];
  __shared__ float sblk[32][17];
  __shared__ float shist[6][32][17];
  __shared__ float dblkT[2][32][33];
  __shared__ float doff[32][33];
  __shared__ float ablk[32][17];
  __shared__ float rl2[512];
  const int tid = threadIdx.x;
  const int row0 = blockIdx.x * 16;

  rl2[tid] = 2.f / Lam[tid];
  if (tid < 128) {
    int rr = tid >> 3, cq = (tid & 7) * 4;
    float4 v = *(const float4*)(a + (size_t)(row0 + rr) * 512 + cq);
    sblk[cq + 0][rr] = v.x; sblk[cq + 1][rr] = v.y;
    sblk[cq + 2][rr] = v.z; sblk[cq + 3][rr] = v.w;
  } else if (tid < 384) {
    int f = tid - 128;
    int rr = f >> 3, cq = (f & 7) * 4;
    float4 v = *(const float4*)(D11 + (size_t)rr * 512 + cq);
    dblkT[0][cq + 0][rr] = v.x; dblkT[0][cq + 1][rr] = v.y;
    dblkT[0][cq + 2][rr] = v.z; dblkT[0][cq + 3][rr] = v.w;
  }
  __syncthreads();

  for (int t = 0; t < 16; ++t) {
    const int wv = tid >> 6;
    const int lane = tid & 63;
    const int c0 = 32 * t;
    const int jend2 = 32 * (t + 1);
    if (wv == 0) {
      // serial triangle, 16 lanes, deferred updates
      if (lane < 16) {
        float s[32];
#pragma unroll
        for (int il = 0; il < 32; ++il) s[il] = sblk[il][lane];
#pragma unroll
        for (int il = 0; il < 32; ++il) {
          float x2 = s[il] * rl2[c0 + il];
          float e = __expf(x2);
          float wv2 = 1.f - 2.f * __builtin_amdgcn_rcpf(e + 1.f);
          wt[c0 + il][lane] = wv2;
#pragma unroll
          for (int j2 = il + 1; j2 < 32; ++j2)
            s[j2] = fmaf(dblkT[t & 1][il][j2], wv2, s[j2]);
        }
      }
    } else if (wv <= 6) {
      // pipelined history partials for S(t+1): chunks of 4 consecutive j, wave-strided
      if (t < 15) {
        const int r = lane & 15;
        const int il0 = (lane >> 4) * 8;
        const int n = c0;
        float acc[8] = {0.f, 0.f, 0.f, 0.f, 0.f, 0.f, 0.f, 0.f};
        for (int j0 = (wv - 1) * 4; j0 < n; j0 += 24) {
          float4 d[4][2];
          float wj4[4];
#pragma unroll
          for (int q = 0; q < 4; ++q) {
            int j = j0 + q;
            int jc = (j < n) ? j : 0;
            const float* dp = D11T + (size_t)jc * 512 + jend2 + il0;
            d[q][0] = *(const float4*)dp;
            d[q][1] = *(const float4*)(dp + 4);
            wj4[q] = (j < n) ? wt[j][r] : 0.f;
          }
#pragma unroll
          for (int q = 0; q < 4; ++q) {
            acc[0] = fmaf(d[q][0].x, wj4[q], acc[0]);
            acc[1] = fmaf(d[q][0].y, wj4[q], acc[1]);
            acc[2] = fmaf(d[q][0].z, wj4[q], acc[2]);
            acc[3] = fmaf(d[q][0].w, wj4[q], acc[3]);
            acc[4] = fmaf(d[q][1].x, wj4[q], acc[4]);
            acc[5] = fmaf(d[q][1].y, wj4[q], acc[5]);
            acc[6] = fmaf(d[q][1].z, wj4[q], acc[6]);
            acc[7] = fmaf(d[q][1].w, wj4[q], acc[7]);
          }
        }
#pragma unroll
        for (int k = 0; k < 8; ++k) shist[wv - 1][il0 + k][r] = acc[k];
      }
    } else {
      // wave 7: stage next-step operands
      if (t < 15) {
#pragma unroll
        for (int e = 0; e < 4; ++e) {
          int f = lane + 64 * e;
          int rr = f >> 3, cq = (f & 7) * 4;
          float4 v = *(const float4*)(D11 + (size_t)(jend2 + rr) * 512 + c0 + cq);
          doff[rr][cq + 0] = v.x; doff[rr][cq + 1] = v.y;
          doff[rr][cq + 2] = v.z; doff[rr][cq + 3] = v.w;
          float4 v2 = *(const float4*)(D11 + (size_t)(jend2 + rr) * 512 + jend2 + cq);
          dblkT[(t + 1) & 1][cq + 0][rr] = v2.x; dblkT[(t + 1) & 1][cq + 1][rr] = v2.y;
          dblkT[(t + 1) & 1][cq + 2][rr] = v2.z; dblkT[(t + 1) & 1][cq + 3][rr] = v2.w;
        }
#pragma unroll
        for (int e = 0; e < 2; ++e) {
          int f = lane + 64 * e;
          int rr = f >> 3, cq = (f & 7) * 4;
          float4 v = *(const float4*)(a + (size_t)(row0 + rr) * 512 + jend2 + cq);
          ablk[cq + 0][rr] = v.x; ablk[cq + 1][rr] = v.y;
          ablk[cq + 2][rr] = v.z; ablk[cq + 3][rr] = v.w;
        }
      }
    }
    __syncthreads();
    if (t < 15) {
      const int il = tid >> 4, r2 = tid & 15;
      float s = ablk[il][r2];
#pragma unroll
      for (int k = 0; k < 6; ++k) s += shist[k][il][r2];
#pragma unroll 8
      for (int j = 0; j < 32; ++j)
        s = fmaf(doff[il][j], wt[c0 + j][r2], s);
      sblk[il][r2] = s;
      __syncthreads();
    }
  }

  // write out w as bf16 hi/lo pairs
  const int c2 = tid & 255;
  const int rh = tid >> 8;
#pragma unroll
  for (int k = 0; k < 8; ++k) {
    int row = rh * 8 + k;
    float f0 = wt[2 * c2][row];
    float f1 = wt[2 * c2 + 1][row];
    uint b0 = __float_as_uint(f0), b1 = __float_as_uint(f1);
    ushort h0 = (ushort)(b0 >> 16), h1 = (ushort)(b1 >> 16);
    float r0 = f0 - __uint_as_float(b0 & 0xFFFF0000u);
    float r1 = f1 - __uint_as_float(b1 & 0xFFFF0000u);
    ushort l0 = (ushort)(__float_as_uint(r0) >> 16);
    ushort l1 = (ushort)(__float_as_uint(r1) >> 16);
    size_t off = (size_t)(row0 + row) * 512 + 2 * c2;
    *(ushort2*)(wh + off) = make_ushort2(h0, h1);
    *(ushort2*)(wl + off) = make_ushort2(l0, l1);
  }
}

// ---------------------------------------------------------------- launcher
extern "C" void kernel_launch(void* const* d_in, const int* in_sizes, int n_in,
                              void* d_out, int out_size, void* d_ws, size_t ws_size,
                              hipStream_t stream)
{
  const float* u   = (const float*)d_in[0];   // 8192 x 256
  const float* x0  = (const float*)d_in[1];   // 8192 x 512
  const float* X   = (const float*)d_in[2];   // 1536 x 1536
  const float* Y   = (const float*)d_in[3];   // 512 x 512
  const float* B2  = (const float*)d_in[4];   // 512 x 256
  const float* C2  = (const float*)d_in[5];   // 256 x 512
  const float* D21 = (const float*)d_in[6];   // 256 x 512
  const float* D22 = (const float*)d_in[7];   // 256 x 256
  const float* D12 = (const float*)d_in[8];   // 512 x 256
  float* out = (float*)d_out;
  float* ws = (float*)d_ws;

  float* E    = ws + 0;
  float* T0   = ws + 262144;
  float* T1   = ws + 524288;
  float* Q0   = ws + 786432;
  float* Q1   = ws + 917504;
  float* C1   = ws + 1048576;
  float* D11  = ws + 1310720;
  float* Fm   = ws + 1572864;
  float* B1   = ws + 1835008;
  float* P1   = ws + 2097152;
  float* P2   = ws + 2228224;
  float* P3   = ws + 2359296;
  float* Lam  = ws + 2424832;
  int*   flag = (int*)(ws + 2425344);
  float* D11T = ws + 2425472;
  float* abuf = ws + 2687616;                 // 8192x512 f32
  ushort* uh  = (ushort*)(ws + 6881920);      // 8192x256
  ushort* ul  = (ushort*)(ws + 7930496);
  ushort* wh  = (ushort*)(ws + 8979072);      // 8192x512
  ushort* wl  = (ushort*)(ws + 11076224);
  ushort* D12h = (ushort*)(ws + 13173376);    // 512x256
  ushort* D12l = (ushort*)(ws + 13238912);
  ushort* P2h = (ushort*)(ws + 13304448);     // 256x512
  ushort* P2l = (ushort*)(ws + 13369984);
  ushort* P3h = (ushort*)(ws + 13435520);     // 256x256
  ushort* P3l = (ushort*)(ws + 13468288);

  hipMemsetAsync(flag, 0, 4, stream);
  k_anynz<<<256, 256, 0, stream>>>(x0, 8192 * 512 / 4, flag);

  // H = X^T X needed blocks
  k_xtx5<<<dim3(16, 16, 5), 256, 0, stream>>>(X, Y, E, C1, D11, D11T, Fm, B1, Lam);

  // split u and D12 to bf16 hi/lo
  k_split2<<<2048, 256, 0, stream>>>(u, uh, ul, 524288, D12, D12h, D12l, 32768);

  // abuf = u @ D12^T (MFMA, 3-pass split-bf16); + x0 @ C1^T if flag
  k_ntm<1><<<dim3(128, 8), 256, 0, stream>>>(uh, ul, D12h, D12l, 256,
                                             nullptr, nullptr, nullptr, nullptr, 0,
                                             abuf, 512);
  k_ntadd<<<dim3(128, 8), 256, 0, stream>>>(x0, C1, 512, flag, abuf, 512);

  // Newton-Schulz on (T, Q)
  k_nsinit<<<384, 256, 0, stream>>>(E, C2, T0, Q0);
  float *Ta = T0, *Tb = T1, *Qa = Q0, *Qb = Q1;
  for (int it = 0; it < 5; ++it) {
    k_ns<true><<<dim3(16, 24), 256, 0, stream>>>(Ta, Qa, Tb, Qb);
    float* tp = Ta; Ta = Tb; Tb = tp;
    float* qp = Qa; Qa = Qb; Qb = qp;
  }
  k_ns<false><<<dim3(16, 8), 256, 0, stream>>>(Ta, Qa, nullptr, Qb);
  float* Q = Qb;

  // folds
  k_fold<<<dim3(16, 8, 3), 256, 0, stream>>>(Q, Fm, B1, B2, D21, D22, P1, P2, P3);
  k_split2<<<192, 256, 0, stream>>>(P2, P2h, P2l, 32768, P3, P3h, P3l, 16384);

  // scan -> w (bf16 hi/lo)
  k_scan<<<512, 512, 0, stream>>>(abuf, D11, D11T, Lam, wh, wl);

  // y = w @ P2^T + u @ P3^T (MFMA); + x0 @ P1^T if flag
  k_ntm<2><<<dim3(128, 4), 256, 0, stream>>>(wh, wl, P2h, P2l, 512,
                                             uh, ul, P3h, P3l, 256,
                                             out, 256);
  k_ntadd<<<dim3(128, 4), 256, 0, stream>>>(x0, P1, 512, flag, out, 256);
}

// Round 5
// 438.674 us; speedup vs baseline: 2.4946x; 1.2737x over previous
//
#include <hip/hip_runtime.h>
#include <cstdint>
#include <cstddef>

#define EPSC 0.001f

typedef __attribute__((ext_vector_type(8))) short short8;
typedef __attribute__((ext_vector_type(4))) float f32x4;

__device__ inline void bsplit(float f, ushort& h, ushort& l) {
  uint b = __float_as_uint(f);
  h = (ushort)(b >> 16);
  float r = f - __uint_as_float(b & 0xFFFF0000u);
  l = (ushort)(__float_as_uint(r) >> 16);
}

// ---------------------------------------------------------------- any-nonzero
__global__ void k_anynz(const float* __restrict__ x, int n4, int* __restrict__ flag) {
  int i = blockIdx.x * blockDim.x + threadIdx.x;
  int stride = gridDim.x * blockDim.x;
  int found = 0;
  for (; i < n4; i += stride) {
    float4 v = ((const float4*)x)[i];
    if (v.x != 0.f || v.y != 0.f || v.z != 0.f || v.w != 0.f) { found = 1; break; }
  }
  if (found) atomicOr(flag, 1);
}

// ---------------------------------------------------------------- transpose + bf16 split: dst[C x R] = src[R x C]^T
__global__ __launch_bounds__(256) void k_tsplit(const float* __restrict__ src,
    ushort* __restrict__ dh, ushort* __restrict__ dl, int R, int C)
{
  __shared__ float t[32][33];
  const int c0 = blockIdx.x * 32, r0 = blockIdx.y * 32;
  const int tid = threadIdx.x;
  const int lr = tid >> 3, lc4 = (tid & 7) * 4;
  float4 v = *(const float4*)(src + (size_t)(r0 + lr) * C + c0 + lc4);
  t[lr][lc4 + 0] = v.x; t[lr][lc4 + 1] = v.y;
  t[lr][lc4 + 2] = v.z; t[lr][lc4 + 3] = v.w;
  __syncthreads();
  ushort4 hv, lv;
  float f;
  f = t[lc4 + 0][lr]; bsplit(f, hv.x, lv.x);
  f = t[lc4 + 1][lr]; bsplit(f, hv.y, lv.y);
  f = t[lc4 + 2][lr]; bsplit(f, hv.z, lv.z);
  f = t[lc4 + 3][lr]; bsplit(f, hv.w, lv.w);
  size_t off = (size_t)(c0 + lr) * R + r0 + lc4;
  *(ushort4*)(dh + off) = hv;
  *(ushort4*)(dl + off) = lv;
}

// ---------------------------------------------------------------- plain bf16 split (2 segments)
__global__ void k_split2(const float* __restrict__ s0, ushort* __restrict__ h0,
                         ushort* __restrict__ l0, int c0,
                         const float* __restrict__ s1, ushort* __restrict__ h1,
                         ushort* __restrict__ l1, int c1)
{
  int i = blockIdx.x * 256 + threadIdx.x;
  int tot = c0 + c1;
  int stride = gridDim.x * 256;
  for (; i < tot; i += stride) {
    const float* s; ushort* h; ushort* l; int k;
    if (i < c0) { s = s0; h = h0; l = l0; k = i; }
    else        { s = s1; h = h1; l = l1; k = i - c0; }
    float4 v = ((const float4*)s)[k];
    ushort4 hv, lv;
    bsplit(v.x, hv.x, lv.x);
    bsplit(v.y, hv.y, lv.y);
    bsplit(v.z, hv.z, lv.z);
    bsplit(v.w, hv.w, lv.w);
    ((ushort4*)h)[k] = hv;
    ((ushort4*)l)[k] = lv;
  }
}

// ---------------------------------------------------------------- MFMA XtX: 6 H-blocks from Xt splits
// z=0: E=0.5(H11+H33+Y-Y^T)+epsI ; z=1: C1=-H21 ; z=2: D11/D11T/Lam ;
// z=3: FmT=H13 (hi/lo) ; z=4: B1T=H23 (hi/lo)
__global__ __launch_bounds__(256) void k_xtxm(
    const ushort* __restrict__ Xth, const ushort* __restrict__ Xtl,
    const float* __restrict__ Y,
    float* __restrict__ E, float* __restrict__ C1,
    float* __restrict__ D11, float* __restrict__ D11T, float* __restrict__ Lam,
    ushort* __restrict__ FmTh, ushort* __restrict__ FmTl,
    ushort* __restrict__ B1Th, ushort* __restrict__ B1Tl)
{
  __shared__ ushort sAh[64][40], sAl[64][40], sBh[64][40], sBl[64][40];
  const int z = blockIdx.z;
  int aOff[2], bOff[2], nops;
  switch (z) {
    case 0:  aOff[0] = 0;    bOff[0] = 0;    aOff[1] = 1024; bOff[1] = 1024; nops = 2; break;
    case 1:  aOff[0] = 512;  bOff[0] = 0;    nops = 1; break;
    case 2:  aOff[0] = 512;  bOff[0] = 512;  nops = 1; break;
    case 3:  aOff[0] = 0;    bOff[0] = 1024; nops = 1; break;
    default: aOff[0] = 512;  bOff[0] = 1024; nops = 1; break;
  }
  const int tid = threadIdx.x;
  const int m0 = blockIdx.x * 64, n0 = blockIdx.y * 64;
  const int wid = tid >> 6, lane = tid & 63;
  const int wr = wid >> 1, wc = wid & 1;
  const int fr = lane & 15, fg = lane >> 4;
  const int srow = tid >> 2;
  const int sko = (tid & 3) * 8;
  f32x4 acc[2][2] = {};
  const int K = 1536;

  for (int op = 0; op < nops; ++op) {
    const ushort* Ah = Xth + (size_t)(aOff[op]) * K;
    const ushort* Al = Xtl + (size_t)(aOff[op]) * K;
    const ushort* Bh = Xth + (size_t)(bOff[op]) * K;
    const ushort* Bl = Xtl + (size_t)(bOff[op]) * K;
    uint4 pah = *(const uint4*)(Ah + (size_t)(m0 + srow) * K + sko);
    uint4 pal = *(const uint4*)(Al + (size_t)(m0 + srow) * K + sko);
    uint4 pbh = *(const uint4*)(Bh + (size_t)(n0 + srow) * K + sko);
    uint4 pbl = *(const uint4*)(Bl + (size_t)(n0 + srow) * K + sko);
    for (int k0 = 0; k0 < K; k0 += 32) {
      __syncthreads();
      *(uint4*)&sAh[srow][sko] = pah;
      *(uint4*)&sAl[srow][sko] = pal;
      *(uint4*)&sBh[srow][sko] = pbh;
      *(uint4*)&sBl[srow][sko] = pbl;
      __syncthreads();
      if (k0 + 32 < K) {
        pah = *(const uint4*)(Ah + (size_t)(m0 + srow) * K + k0 + 32 + sko);
        pal = *(const uint4*)(Al + (size_t)(m0 + srow) * K + k0 + 32 + sko);
        pbh = *(const uint4*)(Bh + (size_t)(n0 + srow) * K + k0 + 32 + sko);
        pbl = *(const uint4*)(Bl + (size_t)(n0 + srow) * K + k0 + 32 + sko);
      }
      short8 fah[2], fal[2], fbh[2], fbl[2];
#pragma unroll
      for (int s = 0; s < 2; ++s) {
        fah[s] = *(const short8*)&sAh[wr * 32 + s * 16 + fr][fg * 8];
        fal[s] = *(const short8*)&sAl[wr * 32 + s * 16 + fr][fg * 8];
        fbh[s] = *(const short8*)&sBh[wc * 32 + s * 16 + fr][fg * 8];
        fbl[s] = *(const short8*)&sBl[wc * 32 + s * 16 + fr][fg * 8];
      }
#pragma unroll
      for (int i = 0; i < 2; ++i)
#pragma unroll
        for (int j = 0; j < 2; ++j) {
          acc[i][j] = __builtin_amdgcn_mfma_f32_16x16x32_bf16(fah[i], fbh[j], acc[i][j], 0, 0, 0);
          acc[i][j] = __builtin_amdgcn_mfma_f32_16x16x32_bf16(fah[i], fbl[j], acc[i][j], 0, 0, 0);
          acc[i][j] = __builtin_amdgcn_mfma_f32_16x16x32_bf16(fal[i], fbh[j], acc[i][j], 0, 0, 0);
        }
    }
  }

#pragma unroll
  for (int i = 0; i < 2; ++i)
#pragma unroll
    for (int j = 0; j < 2; ++j) {
      int rbase = m0 + wr * 32 + i * 16 + fg * 4;
      int cc = n0 + wc * 32 + j * 16 + fr;
#pragma unroll
      for (int q = 0; q < 4; ++q) {
        int rr = rbase + q;
        float d = acc[i][j][q];
        size_t idx = (size_t)rr * 512 + cc;
        if (z == 0) {
          float o = 0.5f * (d + Y[idx] - Y[(size_t)cc * 512 + rr]);
          if (rr == cc) o += EPSC;
          E[idx] = o;
        } else if (z == 1) {
          C1[idx] = -d;
        } else if (z == 2) {
          float o = (cc < rr) ? -d : 0.f;
          D11[idx] = o;
          D11T[(size_t)cc * 512 + rr] = o;
          if (rr == cc) Lam[rr] = 0.5f * (d + EPSC);
        } else if (z == 3) {
          ushort h, l; bsplit(d, h, l);
          FmTh[idx] = h; FmTl[idx] = l;
        } else {
          ushort h, l; bsplit(d, h, l);
          B1Th[idx] = h; B1Tl[idx] = l;
        }
      }
    }
}

// ---------------------------------------------------------------- NS init: T0=E*diag(s), Q0=C2*diag(s), s=0.85/diag(E)
__global__ void k_nsinit(const float* __restrict__ E, const float* __restrict__ C2,
    float* __restrict__ Tf, ushort* __restrict__ Th, ushort* __restrict__ Tl,
    ushort* __restrict__ Tth, ushort* __restrict__ Ttl,
    float* __restrict__ Qf, ushort* __restrict__ Qh, ushort* __restrict__ Ql)
{
  int g = blockIdx.x * 256 + threadIdx.x;   // 768 rows x 128 quads
  int row = g >> 7;
  int c4 = (g & 127) << 2;
  float s0 = 0.85f / E[(size_t)(c4 + 0) * 513];
  float s1 = 0.85f / E[(size_t)(c4 + 1) * 513];
  float s2 = 0.85f / E[(size_t)(c4 + 2) * 513];
  float s3 = 0.85f / E[(size_t)(c4 + 3) * 513];
  if (row < 512) {
    float4 v = *(const float4*)(E + (size_t)row * 512 + c4);
    v.x *= s0; v.y *= s1; v.z *= s2; v.w *= s3;
    *(float4*)(Tf + (size_t)row * 512 + c4) = v;
    ushort4 hv, lv;
    bsplit(v.x, hv.x, lv.x); bsplit(v.y, hv.y, lv.y);
    bsplit(v.z, hv.z, lv.z); bsplit(v.w, hv.w, lv.w);
    *(ushort4*)(Th + (size_t)row * 512 + c4) = hv;
    *(ushort4*)(Tl + (size_t)row * 512 + c4) = lv;
    Tth[(size_t)(c4 + 0) * 512 + row] = hv.x; Ttl[(size_t)(c4 + 0) * 512 + row] = lv.x;
    Tth[(size_t)(c4 + 1) * 512 + row] = hv.y; Ttl[(size_t)(c4 + 1) * 512 + row] = lv.y;
    Tth[(size_t)(c4 + 2) * 512 + row] = hv.z; Ttl[(size_t)(c4 + 2) * 512 + row] = lv.z;
    Tth[(size_t)(c4 + 3) * 512 + row] = hv.w; Ttl[(size_t)(c4 + 3) * 512 + row] = lv.w;
  } else {
    int qr = row - 512;
    float4 v = *(const float4*)(C2 + (size_t)qr * 512 + c4);
    v.x *= s0; v.y *= s1; v.z *= s2; v.w *= s3;
    *(float4*)(Qf + (size_t)qr * 512 + c4) = v;
    ushort4 hv, lv;
    bsplit(v.x, hv.x, lv.x); bsplit(v.y, hv.y, lv.y);
    bsplit(v.z, hv.z, lv.z); bsplit(v.w, hv.w, lv.w);
    *(ushort4*)(Qh + (size_t)qr * 512 + c4) = hv;
    *(ushort4*)(Ql + (size_t)qr * 512 + c4) = lv;
  }
}

// ---------------------------------------------------------------- MFMA NS step: Tn=2T-T*T ; Qn=2Q-Q*T (NT vs Tt splits)
template <bool WITH_T>
__global__ __launch_bounds__(256) void k_nsm(
    const ushort* __restrict__ Th, const ushort* __restrict__ Tl,
    const ushort* __restrict__ Tth, const ushort* __restrict__ Ttl,
    const ushort* __restrict__ Qh, const ushort* __restrict__ Ql,
    const float* __restrict__ Tprev, const float* __restrict__ Qprev,
    float* __restrict__ Tnext, ushort* __restrict__ Thn, ushort* __restrict__ Tln,
    ushort* __restrict__ Tthn, ushort* __restrict__ Ttln,
    float* __restrict__ Qnext, ushort* __restrict__ Qhn, ushort* __restrict__ Qln)
{
  __shared__ ushort sAh[64][40], sAl[64][40], sBh[64][40], sBl[64][40];
  const int tid = threadIdx.x;
  const int yy = blockIdx.y;
  const bool isT = WITH_T && (yy < 8);
  const int m0 = (isT ? yy : (yy - (WITH_T ? 8 : 0))) * 64;
  const int n0 = blockIdx.x * 64;
  const ushort* Ah = isT ? Th : Qh;
  const ushort* Al = isT ? Tl : Ql;
  const int wid = tid >> 6, lane = tid & 63;
  const int wr = wid >> 1, wc = wid & 1;
  const int fr = lane & 15, fg = lane >> 4;
  const int srow = tid >> 2;
  const int sko = (tid & 3) * 8;
  const int K = 512;
  f32x4 acc[2][2] = {};

  uint4 pah = *(const uint4*)(Ah + (size_t)(m0 + srow) * K + sko);
  uint4 pal = *(const uint4*)(Al + (size_t)(m0 + srow) * K + sko);
  uint4 pbh = *(const uint4*)(Tth + (size_t)(n0 + srow) * K + sko);
  uint4 pbl = *(const uint4*)(Ttl + (size_t)(n0 + srow) * K + sko);
  for (int k0 = 0; k0 < K; k0 += 32) {
    __syncthreads();
    *(uint4*)&sAh[srow][sko] = pah;
    *(uint4*)&sAl[srow][sko] = pal;
    *(uint4*)&sBh[srow][sko] = pbh;
    *(uint4*)&sBl[srow][sko] = pbl;
    __syncthreads();
    if (k0 + 32 < K) {
      pah = *(const uint4*)(Ah + (size_t)(m0 + srow) * K + k0 + 32 + sko);
      pal = *(const uint4*)(Al + (size_t)(m0 + srow) * K + k0 + 32 + sko);
      pbh = *(const uint4*)(Tth + (size_t)(n0 + srow) * K + k0 + 32 + sko);
      pbl = *(const uint4*)(Ttl + (size_t)(n0 + srow) * K + k0 + 32 + sko);
    }
    short8 fah[2], fal[2], fbh[2], fbl[2];
#pragma unroll
    for (int s = 0; s < 2; ++s) {
      fah[s] = *(const short8*)&sAh[wr * 32 + s * 16 + fr][fg * 8];
      fal[s] = *(const short8*)&sAl[wr * 32 + s * 16 + fr][fg * 8];
      fbh[s] = *(const short8*)&sBh[wc * 32 + s * 16 + fr][fg * 8];
      fbl[s] = *(const short8*)&sBl[wc * 32 + s * 16 + fr][fg * 8];
    }
#pragma unroll
    for (int i = 0; i < 2; ++i)
#pragma unroll
      for (int j = 0; j < 2; ++j) {
        acc[i][j] = __builtin_amdgcn_mfma_f32_16x16x32_bf16(fah[i], fbh[j], acc[i][j], 0, 0, 0);
        acc[i][j] = __builtin_amdgcn_mfma_f32_16x16x32_bf16(fah[i], fbl[j], acc[i][j], 0, 0, 0);
        acc[i][j] = __builtin_amdgcn_mfma_f32_16x16x32_bf16(fal[i], fbh[j], acc[i][j], 0, 0, 0);
      }
  }

#pragma unroll
  for (int i = 0; i < 2; ++i)
#pragma unroll
    for (int j = 0; j < 2; ++j) {
      int rbase = m0 + wr * 32 + i * 16 + fg * 4;
      int cc = n0 + wc * 32 + j * 16 + fr;
#pragma unroll
      for (int q = 0; q < 4; ++q) {
        int rr = rbase + q;
        size_t idx = (size_t)rr * 512 + cc;
        ushort h, l;
        if (isT) {
          float tn = 2.f * Tprev[idx] - acc[i][j][q];
          Tnext[idx] = tn;
          bsplit(tn, h, l);
          Thn[idx] = h; Tln[idx] = l;
          Tthn[(size_t)cc * 512 + rr] = h; Ttln[(size_t)cc * 512 + rr] = l;
        } else {
          float qn = 2.f * Qprev[idx] - acc[i][j][q];
          Qnext[idx] = qn;
          bsplit(qn, h, l);
          Qhn[idx] = h; Qln[idx] = l;
        }
      }
    }
}

// ---------------------------------------------------------------- MFMA folds: P1=Q*Fm (fp32) ; P2=Q*B1+D21 (h/l) ; P3=Q*B2+D22 (h/l)
__global__ __launch_bounds__(256) void k_foldm(
    const ushort* __restrict__ Qh, const ushort* __restrict__ Ql,
    const ushort* __restrict__ FmTh, const ushort* __restrict__ FmTl,
    const ushort* __restrict__ B1Th, const ushort* __restrict__ B1Tl,
    const ushort* __restrict__ B2Th, const ushort* __restrict__ B2Tl,
    const float* __restrict__ D21, const float* __restrict__ D22,
    float* __restrict__ P1, ushort* __restrict__ P2h, ushort* __restrict__ P2l,
    ushort* __restrict__ P3h, ushort* __restrict__ P3l)
{
  __shared__ ushort sAh[64][40], sAl[64][40], sBh[64][40], sBl[64][40];
  const int z = blockIdx.z;
  const int N = (z == 2) ? 256 : 512;
  const int n0 = blockIdx.x * 64;
  if (n0 >= N) return;
  const ushort* Bh = (z == 0) ? FmTh : (z == 1) ? B1Th : B2Th;
  const ushort* Bl = (z == 0) ? FmTl : (z == 1) ? B1Tl : B2Tl;
  const int tid = threadIdx.x;
  const int m0 = blockIdx.y * 64;
  const int wid = tid >> 6, lane = tid & 63;
  const int wr = wid >> 1, wc = wid & 1;
  const int fr = lane & 15, fg = lane >> 4;
  const int srow = tid >> 2;
  const int sko = (tid & 3) * 8;
  const int K = 512;
  f32x4 acc[2][2] = {};

  uint4 pah = *(const uint4*)(Qh + (size_t)(m0 + srow) * K + sko);
  uint4 pal = *(const uint4*)(Ql + (size_t)(m0 + srow) * K + sko);
  uint4 pbh = *(const uint4*)(Bh + (size_t)(n0 + srow) * K + sko);
  uint4 pbl = *(const uint4*)(Bl + (size_t)(n0 + srow) * K + sko);
  for (int k0 = 0; k0 < K; k0 += 32) {
    __syncthreads();
    *(uint4*)&sAh[srow][sko] = pah;
    *(uint4*)&sAl[srow][sko] = pal;
    *(uint4*)&sBh[srow][sko] = pbh;
    *(uint4*)&sBl[srow][sko] = pbl;
    __syncthreads();
    if (k0 + 32 < K) {
      pah = *(const uint4*)(Qh + (size_t)(m0 + srow) * K + k0 + 32 + sko);
      pal = *(const uint4*)(Ql + (size_t)(m0 + srow) * K + k0 + 32 + sko);
      pbh = *(const uint4*)(Bh + (size_t)(n0 + srow) * K + k0 + 32 + sko);
      pbl = *(const uint4*)(Bl + (size_t)(n0 + srow) * K + k0 + 32 + sko);
    }
    short8 fah[2], fal[2], fbh[2], fbl[2];
#pragma unroll
    for (int s = 0; s < 2; ++s) {
      fah[s] = *(const short8*)&sAh[wr * 32 + s * 16 + fr][fg * 8];
      fal[s] = *(const short8*)&sAl[wr * 32 + s * 16 + fr][fg * 8];
      fbh[s] = *(const short8*)&sBh[wc * 32 + s * 16 + fr][fg * 8];
      fbl[s] = *(const short8*)&sBl[wc * 32 + s * 16 + fr][fg * 8];
    }
#pragma unroll
    for (int i = 0; i < 2; ++i)
#pragma unroll
      for (int j = 0; j < 2; ++j) {
        acc[i][j] = __builtin_amdgcn_mfma_f32_16x16x32_bf16(fah[i], fbh[j], acc[i][j], 0, 0, 0);
        acc[i][j] = __builtin_amdgcn_mfma_f32_16x16x32_bf16(fah[i], fbl[j], acc[i][j], 0, 0, 0);
        acc[i][j] = __builtin_amdgcn_mfma_f32_16x16x32_bf16(fal[i], fbh[j], acc[i][j], 0, 0, 0);
      }
  }

#pragma unroll
  for (int i = 0; i < 2; ++i)
#pragma unroll
    for (int j = 0; j < 2; ++j) {
      int rbase = m0 + wr * 32 + i * 16 + fg * 4;
      int cc = n0 + wc * 32 + j * 16 + fr;
#pragma unroll
      for (int q = 0; q < 4; ++q) {
        int rr = rbase + q;
        float d = acc[i][j][q];
        if (z == 0) {
          P1[(size_t)rr * 512 + cc] = d;
        } else if (z == 1) {
          size_t idx = (size_t)rr * 512 + cc;
          float p = d + D21[idx];
          ushort h, l; bsplit(p, h, l);
          P2h[idx] = h; P2l[idx] = l;
        } else {
          size_t idx = (size_t)rr * 256 + cc;
          float p = d + D22[idx];
          ushort h, l; bsplit(p, h, l);
          P3h[idx] = h; P3l[idx] = l;
        }
      }
    }
}

// ---------------------------------------------------------------- MFMA NT GEMM, split-bf16 3-pass (batch)
template <int NOPS>
__global__ __launch_bounds__(256) void k_ntm(
    const ushort* __restrict__ Ah0, const ushort* __restrict__ Al0,
    const ushort* __restrict__ Bh0, const ushort* __restrict__ Bl0, int K0,
    const ushort* __restrict__ Ah1, const ushort* __restrict__ Al1,
    const ushort* __restrict__ Bh1, const ushort* __restrict__ Bl1, int K1,
    float* __restrict__ C, int ldc)
{
  __shared__ ushort sAh[64][40], sAl[64][40], sBh[64][40], sBl[64][40];
  const int tid = threadIdx.x;
  const int m0 = blockIdx.x * 64, n0 = blockIdx.y * 64;
  const int wid = tid >> 6, lane = tid & 63;
  const int wr = wid >> 1, wc = wid & 1;
  const int fr = lane & 15, fg = lane >> 4;
  const int srow = tid >> 2;
  const int sko = (tid & 3) * 8;
  f32x4 acc[2][2] = {};

#pragma unroll
  for (int op = 0; op < NOPS; ++op) {
    const ushort* Ah = (op == 0) ? Ah0 : Ah1;
    const ushort* Al = (op == 0) ? Al0 : Al1;
    const ushort* Bh = (op == 0) ? Bh0 : Bh1;
    const ushort* Bl = (op == 0) ? Bl0 : Bl1;
    const int K = (op == 0) ? K0 : K1;
    uint4 pah = *(const uint4*)(Ah + (size_t)(m0 + srow) * K + sko);
    uint4 pal = *(const uint4*)(Al + (size_t)(m0 + srow) * K + sko);
    uint4 pbh = *(const uint4*)(Bh + (size_t)(n0 + srow) * K + sko);
    uint4 pbl = *(const uint4*)(Bl + (size_t)(n0 + srow) * K + sko);
    for (int k0 = 0; k0 < K; k0 += 32) {
      __syncthreads();
      *(uint4*)&sAh[srow][sko] = pah;
      *(uint4*)&sAl[srow][sko] = pal;
      *(uint4*)&sBh[srow][sko] = pbh;
      *(uint4*)&sBl[srow][sko] = pbl;
      __syncthreads();
      if (k0 + 32 < K) {
        pah = *(const uint4*)(Ah + (size_t)(m0 + srow) * K + k0 + 32 + sko);
        pal = *(const uint4*)(Al + (size_t)(m0 + srow) * K + k0 + 32 + sko);
        pbh = *(const uint4*)(Bh + (size_t)(n0 + srow) * K + k0 + 32 + sko);
        pbl = *(const uint4*)(Bl + (size_t)(n0 + srow) * K + k0 + 32 + sko);
      }
      short8 fah[2], fal[2], fbh[2], fbl[2];
#pragma unroll
      for (int s = 0; s < 2; ++s) {
        fah[s] = *(const short8*)&sAh[wr * 32 + s * 16 + fr][fg * 8];
        fal[s] = *(const short8*)&sAl[wr * 32 + s * 16 + fr][fg * 8];
        fbh[s] = *(const short8*)&sBh[wc * 32 + s * 16 + fr][fg * 8];
        fbl[s] = *(const short8*)&sBl[wc * 32 + s * 16 + fr][fg * 8];
      }
#pragma unroll
      for (int i = 0; i < 2; ++i)
#pragma unroll
        for (int j = 0; j < 2; ++j) {
          acc[i][j] = __builtin_amdgcn_mfma_f32_16x16x32_bf16(fah[i], fbh[j], acc[i][j], 0, 0, 0);
          acc[i][j] = __builtin_amdgcn_mfma_f32_16x16x32_bf16(fah[i], fbl[j], acc[i][j], 0, 0, 0);
          acc[i][j] = __builtin_amdgcn_mfma_f32_16x16x32_bf16(fal[i], fbh[j], acc[i][j], 0, 0, 0);
        }
    }
  }

#pragma unroll
  for (int i = 0; i < 2; ++i)
#pragma unroll
    for (int j = 0; j < 2; ++j) {
      int rr = m0 + wr * 32 + i * 16 + fg * 4;
      int cc = n0 + wc * 32 + j * 16 + fr;
#pragma unroll
      for (int q = 0; q < 4; ++q)
        C[(size_t)(rr + q) * ldc + cc] = acc[i][j][q];
    }
}

// ---------------------------------------------------------------- flag-gated fp32 NT accumulate (x0 terms)
__global__ __launch_bounds__(256) void k_ntadd(const float* __restrict__ A,
    const float* __restrict__ B, int K, const int* __restrict__ flag,
    float* __restrict__ C, int ldc)
{
  if (*flag == 0) return;
  __shared__ float As[16][68];
  __shared__ float Bs[16][68];
  const int tid = threadIdx.x;
  const int tx = tid & 15, ty = tid >> 4;
  const int m0 = blockIdx.x * 64, n0 = blockIdx.y * 64;
  const int lr = tid >> 2;
  const int lk = (tid & 3) * 4;
  float acc[4][4];
#pragma unroll
  for (int i = 0; i < 4; ++i)
#pragma unroll
    for (int j = 0; j < 4; ++j) acc[i][j] = 0.f;
  float4 av = *(const float4*)(A + (size_t)(m0 + lr) * K + lk);
  float4 bv = *(const float4*)(B + (size_t)(n0 + lr) * K + lk);
  for (int k0 = 0; k0 < K; k0 += 16) {
    __syncthreads();
    As[lk + 0][lr] = av.x; As[lk + 1][lr] = av.y;
    As[lk + 2][lr] = av.z; As[lk + 3][lr] = av.w;
    Bs[lk + 0][lr] = bv.x; Bs[lk + 1][lr] = bv.y;
    Bs[lk + 2][lr] = bv.z; Bs[lk + 3][lr] = bv.w;
    __syncthreads();
    if (k0 + 16 < K) {
      av = *(const float4*)(A + (size_t)(m0 + lr) * K + k0 + 16 + lk);
      bv = *(const float4*)(B + (size_t)(n0 + lr) * K + k0 + 16 + lk);
    }
#pragma unroll
    for (int kk = 0; kk < 16; ++kk) {
      float4 a4 = *(const float4*)&As[kk][4 * ty];
      float4 b4 = *(const float4*)&Bs[kk][4 * tx];
      float ar[4] = {a4.x, a4.y, a4.z, a4.w};
      float br[4] = {b4.x, b4.y, b4.z, b4.w};
#pragma unroll
      for (int i = 0; i < 4; ++i)
#pragma unroll
        for (int j = 0; j < 4; ++j)
          acc[i][j] = fmaf(ar[i], br[j], acc[i][j]);
    }
  }
#pragma unroll
  for (int i = 0; i < 4; ++i) {
    float* p = C + (size_t)(m0 + 4 * ty + i) * ldc + n0 + 4 * tx;
    float4 v = *(float4*)p;
    v.x += acc[i][0]; v.y += acc[i][1]; v.z += acc[i][2]; v.w += acc[i][3];
    *(float4*)p = v;
  }
}

// ---------------------------------------------------------------- blocked tanh scan (v4: pipelined history)
__global__ __launch_bounds__(512, 4) void k_scan(const float* __restrict__ a,
    const float* __restrict__ D11, const float* __restrict__ D11T,
    const float* __restrict__ Lam, ushort* __restrict__ wh, ushort* __restrict__ wl)
{
  __shared__ float wt[512][17];
  __shared__ float sblk[32][17];
  __shared__ float shist[6][32][17];
  __shared__ float dblkT[2][32][33];
  __shared__ float doff[32][33];
  __shared__ float ablk[32][17];
  __shared__ float rl2[512];
  const int tid = threadIdx.x;
  const int row0 = blockIdx.x * 16;

  rl2[tid] = 2.f / Lam[tid];
  if (tid < 128) {
    int rr = tid >> 3, cq = (tid & 7) * 4;
    float4 v = *(const float4*)(a + (size_t)(row0 + rr) * 512 + cq);
    sblk[cq + 0][rr] = v.x; sblk[cq + 1][rr] = v.y;
    sblk[cq + 2][rr] = v.z; sblk[cq + 3][rr] = v.w;
  } else if (tid < 384) {
    int f = tid - 128;
    int rr = f >> 3, cq = (f & 7) * 4;
    float4 v = *(const float4*)(D11 + (size_t)rr * 512 + cq);
    dblkT[0][cq + 0][rr] = v.x; dblkT[0][cq + 1][rr] = v.y;
    dblkT[0][cq + 2][rr] = v.z; dblkT[0][cq + 3][rr] = v.w;
  }
  __syncthreads();

  for (int t = 0; t < 16; ++t) {
    const int wv = tid >> 6;
    const int lane = tid & 63;
    const int c0 = 32 * t;
    const int jend2 = 32 * (t + 1);
    if (wv == 0) {
      if (lane < 16) {
        float s[32];
#pragma unroll
        for (int il = 0; il < 32; ++il) s[il] = sblk[il][lane];
#pragma unroll
        for (int il = 0; il < 32; ++il) {
          float x2 = s[il] * rl2[c0 + il];
          float e = __expf(x2);
          float wv2 = 1.f - 2.f * __builtin_amdgcn_rcpf(e + 1.f);
          wt[c0 + il][lane] = wv2;
#pragma unroll
          for (int j2 = il + 1; j2 < 32; ++j2)
            s[j2] = fmaf(dblkT[t & 1][il][j2], wv2, s[j2]);
        }
      }
    } else if (wv <= 6) {
      if (t < 15) {
        const int r = lane & 15;
        const int il0 = (lane >> 4) * 8;
        const int n = c0;
        float acc[8] = {0.f, 0.f, 0.f, 0.f, 0.f, 0.f, 0.f, 0.f};
        for (int j0 = (wv - 1) * 4; j0 < n; j0 += 24) {
          float4 d[4][2];
          float wj4[4];
#pragma unroll
          for (int q = 0; q < 4; ++q) {
            int j = j0 + q;
            int jc = (j < n) ? j : 0;
            const float* dp = D11T + (size_t)jc * 512 + jend2 + il0;
            d[q][0] = *(const float4*)dp;
            d[q][1] = *(const float4*)(dp + 4);
            wj4[q] = (j < n) ? wt[j][r] : 0.f;
          }
#pragma unroll
          for (int q = 0; q < 4; ++q) {
            acc[0] = fmaf(d[q][0].x, wj4[q], acc[0]);
            acc[1] = fmaf(d[q][0].y, wj4[q], acc[1]);
            acc[2] = fmaf(d[q][0].z, wj4[q], acc[2]);
            acc[3] = fmaf(d[q][0].w, wj4[q], acc[3]);
            acc[4] = fmaf(d[q][1].x, wj4[q], acc[4]);
            acc[5] = fmaf(d[q][1].y, wj4[q], acc[5]);
            acc[6] = fmaf(d[q][1].z, wj4[q], acc[6]);
            acc[7] = fmaf(d[q][1].w, wj4[q], acc[7]);
          }
        }
#pragma unroll
        for (int k = 0; k < 8; ++k) shist[wv - 1][il0 + k][r] = acc[k];
      }
    } else {
      if (t < 15) {
#pragma unroll
        for (int e = 0; e < 4; ++e) {
          int f = lane + 64 * e;
          int rr = f >> 3, cq = (f & 7) * 4;
          float4 v = *(const float4*)(D11 + (size_t)(jend2 + rr) * 512 + c0 + cq);
          doff[rr][cq + 0] = v.x; doff[rr][cq + 1] = v.y;
          doff[rr][cq + 2] = v.z; doff[rr][cq + 3] = v.w;
          float4 v2 = *(const float4*)(D11 + (size_t)(jend2 + rr) * 512 + jend2 + cq);
          dblkT[(t + 1) & 1][cq + 0][rr] = v2.x; dblkT[(t + 1) & 1][cq + 1][rr] = v2.y;
          dblkT[(t + 1) & 1][cq + 2][rr] = v2.z; dblkT[(t + 1) & 1][cq + 3][rr] = v2.w;
        }
#pragma unroll
        for (int e = 0; e < 2; ++e) {
          int f = lane + 64 * e;
          int rr = f >> 3, cq = (f & 7) * 4;
          float4 v = *(const float4*)(a + (size_t)(row0 + rr) * 512 + jend2 + cq);
          ablk[cq + 0][rr] = v.x; ablk[cq + 1][rr] = v.y;
          ablk[cq + 2][rr] = v.z; ablk[cq + 3][rr] = v.w;
        }
      }
    }
    __syncthreads();
    if (t < 15) {
      const int il = tid >> 4, r2 = tid & 15;
      float s = ablk[il][r2];
#pragma unroll
      for (int k = 0; k < 6; ++k) s += shist[k][il][r2];
#pragma unroll 8
      for (int j = 0; j < 32; ++j)
        s = fmaf(doff[il][j], wt[c0 + j][r2], s);
      sblk[il][r2] = s;
      __syncthreads();
    }
  }

  const int c2 = tid & 255;
  const int rh = tid >> 8;
#pragma unroll
  for (int k = 0; k < 8; ++k) {
    int row = rh * 8 + k;
    float f0 = wt[2 * c2][row];
    float f1 = wt[2 * c2 + 1][row];
    ushort h0, l0, h1, l1;
    bsplit(f0, h0, l0);
    bsplit(f1, h1, l1);
    size_t off = (size_t)(row0 + row) * 512 + 2 * c2;
    *(ushort2*)(wh + off) = make_ushort2(h0, h1);
    *(ushort2*)(wl + off) = make_ushort2(l0, l1);
  }
}

// ---------------------------------------------------------------- launcher
extern "C" void kernel_launch(void* const* d_in, const int* in_sizes, int n_in,
                              void* d_out, int out_size, void* d_ws, size_t ws_size,
                              hipStream_t stream)
{
  const float* u   = (const float*)d_in[0];   // 8192 x 256
  const float* x0  = (const float*)d_in[1];   // 8192 x 512
  const float* X   = (const float*)d_in[2];   // 1536 x 1536
  const float* Y   = (const float*)d_in[3];   // 512 x 512
  const float* B2  = (const float*)d_in[4];   // 512 x 256
  const float* C2  = (const float*)d_in[5];   // 256 x 512
  const float* D21 = (const float*)d_in[6];   // 256 x 512
  const float* D22 = (const float*)d_in[7];   // 256 x 256
  const float* D12 = (const float*)d_in[8];   // 512 x 256
  float* out = (float*)d_out;
  float* ws = (float*)d_ws;

  float*  E    = ws + 0;
  float*  C1   = ws + 262144;
  float*  D11  = ws + 524288;
  float*  D11T = ws + 786432;
  float*  Lam  = ws + 1048576;
  int*    flag = (int*)(ws + 1049088);
  float*  Tf0  = ws + 1049600;
  float*  Tf1  = ws + 1311744;
  float*  Qf0  = ws + 1573888;
  float*  Qf1  = ws + 1704960;
  ushort* Th0  = (ushort*)(ws + 1836032);
  ushort* Tl0  = (ushort*)(ws + 1967104);
  ushort* Tth0 = (ushort*)(ws + 2098176);
  ushort* Ttl0 = (ushort*)(ws + 2229248);
  ushort* Th1  = (ushort*)(ws + 2360320);
  ushort* Tl1  = (ushort*)(ws + 2491392);
  ushort* Tth1 = (ushort*)(ws + 2622464);
  ushort* Ttl1 = (ushort*)(ws + 2753536);
  ushort* Qh0  = (ushort*)(ws + 2884608);
  ushort* Ql0  = (ushort*)(ws + 2950144);
  ushort* Qh1  = (ushort*)(ws + 3015680);
  ushort* Ql1  = (ushort*)(ws + 3081216);
  ushort* FmTh = (ushort*)(ws + 3146752);
  ushort* FmTl = (ushort*)(ws + 3277824);
  ushort* B1Th = (ushort*)(ws + 3408896);
  ushort* B1Tl = (ushort*)(ws + 3539968);
  ushort* B2Th = (ushort*)(ws + 3671040);
  ushort* B2Tl = (ushort*)(ws + 3736576);
  float*  P1   = ws + 3802112;
  ushort* P2h  = (ushort*)(ws + 3933184);
  ushort* P2l  = (ushort*)(ws + 3998720);
  ushort* P3h  = (ushort*)(ws + 4064256);
  ushort* P3l  = (ushort*)(ws + 4097024);
  ushort* D12h = (ushort*)(ws + 4129792);
  ushort* D12l = (ushort*)(ws + 4195328);
  ushort* uh   = (ushort*)(ws + 4260864);
  ushort* ul   = (ushort*)(ws + 5309440);
  float*  abuf = ws + 6358016;
  ushort* wh   = (ushort*)(ws + 10552320);
  ushort* wl   = (ushort*)(ws + 12649472);
  // Xt splits alias the wh/wl region (dead before k_scan writes wh/wl)
  ushort* Xth  = (ushort*)(ws + 10552320);
  ushort* Xtl  = (ushort*)(ws + 11731968);

  hipMemsetAsync(flag, 0, 4, stream);
  k_anynz<<<256, 256, 0, stream>>>(x0, 8192 * 512 / 4, flag);

  // transpose+split X -> Xt hi/lo; B2 -> B2T hi/lo; plain split u, D12
  k_tsplit<<<dim3(48, 48), 256, 0, stream>>>(X, Xth, Xtl, 1536, 1536);
  k_tsplit<<<dim3(8, 16), 256, 0, stream>>>(B2, B2Th, B2Tl, 512, 256);
  k_split2<<<2048, 256, 0, stream>>>(u, uh, ul, 524288, D12, D12h, D12l, 32768);

  // all 6 H-blocks via MFMA (E, C1, D11/D11T/Lam, FmT h/l, B1T h/l)
  k_xtxm<<<dim3(8, 8, 5), 256, 0, stream>>>(Xth, Xtl, Y, E, C1, D11, D11T, Lam,
                                            FmTh, FmTl, B1Th, B1Tl);

  // abuf = u @ D12^T (MFMA); + x0 @ C1^T if flag
  k_ntm<1><<<dim3(128, 8), 256, 0, stream>>>(uh, ul, D12h, D12l, 256,
                                             nullptr, nullptr, nullptr, nullptr, 0,
                                             abuf, 512);
  k_ntadd<<<dim3(128, 8), 256, 0, stream>>>(x0, C1, 512, flag, abuf, 512);

  // Newton-Schulz on (T, Q) via MFMA: 5 x {T,Q} + 1 final Q-only
  k_nsinit<<<384, 256, 0, stream>>>(E, C2, Tf0, Th0, Tl0, Tth0, Ttl0, Qf0, Qh0, Ql0);
  ushort *Tha[2] = {Th0, Th1}, *Tla[2] = {Tl0, Tl1};
  ushort *Ttha[2] = {Tth0, Tth1}, *Ttla[2] = {Ttl0, Ttl1};
  ushort *Qha[2] = {Qh0, Qh1}, *Qla[2] = {Ql0, Ql1};
  float *Tfa[2] = {Tf0, Tf1}, *Qfa[2] = {Qf0, Qf1};
  int cur = 0;
  for (int it = 0; it < 5; ++it) {
    int nxt = cur ^ 1;
    k_nsm<true><<<dim3(8, 12), 256, 0, stream>>>(
        Tha[cur], Tla[cur], Ttha[cur], Ttla[cur], Qha[cur], Qla[cur],
        Tfa[cur], Qfa[cur],
        Tfa[nxt], Tha[nxt], Tla[nxt], Ttha[nxt], Ttla[nxt],
        Qfa[nxt], Qha[nxt], Qla[nxt]);
    cur = nxt;
  }
  int nxt = cur ^ 1;
  k_nsm<false><<<dim3(8, 4), 256, 0, stream>>>(
      Tha[cur], Tla[cur], Ttha[cur], Ttla[cur], Qha[cur], Qla[cur],
      Tfa[cur], Qfa[cur],
      Tfa[nxt], Tha[nxt], Tla[nxt], Ttha[nxt], Ttla[nxt],
      Qfa[nxt], Qha[nxt], Qla[nxt]);
  ushort* Qh = Qha[nxt];
  ushort* Ql = Qla[nxt];

  // folds: P1 fp32, P2/P3 hi/lo (MFMA)
  k_foldm<<<dim3(8, 4, 3), 256, 0, stream>>>(Qh, Ql, FmTh, FmTl, B1Th, B1Tl,
                                             B2Th, B2Tl, D21, D22,
                                             P1, P2h, P2l, P3h, P3l);

  // scan -> w (bf16 hi/lo)
  k_scan<<<512, 512, 0, stream>>>(abuf, D11, D11T, Lam, wh, wl);

  // y = w @ P2^T + u @ P3^T (MFMA); + x0 @ P1^T if flag
  k_ntm<2><<<dim3(128, 4), 256, 0, stream>>>(wh, wl, P2h, P2l, 512,
                                             uh, ul, P3h, P3l, 256,
                                             out, 256);
  k_ntadd<<<dim3(128, 4), 256, 0, stream>>>(x0, P1, 512, flag, out, 256);
}

// Round 6
// 406.824 us; speedup vs baseline: 2.6899x; 1.0783x over previous
//
#include <hip/hip_runtime.h>
#include <cstdint>
#include <cstddef>

#define EPSC 0.001f

typedef __attribute__((ext_vector_type(8))) short short8;
typedef __attribute__((ext_vector_type(4))) float f32x4;

__device__ inline void bsplit(float f, ushort& h, ushort& l) {
  uint b = __float_as_uint(f);
  h = (ushort)(b >> 16);
  float r = f - __uint_as_float(b & 0xFFFF0000u);
  l = (ushort)(__float_as_uint(r) >> 16);
}

// ---------------------------------------------------------------- any-nonzero
__global__ void k_anynz(const float* __restrict__ x, int n4, int* __restrict__ flag) {
  int i = blockIdx.x * blockDim.x + threadIdx.x;
  int stride = gridDim.x * blockDim.x;
  int found = 0;
  for (; i < n4; i += stride) {
    float4 v = ((const float4*)x)[i];
    if (v.x != 0.f || v.y != 0.f || v.z != 0.f || v.w != 0.f) { found = 1; break; }
  }
  if (found) atomicOr(flag, 1);
}

// ---------------------------------------------------------------- transpose + bf16 split: dst[C x R] = src[R x C]^T
__global__ __launch_bounds__(256) void k_tsplit(const float* __restrict__ src,
    ushort* __restrict__ dh, ushort* __restrict__ dl, int R, int C)
{
  __shared__ float t[32][33];
  const int c0 = blockIdx.x * 32, r0 = blockIdx.y * 32;
  const int tid = threadIdx.x;
  const int lr = tid >> 3, lc4 = (tid & 7) * 4;
  float4 v = *(const float4*)(src + (size_t)(r0 + lr) * C + c0 + lc4);
  t[lr][lc4 + 0] = v.x; t[lr][lc4 + 1] = v.y;
  t[lr][lc4 + 2] = v.z; t[lr][lc4 + 3] = v.w;
  __syncthreads();
  ushort4 hv, lv;
  float f;
  f = t[lc4 + 0][lr]; bsplit(f, hv.x, lv.x);
  f = t[lc4 + 1][lr]; bsplit(f, hv.y, lv.y);
  f = t[lc4 + 2][lr]; bsplit(f, hv.z, lv.z);
  f = t[lc4 + 3][lr]; bsplit(f, hv.w, lv.w);
  size_t off = (size_t)(c0 + lr) * R + r0 + lc4;
  *(ushort4*)(dh + off) = hv;
  *(ushort4*)(dl + off) = lv;
}

// ---------------------------------------------------------------- plain bf16 split (2 segments)
__global__ void k_split2(const float* __restrict__ s0, ushort* __restrict__ h0,
                         ushort* __restrict__ l0, int c0,
                         const float* __restrict__ s1, ushort* __restrict__ h1,
                         ushort* __restrict__ l1, int c1)
{
  int i = blockIdx.x * 256 + threadIdx.x;
  int tot = c0 + c1;
  int stride = gridDim.x * 256;
  for (; i < tot; i += stride) {
    const float* s; ushort* h; ushort* l; int k;
    if (i < c0) { s = s0; h = h0; l = l0; k = i; }
    else        { s = s1; h = h1; l = l1; k = i - c0; }
    float4 v = ((const float4*)s)[k];
    ushort4 hv, lv;
    bsplit(v.x, hv.x, lv.x);
    bsplit(v.y, hv.y, lv.y);
    bsplit(v.z, hv.z, lv.z);
    bsplit(v.w, hv.w, lv.w);
    ((ushort4*)h)[k] = hv;
    ((ushort4*)l)[k] = lv;
  }
}

// ---------------------------------------------------------------- MFMA XtX: 6 H-blocks from Xt splits
// z=0: E=0.5(H11+H33+Y-Y^T)+epsI ; z=1: C1=-H21 ; z=2: D11 (fp32 + h/l splits) + Lam ;
// z=3: FmT=H13 (hi/lo) ; z=4: B1T=H23 (hi/lo)
__global__ __launch_bounds__(256) void k_xtxm(
    const ushort* __restrict__ Xth, const ushort* __restrict__ Xtl,
    const float* __restrict__ Y,
    float* __restrict__ E, float* __restrict__ C1,
    float* __restrict__ D11, ushort* __restrict__ D11h, ushort* __restrict__ D11l,
    float* __restrict__ Lam,
    ushort* __restrict__ FmTh, ushort* __restrict__ FmTl,
    ushort* __restrict__ B1Th, ushort* __restrict__ B1Tl)
{
  __shared__ ushort sAh[64][40], sAl[64][40], sBh[64][40], sBl[64][40];
  const int z = blockIdx.z;
  int aOff[2], bOff[2], nops;
  switch (z) {
    case 0:  aOff[0] = 0;    bOff[0] = 0;    aOff[1] = 1024; bOff[1] = 1024; nops = 2; break;
    case 1:  aOff[0] = 512;  bOff[0] = 0;    nops = 1; break;
    case 2:  aOff[0] = 512;  bOff[0] = 512;  nops = 1; break;
    case 3:  aOff[0] = 0;    bOff[0] = 1024; nops = 1; break;
    default: aOff[0] = 512;  bOff[0] = 1024; nops = 1; break;
  }
  const int tid = threadIdx.x;
  const int m0 = blockIdx.x * 64, n0 = blockIdx.y * 64;
  const int wid = tid >> 6, lane = tid & 63;
  const int wr = wid >> 1, wc = wid & 1;
  const int fr = lane & 15, fg = lane >> 4;
  const int srow = tid >> 2;
  const int sko = (tid & 3) * 8;
  f32x4 acc[2][2] = {};
  const int K = 1536;

  for (int op = 0; op < nops; ++op) {
    const ushort* Ah = Xth + (size_t)(aOff[op]) * K;
    const ushort* Al = Xtl + (size_t)(aOff[op]) * K;
    const ushort* Bh = Xth + (size_t)(bOff[op]) * K;
    const ushort* Bl = Xtl + (size_t)(bOff[op]) * K;
    uint4 pah = *(const uint4*)(Ah + (size_t)(m0 + srow) * K + sko);
    uint4 pal = *(const uint4*)(Al + (size_t)(m0 + srow) * K + sko);
    uint4 pbh = *(const uint4*)(Bh + (size_t)(n0 + srow) * K + sko);
    uint4 pbl = *(const uint4*)(Bl + (size_t)(n0 + srow) * K + sko);
    for (int k0 = 0; k0 < K; k0 += 32) {
      __syncthreads();
      *(uint4*)&sAh[srow][sko] = pah;
      *(uint4*)&sAl[srow][sko] = pal;
      *(uint4*)&sBh[srow][sko] = pbh;
      *(uint4*)&sBl[srow][sko] = pbl;
      __syncthreads();
      if (k0 + 32 < K) {
        pah = *(const uint4*)(Ah + (size_t)(m0 + srow) * K + k0 + 32 + sko);
        pal = *(const uint4*)(Al + (size_t)(m0 + srow) * K + k0 + 32 + sko);
        pbh = *(const uint4*)(Bh + (size_t)(n0 + srow) * K + k0 + 32 + sko);
        pbl = *(const uint4*)(Bl + (size_t)(n0 + srow) * K + k0 + 32 + sko);
      }
      short8 fah[2], fal[2], fbh[2], fbl[2];
#pragma unroll
      for (int s = 0; s < 2; ++s) {
        fah[s] = *(const short8*)&sAh[wr * 32 + s * 16 + fr][fg * 8];
        fal[s] = *(const short8*)&sAl[wr * 32 + s * 16 + fr][fg * 8];
        fbh[s] = *(const short8*)&sBh[wc * 32 + s * 16 + fr][fg * 8];
        fbl[s] = *(const short8*)&sBl[wc * 32 + s * 16 + fr][fg * 8];
      }
#pragma unroll
      for (int i = 0; i < 2; ++i)
#pragma unroll
        for (int j = 0; j < 2; ++j) {
          acc[i][j] = __builtin_amdgcn_mfma_f32_16x16x32_bf16(fah[i], fbh[j], acc[i][j], 0, 0, 0);
          acc[i][j] = __builtin_amdgcn_mfma_f32_16x16x32_bf16(fah[i], fbl[j], acc[i][j], 0, 0, 0);
          acc[i][j] = __builtin_amdgcn_mfma_f32_16x16x32_bf16(fal[i], fbh[j], acc[i][j], 0, 0, 0);
        }
    }
  }

#pragma unroll
  for (int i = 0; i < 2; ++i)
#pragma unroll
    for (int j = 0; j < 2; ++j) {
      int rbase = m0 + wr * 32 + i * 16 + fg * 4;
      int cc = n0 + wc * 32 + j * 16 + fr;
#pragma unroll
      for (int q = 0; q < 4; ++q) {
        int rr = rbase + q;
        float d = acc[i][j][q];
        size_t idx = (size_t)rr * 512 + cc;
        if (z == 0) {
          float o = 0.5f * (d + Y[idx] - Y[(size_t)cc * 512 + rr]);
          if (rr == cc) o += EPSC;
          E[idx] = o;
        } else if (z == 1) {
          C1[idx] = -d;
        } else if (z == 2) {
          float o = (cc < rr) ? -d : 0.f;
          D11[idx] = o;
          ushort h, l; bsplit(o, h, l);
          D11h[idx] = h; D11l[idx] = l;
          if (rr == cc) Lam[rr] = 0.5f * (d + EPSC);
        } else if (z == 3) {
          ushort h, l; bsplit(d, h, l);
          FmTh[idx] = h; FmTl[idx] = l;
        } else {
          ushort h, l; bsplit(d, h, l);
          B1Th[idx] = h; B1Tl[idx] = l;
        }
      }
    }
}

// ---------------------------------------------------------------- NS init: T0=E*diag(s), Q0=C2*diag(s), s=0.85/diag(E)
__global__ void k_nsinit(const float* __restrict__ E, const float* __restrict__ C2,
    float* __restrict__ Tf, ushort* __restrict__ Th, ushort* __restrict__ Tl,
    ushort* __restrict__ Tth, ushort* __restrict__ Ttl,
    float* __restrict__ Qf, ushort* __restrict__ Qh, ushort* __restrict__ Ql)
{
  int g = blockIdx.x * 256 + threadIdx.x;   // 768 rows x 128 quads
  int row = g >> 7;
  int c4 = (g & 127) << 2;
  float s0 = 0.85f / E[(size_t)(c4 + 0) * 513];
  float s1 = 0.85f / E[(size_t)(c4 + 1) * 513];
  float s2 = 0.85f / E[(size_t)(c4 + 2) * 513];
  float s3 = 0.85f / E[(size_t)(c4 + 3) * 513];
  if (row < 512) {
    float4 v = *(const float4*)(E + (size_t)row * 512 + c4);
    v.x *= s0; v.y *= s1; v.z *= s2; v.w *= s3;
    *(float4*)(Tf + (size_t)row * 512 + c4) = v;
    ushort4 hv, lv;
    bsplit(v.x, hv.x, lv.x); bsplit(v.y, hv.y, lv.y);
    bsplit(v.z, hv.z, lv.z); bsplit(v.w, hv.w, lv.w);
    *(ushort4*)(Th + (size_t)row * 512 + c4) = hv;
    *(ushort4*)(Tl + (size_t)row * 512 + c4) = lv;
    Tth[(size_t)(c4 + 0) * 512 + row] = hv.x; Ttl[(size_t)(c4 + 0) * 512 + row] = lv.x;
    Tth[(size_t)(c4 + 1) * 512 + row] = hv.y; Ttl[(size_t)(c4 + 1) * 512 + row] = lv.y;
    Tth[(size_t)(c4 + 2) * 512 + row] = hv.z; Ttl[(size_t)(c4 + 2) * 512 + row] = lv.z;
    Tth[(size_t)(c4 + 3) * 512 + row] = hv.w; Ttl[(size_t)(c4 + 3) * 512 + row] = lv.w;
  } else {
    int qr = row - 512;
    float4 v = *(const float4*)(C2 + (size_t)qr * 512 + c4);
    v.x *= s0; v.y *= s1; v.z *= s2; v.w *= s3;
    *(float4*)(Qf + (size_t)qr * 512 + c4) = v;
    ushort4 hv, lv;
    bsplit(v.x, hv.x, lv.x); bsplit(v.y, hv.y, lv.y);
    bsplit(v.z, hv.z, lv.z); bsplit(v.w, hv.w, lv.w);
    *(ushort4*)(Qh + (size_t)qr * 512 + c4) = hv;
    *(ushort4*)(Ql + (size_t)qr * 512 + c4) = lv;
  }
}

// ---------------------------------------------------------------- MFMA NS step: Tn=2T-T*T ; Qn=2Q-Q*T (NT vs Tt splits)
template <bool WITH_T>
__global__ __launch_bounds__(256) void k_nsm(
    const ushort* __restrict__ Th, const ushort* __restrict__ Tl,
    const ushort* __restrict__ Tth, const ushort* __restrict__ Ttl,
    const ushort* __restrict__ Qh, const ushort* __restrict__ Ql,
    const float* __restrict__ Tprev, const float* __restrict__ Qprev,
    float* __restrict__ Tnext, ushort* __restrict__ Thn, ushort* __restrict__ Tln,
    ushort* __restrict__ Tthn, ushort* __restrict__ Ttln,
    float* __restrict__ Qnext, ushort* __restrict__ Qhn, ushort* __restrict__ Qln)
{
  __shared__ ushort sAh[64][40], sAl[64][40], sBh[64][40], sBl[64][40];
  const int tid = threadIdx.x;
  const int yy = blockIdx.y;
  const bool isT = WITH_T && (yy < 8);
  const int m0 = (isT ? yy : (yy - (WITH_T ? 8 : 0))) * 64;
  const int n0 = blockIdx.x * 64;
  const ushort* Ah = isT ? Th : Qh;
  const ushort* Al = isT ? Tl : Ql;
  const int wid = tid >> 6, lane = tid & 63;
  const int wr = wid >> 1, wc = wid & 1;
  const int fr = lane & 15, fg = lane >> 4;
  const int srow = tid >> 2;
  const int sko = (tid & 3) * 8;
  const int K = 512;
  f32x4 acc[2][2] = {};

  uint4 pah = *(const uint4*)(Ah + (size_t)(m0 + srow) * K + sko);
  uint4 pal = *(const uint4*)(Al + (size_t)(m0 + srow) * K + sko);
  uint4 pbh = *(const uint4*)(Tth + (size_t)(n0 + srow) * K + sko);
  uint4 pbl = *(const uint4*)(Ttl + (size_t)(n0 + srow) * K + sko);
  for (int k0 = 0; k0 < K; k0 += 32) {
    __syncthreads();
    *(uint4*)&sAh[srow][sko] = pah;
    *(uint4*)&sAl[srow][sko] = pal;
    *(uint4*)&sBh[srow][sko] = pbh;
    *(uint4*)&sBl[srow][sko] = pbl;
    __syncthreads();
    if (k0 + 32 < K) {
      pah = *(const uint4*)(Ah + (size_t)(m0 + srow) * K + k0 + 32 + sko);
      pal = *(const uint4*)(Al + (size_t)(m0 + srow) * K + k0 + 32 + sko);
      pbh = *(const uint4*)(Tth + (size_t)(n0 + srow) * K + k0 + 32 + sko);
      pbl = *(const uint4*)(Ttl + (size_t)(n0 + srow) * K + k0 + 32 + sko);
    }
    short8 fah[2], fal[2], fbh[2], fbl[2];
#pragma unroll
    for (int s = 0; s < 2; ++s) {
      fah[s] = *(const short8*)&sAh[wr * 32 + s * 16 + fr][fg * 8];
      fal[s] = *(const short8*)&sAl[wr * 32 + s * 16 + fr][fg * 8];
      fbh[s] = *(const short8*)&sBh[wc * 32 + s * 16 + fr][fg * 8];
      fbl[s] = *(const short8*)&sBl[wc * 32 + s * 16 + fr][fg * 8];
    }
#pragma unroll
    for (int i = 0; i < 2; ++i)
#pragma unroll
      for (int j = 0; j < 2; ++j) {
        acc[i][j] = __builtin_amdgcn_mfma_f32_16x16x32_bf16(fah[i], fbh[j], acc[i][j], 0, 0, 0);
        acc[i][j] = __builtin_amdgcn_mfma_f32_16x16x32_bf16(fah[i], fbl[j], acc[i][j], 0, 0, 0);
        acc[i][j] = __builtin_amdgcn_mfma_f32_16x16x32_bf16(fal[i], fbh[j], acc[i][j], 0, 0, 0);
      }
  }

#pragma unroll
  for (int i = 0; i < 2; ++i)
#pragma unroll
    for (int j = 0; j < 2; ++j) {
      int rbase = m0 + wr * 32 + i * 16 + fg * 4;
      int cc = n0 + wc * 32 + j * 16 + fr;
#pragma unroll
      for (int q = 0; q < 4; ++q) {
        int rr = rbase + q;
        size_t idx = (size_t)rr * 512 + cc;
        ushort h, l;
        if (isT) {
          float tn = 2.f * Tprev[idx] - acc[i][j][q];
          Tnext[idx] = tn;
          bsplit(tn, h, l);
          Thn[idx] = h; Tln[idx] = l;
          Tthn[(size_t)cc * 512 + rr] = h; Ttln[(size_t)cc * 512 + rr] = l;
        } else {
          float qn = 2.f * Qprev[idx] - acc[i][j][q];
          Qnext[idx] = qn;
          bsplit(qn, h, l);
          Qhn[idx] = h; Qln[idx] = l;
        }
      }
    }
}

// ---------------------------------------------------------------- MFMA folds: P1=Q*Fm (fp32) ; P2=Q*B1+D21 (h/l) ; P3=Q*B2+D22 (h/l)
__global__ __launch_bounds__(256) void k_foldm(
    const ushort* __restrict__ Qh, const ushort* __restrict__ Ql,
    const ushort* __restrict__ FmTh, const ushort* __restrict__ FmTl,
    const ushort* __restrict__ B1Th, const ushort* __restrict__ B1Tl,
    const ushort* __restrict__ B2Th, const ushort* __restrict__ B2Tl,
    const float* __restrict__ D21, const float* __restrict__ D22,
    float* __restrict__ P1, ushort* __restrict__ P2h, ushort* __restrict__ P2l,
    ushort* __restrict__ P3h, ushort* __restrict__ P3l)
{
  __shared__ ushort sAh[64][40], sAl[64][40], sBh[64][40], sBl[64][40];
  const int z = blockIdx.z;
  const int N = (z == 2) ? 256 : 512;
  const int n0 = blockIdx.x * 64;
  if (n0 >= N) return;
  const ushort* Bh = (z == 0) ? FmTh : (z == 1) ? B1Th : B2Th;
  const ushort* Bl = (z == 0) ? FmTl : (z == 1) ? B1Tl : B2Tl;
  const int tid = threadIdx.x;
  const int m0 = blockIdx.y * 64;
  const int wid = tid >> 6, lane = tid & 63;
  const int wr = wid >> 1, wc = wid & 1;
  const int fr = lane & 15, fg = lane >> 4;
  const int srow = tid >> 2;
  const int sko = (tid & 3) * 8;
  const int K = 512;
  f32x4 acc[2][2] = {};

  uint4 pah = *(const uint4*)(Qh + (size_t)(m0 + srow) * K + sko);
  uint4 pal = *(const uint4*)(Ql + (size_t)(m0 + srow) * K + sko);
  uint4 pbh = *(const uint4*)(Bh + (size_t)(n0 + srow) * K + sko);
  uint4 pbl = *(const uint4*)(Bl + (size_t)(n0 + srow) * K + sko);
  for (int k0 = 0; k0 < K; k0 += 32) {
    __syncthreads();
    *(uint4*)&sAh[srow][sko] = pah;
    *(uint4*)&sAl[srow][sko] = pal;
    *(uint4*)&sBh[srow][sko] = pbh;
    *(uint4*)&sBl[srow][sko] = pbl;
    __syncthreads();
    if (k0 + 32 < K) {
      pah = *(const uint4*)(Qh + (size_t)(m0 + srow) * K + k0 + 32 + sko);
      pal = *(const uint4*)(Ql + (size_t)(m0 + srow) * K + k0 + 32 + sko);
      pbh = *(const uint4*)(Bh + (size_t)(n0 + srow) * K + k0 + 32 + sko);
      pbl = *(const uint4*)(Bl + (size_t)(n0 + srow) * K + k0 + 32 + sko);
    }
    short8 fah[2], fal[2], fbh[2], fbl[2];
#pragma unroll
    for (int s = 0; s < 2; ++s) {
      fah[s] = *(const short8*)&sAh[wr * 32 + s * 16 + fr][fg * 8];
      fal[s] = *(const short8*)&sAl[wr * 32 + s * 16 + fr][fg * 8];
      fbh[s] = *(const short8*)&sBh[wc * 32 + s * 16 + fr][fg * 8];
      fbl[s] = *(const short8*)&sBl[wc * 32 + s * 16 + fr][fg * 8];
    }
#pragma unroll
    for (int i = 0; i < 2; ++i)
#pragma unroll
      for (int j = 0; j < 2; ++j) {
        acc[i][j] = __builtin_amdgcn_mfma_f32_16x16x32_bf16(fah[i], fbh[j], acc[i][j], 0, 0, 0);
        acc[i][j] = __builtin_amdgcn_mfma_f32_16x16x32_bf16(fah[i], fbl[j], acc[i][j], 0, 0, 0);
        acc[i][j] = __builtin_amdgcn_mfma_f32_16x16x32_bf16(fal[i], fbh[j], acc[i][j], 0, 0, 0);
      }
  }

#pragma unroll
  for (int i = 0; i < 2; ++i)
#pragma unroll
    for (int j = 0; j < 2; ++j) {
      int rbase = m0 + wr * 32 + i * 16 + fg * 4;
      int cc = n0 + wc * 32 + j * 16 + fr;
#pragma unroll
      for (int q = 0; q < 4; ++q) {
        int rr = rbase + q;
        float d = acc[i][j][q];
        if (z == 0) {
          P1[(size_t)rr * 512 + cc] = d;
        } else if (z == 1) {
          size_t idx = (size_t)rr * 512 + cc;
          float p = d + D21[idx];
          ushort h, l; bsplit(p, h, l);
          P2h[idx] = h; P2l[idx] = l;
        } else {
          size_t idx = (size_t)rr * 256 + cc;
          float p = d + D22[idx];
          ushort h, l; bsplit(p, h, l);
          P3h[idx] = h; P3l[idx] = l;
        }
      }
    }
}

// ---------------------------------------------------------------- MFMA NT GEMM, split-bf16 3-pass (batch)
template <int NOPS>
__global__ __launch_bounds__(256) void k_ntm(
    const ushort* __restrict__ Ah0, const ushort* __restrict__ Al0,
    const ushort* __restrict__ Bh0, const ushort* __restrict__ Bl0, int K0,
    const ushort* __restrict__ Ah1, const ushort* __restrict__ Al1,
    const ushort* __restrict__ Bh1, const ushort* __restrict__ Bl1, int K1,
    float* __restrict__ C, int ldc)
{
  __shared__ ushort sAh[64][40], sAl[64][40], sBh[64][40], sBl[64][40];
  const int tid = threadIdx.x;
  const int m0 = blockIdx.x * 64, n0 = blockIdx.y * 64;
  const int wid = tid >> 6, lane = tid & 63;
  const int wr = wid >> 1, wc = wid & 1;
  const int fr = lane & 15, fg = lane >> 4;
  const int srow = tid >> 2;
  const int sko = (tid & 3) * 8;
  f32x4 acc[2][2] = {};

#pragma unroll
  for (int op = 0; op < NOPS; ++op) {
    const ushort* Ah = (op == 0) ? Ah0 : Ah1;
    const ushort* Al = (op == 0) ? Al0 : Al1;
    const ushort* Bh = (op == 0) ? Bh0 : Bh1;
    const ushort* Bl = (op == 0) ? Bl0 : Bl1;
    const int K = (op == 0) ? K0 : K1;
    uint4 pah = *(const uint4*)(Ah + (size_t)(m0 + srow) * K + sko);
    uint4 pal = *(const uint4*)(Al + (size_t)(m0 + srow) * K + sko);
    uint4 pbh = *(const uint4*)(Bh + (size_t)(n0 + srow) * K + sko);
    uint4 pbl = *(const uint4*)(Bl + (size_t)(n0 + srow) * K + sko);
    for (int k0 = 0; k0 < K; k0 += 32) {
      __syncthreads();
      *(uint4*)&sAh[srow][sko] = pah;
      *(uint4*)&sAl[srow][sko] = pal;
      *(uint4*)&sBh[srow][sko] = pbh;
      *(uint4*)&sBl[srow][sko] = pbl;
      __syncthreads();
      if (k0 + 32 < K) {
        pah = *(const uint4*)(Ah + (size_t)(m0 + srow) * K + k0 + 32 + sko);
        pal = *(const uint4*)(Al + (size_t)(m0 + srow) * K + k0 + 32 + sko);
        pbh = *(const uint4*)(Bh + (size_t)(n0 + srow) * K + k0 + 32 + sko);
        pbl = *(const uint4*)(Bl + (size_t)(n0 + srow) * K + k0 + 32 + sko);
      }
      short8 fah[2], fal[2], fbh[2], fbl[2];
#pragma unroll
      for (int s = 0; s < 2; ++s) {
        fah[s] = *(const short8*)&sAh[wr * 32 + s * 16 + fr][fg * 8];
        fal[s] = *(const short8*)&sAl[wr * 32 + s * 16 + fr][fg * 8];
        fbh[s] = *(const short8*)&sBh[wc * 32 + s * 16 + fr][fg * 8];
        fbl[s] = *(const short8*)&sBl[wc * 32 + s * 16 + fr][fg * 8];
      }
#pragma unroll
      for (int i = 0; i < 2; ++i)
#pragma unroll
        for (int j = 0; j < 2; ++j) {
          acc[i][j] = __builtin_amdgcn_mfma_f32_16x16x32_bf16(fah[i], fbh[j], acc[i][j], 0, 0, 0);
          acc[i][j] = __builtin_amdgcn_mfma_f32_16x16x32_bf16(fah[i], fbl[j], acc[i][j], 0, 0, 0);
          acc[i][j] = __builtin_amdgcn_mfma_f32_16x16x32_bf16(fal[i], fbh[j], acc[i][j], 0, 0, 0);
        }
    }
  }

#pragma unroll
  for (int i = 0; i < 2; ++i)
#pragma unroll
    for (int j = 0; j < 2; ++j) {
      int rr = m0 + wr * 32 + i * 16 + fg * 4;
      int cc = n0 + wc * 32 + j * 16 + fr;
#pragma unroll
      for (int q = 0; q < 4; ++q)
        C[(size_t)(rr + q) * ldc + cc] = acc[i][j][q];
    }
}

// ---------------------------------------------------------------- flag-gated fp32 NT accumulate (x0 terms)
__global__ __launch_bounds__(256) void k_ntadd(const float* __restrict__ A,
    const float* __restrict__ B, int K, const int* __restrict__ flag,
    float* __restrict__ C, int ldc)
{
  if (*flag == 0) return;
  __shared__ float As[16][68];
  __shared__ float Bs[16][68];
  const int tid = threadIdx.x;
  const int tx = tid & 15, ty = tid >> 4;
  const int m0 = blockIdx.x * 64, n0 = blockIdx.y * 64;
  const int lr = tid >> 2;
  const int lk = (tid & 3) * 4;
  float acc[4][4];
#pragma unroll
  for (int i = 0; i < 4; ++i)
#pragma unroll
    for (int j = 0; j < 4; ++j) acc[i][j] = 0.f;
  float4 av = *(const float4*)(A + (size_t)(m0 + lr) * K + lk);
  float4 bv = *(const float4*)(B + (size_t)(n0 + lr) * K + lk);
  for (int k0 = 0; k0 < K; k0 += 16) {
    __syncthreads();
    As[lk + 0][lr] = av.x; As[lk + 1][lr] = av.y;
    As[lk + 2][lr] = av.z; As[lk + 3][lr] = av.w;
    Bs[lk + 0][lr] = bv.x; Bs[lk + 1][lr] = bv.y;
    Bs[lk + 2][lr] = bv.z; Bs[lk + 3][lr] = bv.w;
    __syncthreads();
    if (k0 + 16 < K) {
      av = *(const float4*)(A + (size_t)(m0 + lr) * K + k0 + 16 + lk);
      bv = *(const float4*)(B + (size_t)(n0 + lr) * K + k0 + 16 + lk);
    }
#pragma unroll
    for (int kk = 0; kk < 16; ++kk) {
      float4 a4 = *(const float4*)&As[kk][4 * ty];
      float4 b4 = *(const float4*)&Bs[kk][4 * tx];
      float ar[4] = {a4.x, a4.y, a4.z, a4.w};
      float br[4] = {b4.x, b4.y, b4.z, b4.w};
#pragma unroll
      for (int i = 0; i < 4; ++i)
#pragma unroll
        for (int j = 0; j < 4; ++j)
          acc[i][j] = fmaf(ar[i], br[j], acc[i][j]);
    }
  }
#pragma unroll
  for (int i = 0; i < 4; ++i) {
    float* p = C + (size_t)(m0 + 4 * ty + i) * ldc + n0 + 4 * tx;
    float4 v = *(float4*)p;
    v.x += acc[i][0]; v.y += acc[i][1]; v.z += acc[i][2]; v.w += acc[i][3];
    *(float4*)p = v;
  }
}

// ---------------------------------------------------------------- blocked tanh scan (v5: MFMA history)
// 512 blocks x 16 rows, 512 threads (8 waves).
// wave 0 : serial tanh triangle for block t (deferred updates); emits w as fp32 (wcur)
//          and bf16 hi/lo into wth/wtl (the MFMA B-operand store).
// waves 1-6: MFMA history partials for S(t+1): K-steps s < t, s%6 == wv-1.
//            A = D11h/l rows [32(t+1), 32(t+1)+32) direct from global; B = wth/wtl LDS.
// wave 7 : stage doff(t+1,t), dblkT(t+1), ablk(t+1).
// combine: S(t+1) = ablk + sum(shist) + doff * wcur.
__global__ __launch_bounds__(512, 4) void k_scan(const float* __restrict__ a,
    const float* __restrict__ D11,
    const ushort* __restrict__ D11h, const ushort* __restrict__ D11l,
    const float* __restrict__ Lam, ushort* __restrict__ wh, ushort* __restrict__ wl)
{
  __shared__ ushort wth[16][520];     // [row r][step k] bf16-hi of w (+8 pad: stride 260 words)
  __shared__ ushort wtl[16][520];     // bf16-lo
  __shared__ float wcur[32][17];      // fp32 w of current block t
  __shared__ float sblk[32][17];      // S(t) for triangle
  __shared__ float shist[6][32][17];  // MFMA hist partials
  __shared__ float dblkT[2][32][33];  // diag block transposed (deferred updates)
  __shared__ float doff[32][33];      // off-diag rows block t+1, cols block t
  __shared__ float ablk[32][17];      // a block t+1
  __shared__ float rl2[512];          // 2/Lam
  const int tid = threadIdx.x;
  const int row0 = blockIdx.x * 16;

  rl2[tid] = 2.f / Lam[tid];
  if (tid < 128) {
    int rr = tid >> 3, cq = (tid & 7) * 4;
    float4 v = *(const float4*)(a + (size_t)(row0 + rr) * 512 + cq);
    sblk[cq + 0][rr] = v.x; sblk[cq + 1][rr] = v.y;
    sblk[cq + 2][rr] = v.z; sblk[cq + 3][rr] = v.w;
  } else if (tid < 384) {
    int f = tid - 128;
    int rr = f >> 3, cq = (f & 7) * 4;
    float4 v = *(const float4*)(D11 + (size_t)rr * 512 + cq);
    dblkT[0][cq + 0][rr] = v.x; dblkT[0][cq + 1][rr] = v.y;
    dblkT[0][cq + 2][rr] = v.z; dblkT[0][cq + 3][rr] = v.w;
  }
  __syncthreads();

  const int wv = tid >> 6;
  const int lane = tid & 63;
  const int fr = lane & 15, fg = lane >> 4;

  for (int t = 0; t < 16; ++t) {
    const int c0 = 32 * t;
    const int jend2 = c0 + 32;
    if (wv == 0) {
      // ---- serial triangle (16 active lanes, one batch row each)
      if (lane < 16) {
        float s[32];
#pragma unroll
        for (int il = 0; il < 32; ++il) s[il] = sblk[il][lane];
#pragma unroll
        for (int il = 0; il < 32; ++il) {
          float x2 = s[il] * rl2[c0 + il];
          float e = __expf(x2);
          float w2 = 1.f - 2.f * __builtin_amdgcn_rcpf(e + 1.f);
          wcur[il][lane] = w2;
          ushort hh, ll; bsplit(w2, hh, ll);
          wth[lane][c0 + il] = hh;
          wtl[lane][c0 + il] = ll;
#pragma unroll
          for (int j2 = il + 1; j2 < 32; ++j2)
            s[j2] = fmaf(dblkT[t & 1][il][j2], w2, s[j2]);
        }
      }
    } else if (wv <= 6) {
      // ---- MFMA history partials for S(t+1)
      if (t < 15) {
        f32x4 acc0 = {}, acc1 = {};
        for (int s = wv - 1; s < t; s += 6) {
          const int jb = 32 * s;
          const size_t ao0 = (size_t)(jend2 + fr) * 512 + jb + fg * 8;
          const size_t ao1 = (size_t)(jend2 + 16 + fr) * 512 + jb + fg * 8;
          short8 a0h = *(const short8*)(D11h + ao0);
          short8 a0l = *(const short8*)(D11l + ao0);
          short8 a1h = *(const short8*)(D11h + ao1);
          short8 a1l = *(const short8*)(D11l + ao1);
          short8 bh = *(const short8*)&wth[fr][jb + fg * 8];
          short8 bl = *(const short8*)&wtl[fr][jb + fg * 8];
          acc0 = __builtin_amdgcn_mfma_f32_16x16x32_bf16(a0h, bh, acc0, 0, 0, 0);
          acc0 = __builtin_amdgcn_mfma_f32_16x16x32_bf16(a0h, bl, acc0, 0, 0, 0);
          acc0 = __builtin_amdgcn_mfma_f32_16x16x32_bf16(a0l, bh, acc0, 0, 0, 0);
          acc1 = __builtin_amdgcn_mfma_f32_16x16x32_bf16(a1h, bh, acc1, 0, 0, 0);
          acc1 = __builtin_amdgcn_mfma_f32_16x16x32_bf16(a1h, bl, acc1, 0, 0, 0);
          acc1 = __builtin_amdgcn_mfma_f32_16x16x32_bf16(a1l, bh, acc1, 0, 0, 0);
        }
        // D layout: col = lane&15 (batch row r), row = fg*4+q (+16 for tile 1)
#pragma unroll
        for (int q = 0; q < 4; ++q) {
          shist[wv - 1][fg * 4 + q][fr] = acc0[q];
          shist[wv - 1][16 + fg * 4 + q][fr] = acc1[q];
        }
      }
    } else {
      // ---- wave 7: stage next-step operands
      if (t < 15) {
#pragma unroll
        for (int e = 0; e < 4; ++e) {
          int f = lane + 64 * e;
          int rr = f >> 3, cq = (f & 7) * 4;
          float4 v = *(const float4*)(D11 + (size_t)(jend2 + rr) * 512 + c0 + cq);
          doff[rr][cq + 0] = v.x; doff[rr][cq + 1] = v.y;
          doff[rr][cq + 2] = v.z; doff[rr][cq + 3] = v.w;
          float4 v2 = *(const float4*)(D11 + (size_t)(jend2 + rr) * 512 + jend2 + cq);
          dblkT[(t + 1) & 1][cq + 0][rr] = v2.x; dblkT[(t + 1) & 1][cq + 1][rr] = v2.y;
          dblkT[(t + 1) & 1][cq + 2][rr] = v2.z; dblkT[(t + 1) & 1][cq + 3][rr] = v2.w;
        }
#pragma unroll
        for (int e = 0; e < 2; ++e) {
          int f = lane + 64 * e;
          int rr = f >> 3, cq = (f & 7) * 4;
          float4 v = *(const float4*)(a + (size_t)(row0 + rr) * 512 + jend2 + cq);
          ablk[cq + 0][rr] = v.x; ablk[cq + 1][rr] = v.y;
          ablk[cq + 2][rr] = v.z; ablk[cq + 3][rr] = v.w;
        }
      }
    }
    __syncthreads();
    if (t < 15) {
      // ---- combine: S(t+1) = ablk + sum(shist) + doff * wcur
      const int il = tid >> 4, r2 = tid & 15;
      float s = ablk[il][r2];
#pragma unroll
      for (int k = 0; k < 6; ++k) s += shist[k][il][r2];
#pragma unroll 8
      for (int j = 0; j < 32; ++j)
        s = fmaf(doff[il][j], wcur[j][r2], s);
      sblk[il][r2] = s;
      __syncthreads();
    }
  }

  // write out w hi/lo (LDS -> global, uint-packed)
  const int k2 = tid & 255;
  const int rb = tid >> 8;
#pragma unroll
  for (int p = 0; p < 8; ++p) {
    int r = rb * 8 + p;
    size_t off = (size_t)(row0 + r) * 512 + 2 * k2;
    *(uint*)(wh + off) = *(const uint*)&wth[r][2 * k2];
    *(uint*)(wl + off) = *(const uint*)&wtl[r][2 * k2];
  }
}

// ---------------------------------------------------------------- launcher
extern "C" void kernel_launch(void* const* d_in, const int* in_sizes, int n_in,
                              void* d_out, int out_size, void* d_ws, size_t ws_size,
                              hipStream_t stream)
{
  const float* u   = (const float*)d_in[0];   // 8192 x 256
  const float* x0  = (const float*)d_in[1];   // 8192 x 512
  const float* X   = (const float*)d_in[2];   // 1536 x 1536
  const float* Y   = (const float*)d_in[3];   // 512 x 512
  const float* B2  = (const float*)d_in[4];   // 512 x 256
  const float* C2  = (const float*)d_in[5];   // 256 x 512
  const float* D21 = (const float*)d_in[6];   // 256 x 512
  const float* D22 = (const float*)d_in[7];   // 256 x 256
  const float* D12 = (const float*)d_in[8];   // 512 x 256
  float* out = (float*)d_out;
  float* ws = (float*)d_ws;

  float*  E    = ws + 0;
  float*  C1   = ws + 262144;
  float*  D11  = ws + 524288;
  ushort* D11h = (ushort*)(ws + 786432);
  ushort* D11l = (ushort*)(ws + 917504);
  float*  Lam  = ws + 1048576;
  int*    flag = (int*)(ws + 1049088);
  float*  Tf0  = ws + 1049600;
  float*  Tf1  = ws + 1311744;
  float*  Qf0  = ws + 1573888;
  float*  Qf1  = ws + 1704960;
  ushort* Th0  = (ushort*)(ws + 1836032);
  ushort* Tl0  = (ushort*)(ws + 1967104);
  ushort* Tth0 = (ushort*)(ws + 2098176);
  ushort* Ttl0 = (ushort*)(ws + 2229248);
  ushort* Th1  = (ushort*)(ws + 2360320);
  ushort* Tl1  = (ushort*)(ws + 2491392);
  ushort* Tth1 = (ushort*)(ws + 2622464);
  ushort* Ttl1 = (ushort*)(ws + 2753536);
  ushort* Qh0  = (ushort*)(ws + 2884608);
  ushort* Ql0  = (ushort*)(ws + 2950144);
  ushort* Qh1  = (ushort*)(ws + 3015680);
  ushort* Ql1  = (ushort*)(ws + 3081216);
  ushort* FmTh = (ushort*)(ws + 3146752);
  ushort* FmTl = (ushort*)(ws + 3277824);
  ushort* B1Th = (ushort*)(ws + 3408896);
  ushort* B1Tl = (ushort*)(ws + 3539968);
  ushort* B2Th = (ushort*)(ws + 3671040);
  ushort* B2Tl = (ushort*)(ws + 3736576);
  float*  P1   = ws + 3802112;
  ushort* P2h  = (ushort*)(ws + 3933184);
  ushort* P2l  = (ushort*)(ws + 3998720);
  ushort* P3h  = (ushort*)(ws + 4064256);
  ushort* P3l  = (ushort*)(ws + 4097024);
  ushort* D12h = (ushort*)(ws + 4129792);
  ushort* D12l = (ushort*)(ws + 4195328);
  ushort* uh   = (ushort*)(ws + 4260864);
  ushort* ul   = (ushort*)(ws + 5309440);
  float*  abuf = ws + 6358016;
  ushort* wh   = (ushort*)(ws + 10552320);
  ushort* wl   = (ushort*)(ws + 12649472);
  // Xt splits alias the wh/wl region (dead before k_scan writes wh/wl)
  ushort* Xth  = (ushort*)(ws + 10552320);
  ushort* Xtl  = (ushort*)(ws + 11731968);

  hipMemsetAsync(flag, 0, 4, stream);
  k_anynz<<<256, 256, 0, stream>>>(x0, 8192 * 512 / 4, flag);

  // transpose+split X -> Xt hi/lo; B2 -> B2T hi/lo; plain split u, D12
  k_tsplit<<<dim3(48, 48), 256, 0, stream>>>(X, Xth, Xtl, 1536, 1536);
  k_tsplit<<<dim3(8, 16), 256, 0, stream>>>(B2, B2Th, B2Tl, 512, 256);
  k_split2<<<2048, 256, 0, stream>>>(u, uh, ul, 524288, D12, D12h, D12l, 32768);

  // all 6 H-blocks via MFMA (E, C1, D11 fp32+h/l + Lam, FmT h/l, B1T h/l)
  k_xtxm<<<dim3(8, 8, 5), 256, 0, stream>>>(Xth, Xtl, Y, E, C1,
                                            D11, D11h, D11l, Lam,
                                            FmTh, FmTl, B1Th, B1Tl);

  // abuf = u @ D12^T (MFMA); + x0 @ C1^T if flag
  k_ntm<1><<<dim3(128, 8), 256, 0, stream>>>(uh, ul, D12h, D12l, 256,
                                             nullptr, nullptr, nullptr, nullptr, 0,
                                             abuf, 512);
  k_ntadd<<<dim3(128, 8), 256, 0, stream>>>(x0, C1, 512, flag, abuf, 512);

  // Newton-Schulz on (T, Q) via MFMA: 5 x {T,Q} + 1 final Q-only
  k_nsinit<<<384, 256, 0, stream>>>(E, C2, Tf0, Th0, Tl0, Tth0, Ttl0, Qf0, Qh0, Ql0);
  ushort *Tha[2] = {Th0, Th1}, *Tla[2] = {Tl0, Tl1};
  ushort *Ttha[2] = {Tth0, Tth1}, *Ttla[2] = {Ttl0, Ttl1};
  ushort *Qha[2] = {Qh0, Qh1}, *Qla[2] = {Ql0, Ql1};
  float *Tfa[2] = {Tf0, Tf1}, *Qfa[2] = {Qf0, Qf1};
  int cur = 0;
  for (int it = 0; it < 5; ++it) {
    int nxt = cur ^ 1;
    k_nsm<true><<<dim3(8, 12), 256, 0, stream>>>(
        Tha[cur], Tla[cur], Ttha[cur], Ttla[cur], Qha[cur], Qla[cur],
        Tfa[cur], Qfa[cur],
        Tfa[nxt], Tha[nxt], Tla[nxt], Ttha[nxt], Ttla[nxt],
        Qfa[nxt], Qha[nxt], Qla[nxt]);
    cur = nxt;
  }
  int nxt = cur ^ 1;
  k_nsm<false><<<dim3(8, 4), 256, 0, stream>>>(
      Tha[cur], Tla[cur], Ttha[cur], Ttla[cur], Qha[cur], Qla[cur],
      Tfa[cur], Qfa[cur],
      Tfa[nxt], Tha[nxt], Tla[nxt], Ttha[nxt], Ttla[nxt],
      Qfa[nxt], Qha[nxt], Qla[nxt]);
  ushort* Qh = Qha[nxt];
  ushort* Ql = Qla[nxt];

  // folds: P1 fp32, P2/P3 hi/lo (MFMA)
  k_foldm<<<dim3(8, 4, 3), 256, 0, stream>>>(Qh, Ql, FmTh, FmTl, B1Th, B1Tl,
                                             B2Th, B2Tl, D21, D22,
                                             P1, P2h, P2l, P3h, P3l);

  // scan -> w (bf16 hi/lo), history via MFMA
  k_scan<<<512, 512, 0, stream>>>(abuf, D11, D11h, D11l, Lam, wh, wl);

  // y = w @ P2^T + u @ P3^T (MFMA); + x0 @ P1^T if flag
  k_ntm<2><<<dim3(128, 4), 256, 0, stream>>>(wh, wl, P2h, P2l, 512,
                                             uh, ul, P3h, P3l, 256,
                                             out, 256);
  k_ntadd<<<dim3(128, 4), 256, 0, stream>>>(x0, P1, 512, flag, out, 256);
}

// Round 7
// 374.692 us; speedup vs baseline: 2.9205x; 1.0858x over previous
//
#include <hip/hip_runtime.h>
#include <cstdint>
#include <cstddef>

#define EPSC 0.001f

typedef __attribute__((ext_vector_type(8))) short short8;
typedef __attribute__((ext_vector_type(4))) float f32x4;

__device__ inline void bsplit(float f, ushort& h, ushort& l) {
  uint b = __float_as_uint(f);
  h = (ushort)(b >> 16);
  float r = f - __uint_as_float(b & 0xFFFF0000u);
  l = (ushort)(__float_as_uint(r) >> 16);
}

// ---------------------------------------------------------------- any-nonzero
__global__ void k_anynz(const float* __restrict__ x, int n4, int* __restrict__ flag) {
  int i = blockIdx.x * blockDim.x + threadIdx.x;
  int stride = gridDim.x * blockDim.x;
  int found = 0;
  for (; i < n4; i += stride) {
    float4 v = ((const float4*)x)[i];
    if (v.x != 0.f || v.y != 0.f || v.z != 0.f || v.w != 0.f) { found = 1; break; }
  }
  if (found) atomicOr(flag, 1);
}

// ---------------------------------------------------------------- transpose + bf16 split: dst[C x R] = src[R x C]^T
__global__ __launch_bounds__(256) void k_tsplit(const float* __restrict__ src,
    ushort* __restrict__ dh, ushort* __restrict__ dl, int R, int C)
{
  __shared__ float t[32][33];
  const int c0 = blockIdx.x * 32, r0 = blockIdx.y * 32;
  const int tid = threadIdx.x;
  const int lr = tid >> 3, lc4 = (tid & 7) * 4;
  float4 v = *(const float4*)(src + (size_t)(r0 + lr) * C + c0 + lc4);
  t[lr][lc4 + 0] = v.x; t[lr][lc4 + 1] = v.y;
  t[lr][lc4 + 2] = v.z; t[lr][lc4 + 3] = v.w;
  __syncthreads();
  ushort4 hv, lv;
  float f;
  f = t[lc4 + 0][lr]; bsplit(f, hv.x, lv.x);
  f = t[lc4 + 1][lr]; bsplit(f, hv.y, lv.y);
  f = t[lc4 + 2][lr]; bsplit(f, hv.z, lv.z);
  f = t[lc4 + 3][lr]; bsplit(f, hv.w, lv.w);
  size_t off = (size_t)(c0 + lr) * R + r0 + lc4;
  *(ushort4*)(dh + off) = hv;
  *(ushort4*)(dl + off) = lv;
}

// ---------------------------------------------------------------- plain bf16 split (2 segments)
__global__ void k_split2(const float* __restrict__ s0, ushort* __restrict__ h0,
                         ushort* __restrict__ l0, int c0,
                         const float* __restrict__ s1, ushort* __restrict__ h1,
                         ushort* __restrict__ l1, int c1)
{
  int i = blockIdx.x * 256 + threadIdx.x;
  int tot = c0 + c1;
  int stride = gridDim.x * 256;
  for (; i < tot; i += stride) {
    const float* s; ushort* h; ushort* l; int k;
    if (i < c0) { s = s0; h = h0; l = l0; k = i; }
    else        { s = s1; h = h1; l = l1; k = i - c0; }
    float4 v = ((const float4*)s)[k];
    ushort4 hv, lv;
    bsplit(v.x, hv.x, lv.x);
    bsplit(v.y, hv.y, lv.y);
    bsplit(v.z, hv.z, lv.z);
    bsplit(v.w, hv.w, lv.w);
    ((ushort4*)h)[k] = hv;
    ((ushort4*)l)[k] = lv;
  }
}

// ---------------------------------------------------------------- MFMA XtX: 6 H-blocks from Xt splits
// z=0: E=0.5(H11+H33+Y-Y^T)+epsI ; z=1: C1=-H21 ; z=2: D11 (fp32 + h/l splits) + Lam ;
// z=3: FmT=H13 (hi/lo) ; z=4: B1T=H23 (hi/lo)
__global__ __launch_bounds__(256) void k_xtxm(
    const ushort* __restrict__ Xth, const ushort* __restrict__ Xtl,
    const float* __restrict__ Y,
    float* __restrict__ E, float* __restrict__ C1,
    float* __restrict__ D11, ushort* __restrict__ D11h, ushort* __restrict__ D11l,
    float* __restrict__ Lam,
    ushort* __restrict__ FmTh, ushort* __restrict__ FmTl,
    ushort* __restrict__ B1Th, ushort* __restrict__ B1Tl)
{
  __shared__ ushort sAh[64][40], sAl[64][40], sBh[64][40], sBl[64][40];
  const int z = blockIdx.z;
  int aOff[2], bOff[2], nops;
  switch (z) {
    case 0:  aOff[0] = 0;    bOff[0] = 0;    aOff[1] = 1024; bOff[1] = 1024; nops = 2; break;
    case 1:  aOff[0] = 512;  bOff[0] = 0;    nops = 1; break;
    case 2:  aOff[0] = 512;  bOff[0] = 512;  nops = 1; break;
    case 3:  aOff[0] = 0;    bOff[0] = 1024; nops = 1; break;
    default: aOff[0] = 512;  bOff[0] = 1024; nops = 1; break;
  }
  const int tid = threadIdx.x;
  const int m0 = blockIdx.x * 64, n0 = blockIdx.y * 64;
  const int wid = tid >> 6, lane = tid & 63;
  const int wr = wid >> 1, wc = wid & 1;
  const int fr = lane & 15, fg = lane >> 4;
  const int srow = tid >> 2;
  const int sko = (tid & 3) * 8;
  f32x4 acc[2][2] = {};
  const int K = 1536;

  for (int op = 0; op < nops; ++op) {
    const ushort* Ah = Xth + (size_t)(aOff[op]) * K;
    const ushort* Al = Xtl + (size_t)(aOff[op]) * K;
    const ushort* Bh = Xth + (size_t)(bOff[op]) * K;
    const ushort* Bl = Xtl + (size_t)(bOff[op]) * K;
    uint4 pah = *(const uint4*)(Ah + (size_t)(m0 + srow) * K + sko);
    uint4 pal = *(const uint4*)(Al + (size_t)(m0 + srow) * K + sko);
    uint4 pbh = *(const uint4*)(Bh + (size_t)(n0 + srow) * K + sko);
    uint4 pbl = *(const uint4*)(Bl + (size_t)(n0 + srow) * K + sko);
    for (int k0 = 0; k0 < K; k0 += 32) {
      __syncthreads();
      *(uint4*)&sAh[srow][sko] = pah;
      *(uint4*)&sAl[srow][sko] = pal;
      *(uint4*)&sBh[srow][sko] = pbh;
      *(uint4*)&sBl[srow][sko] = pbl;
      __syncthreads();
      if (k0 + 32 < K) {
        pah = *(const uint4*)(Ah + (size_t)(m0 + srow) * K + k0 + 32 + sko);
        pal = *(const uint4*)(Al + (size_t)(m0 + srow) * K + k0 + 32 + sko);
        pbh = *(const uint4*)(Bh + (size_t)(n0 + srow) * K + k0 + 32 + sko);
        pbl = *(const uint4*)(Bl + (size_t)(n0 + srow) * K + k0 + 32 + sko);
      }
      short8 fah[2], fal[2], fbh[2], fbl[2];
#pragma unroll
      for (int s = 0; s < 2; ++s) {
        fah[s] = *(const short8*)&sAh[wr * 32 + s * 16 + fr][fg * 8];
        fal[s] = *(const short8*)&sAl[wr * 32 + s * 16 + fr][fg * 8];
        fbh[s] = *(const short8*)&sBh[wc * 32 + s * 16 + fr][fg * 8];
        fbl[s] = *(const short8*)&sBl[wc * 32 + s * 16 + fr][fg * 8];
      }
#pragma unroll
      for (int i = 0; i < 2; ++i)
#pragma unroll
        for (int j = 0; j < 2; ++j) {
          acc[i][j] = __builtin_amdgcn_mfma_f32_16x16x32_bf16(fah[i], fbh[j], acc[i][j], 0, 0, 0);
          acc[i][j] = __builtin_amdgcn_mfma_f32_16x16x32_bf16(fah[i], fbl[j], acc[i][j], 0, 0, 0);
          acc[i][j] = __builtin_amdgcn_mfma_f32_16x16x32_bf16(fal[i], fbh[j], acc[i][j], 0, 0, 0);
        }
    }
  }

#pragma unroll
  for (int i = 0; i < 2; ++i)
#pragma unroll
    for (int j = 0; j < 2; ++j) {
      int rbase = m0 + wr * 32 + i * 16 + fg * 4;
      int cc = n0 + wc * 32 + j * 16 + fr;
#pragma unroll
      for (int q = 0; q < 4; ++q) {
        int rr = rbase + q;
        float d = acc[i][j][q];
        size_t idx = (size_t)rr * 512 + cc;
        if (z == 0) {
          float o = 0.5f * (d + Y[idx] - Y[(size_t)cc * 512 + rr]);
          if (rr == cc) o += EPSC;
          E[idx] = o;
        } else if (z == 1) {
          C1[idx] = -d;
        } else if (z == 2) {
          float o = (cc < rr) ? -d : 0.f;
          D11[idx] = o;
          ushort h, l; bsplit(o, h, l);
          D11h[idx] = h; D11l[idx] = l;
          if (rr == cc) Lam[rr] = 0.5f * (d + EPSC);
        } else if (z == 3) {
          ushort h, l; bsplit(d, h, l);
          FmTh[idx] = h; FmTl[idx] = l;
        } else {
          ushort h, l; bsplit(d, h, l);
          B1Th[idx] = h; B1Tl[idx] = l;
        }
      }
    }
}

// ---------------------------------------------------------------- NS init: T0=E*diag(s), Q0=C2*diag(s), s=0.85/diag(E)
__global__ void k_nsinit(const float* __restrict__ E, const float* __restrict__ C2,
    float* __restrict__ Tf, ushort* __restrict__ Th, ushort* __restrict__ Tl,
    ushort* __restrict__ Tth, ushort* __restrict__ Ttl,
    float* __restrict__ Qf, ushort* __restrict__ Qh, ushort* __restrict__ Ql)
{
  int g = blockIdx.x * 256 + threadIdx.x;   // 768 rows x 128 quads
  int row = g >> 7;
  int c4 = (g & 127) << 2;
  float s0 = 0.85f / E[(size_t)(c4 + 0) * 513];
  float s1 = 0.85f / E[(size_t)(c4 + 1) * 513];
  float s2 = 0.85f / E[(size_t)(c4 + 2) * 513];
  float s3 = 0.85f / E[(size_t)(c4 + 3) * 513];
  if (row < 512) {
    float4 v = *(const float4*)(E + (size_t)row * 512 + c4);
    v.x *= s0; v.y *= s1; v.z *= s2; v.w *= s3;
    *(float4*)(Tf + (size_t)row * 512 + c4) = v;
    ushort4 hv, lv;
    bsplit(v.x, hv.x, lv.x); bsplit(v.y, hv.y, lv.y);
    bsplit(v.z, hv.z, lv.z); bsplit(v.w, hv.w, lv.w);
    *(ushort4*)(Th + (size_t)row * 512 + c4) = hv;
    *(ushort4*)(Tl + (size_t)row * 512 + c4) = lv;
    Tth[(size_t)(c4 + 0) * 512 + row] = hv.x; Ttl[(size_t)(c4 + 0) * 512 + row] = lv.x;
    Tth[(size_t)(c4 + 1) * 512 + row] = hv.y; Ttl[(size_t)(c4 + 1) * 512 + row] = lv.y;
    Tth[(size_t)(c4 + 2) * 512 + row] = hv.z; Ttl[(size_t)(c4 + 2) * 512 + row] = lv.z;
    Tth[(size_t)(c4 + 3) * 512 + row] = hv.w; Ttl[(size_t)(c4 + 3) * 512 + row] = lv.w;
  } else {
    int qr = row - 512;
    float4 v = *(const float4*)(C2 + (size_t)qr * 512 + c4);
    v.x *= s0; v.y *= s1; v.z *= s2; v.w *= s3;
    *(float4*)(Qf + (size_t)qr * 512 + c4) = v;
    ushort4 hv, lv;
    bsplit(v.x, hv.x, lv.x); bsplit(v.y, hv.y, lv.y);
    bsplit(v.z, hv.z, lv.z); bsplit(v.w, hv.w, lv.w);
    *(ushort4*)(Qh + (size_t)qr * 512 + c4) = hv;
    *(ushort4*)(Ql + (size_t)qr * 512 + c4) = lv;
  }
}

// ---------------------------------------------------------------- MFMA NS step: Tn=2T-T*T ; Qn=2Q-Q*T (NT vs Tt splits)
template <bool WITH_T>
__global__ __launch_bounds__(256) void k_nsm(
    const ushort* __restrict__ Th, const ushort* __restrict__ Tl,
    const ushort* __restrict__ Tth, const ushort* __restrict__ Ttl,
    const ushort* __restrict__ Qh, const ushort* __restrict__ Ql,
    const float* __restrict__ Tprev, const float* __restrict__ Qprev,
    float* __restrict__ Tnext, ushort* __restrict__ Thn, ushort* __restrict__ Tln,
    ushort* __restrict__ Tthn, ushort* __restrict__ Ttln,
    float* __restrict__ Qnext, ushort* __restrict__ Qhn, ushort* __restrict__ Qln)
{
  __shared__ ushort sAh[64][40], sAl[64][40], sBh[64][40], sBl[64][40];
  const int tid = threadIdx.x;
  const int yy = blockIdx.y;
  const bool isT = WITH_T && (yy < 8);
  const int m0 = (isT ? yy : (yy - (WITH_T ? 8 : 0))) * 64;
  const int n0 = blockIdx.x * 64;
  const ushort* Ah = isT ? Th : Qh;
  const ushort* Al = isT ? Tl : Ql;
  const int wid = tid >> 6, lane = tid & 63;
  const int wr = wid >> 1, wc = wid & 1;
  const int fr = lane & 15, fg = lane >> 4;
  const int srow = tid >> 2;
  const int sko = (tid & 3) * 8;
  const int K = 512;
  f32x4 acc[2][2] = {};

  uint4 pah = *(const uint4*)(Ah + (size_t)(m0 + srow) * K + sko);
  uint4 pal = *(const uint4*)(Al + (size_t)(m0 + srow) * K + sko);
  uint4 pbh = *(const uint4*)(Tth + (size_t)(n0 + srow) * K + sko);
  uint4 pbl = *(const uint4*)(Ttl + (size_t)(n0 + srow) * K + sko);
  for (int k0 = 0; k0 < K; k0 += 32) {
    __syncthreads();
    *(uint4*)&sAh[srow][sko] = pah;
    *(uint4*)&sAl[srow][sko] = pal;
    *(uint4*)&sBh[srow][sko] = pbh;
    *(uint4*)&sBl[srow][sko] = pbl;
    __syncthreads();
    if (k0 + 32 < K) {
      pah = *(const uint4*)(Ah + (size_t)(m0 + srow) * K + k0 + 32 + sko);
      pal = *(const uint4*)(Al + (size_t)(m0 + srow) * K + k0 + 32 + sko);
      pbh = *(const uint4*)(Tth + (size_t)(n0 + srow) * K + k0 + 32 + sko);
      pbl = *(const uint4*)(Ttl + (size_t)(n0 + srow) * K + k0 + 32 + sko);
    }
    short8 fah[2], fal[2], fbh[2], fbl[2];
#pragma unroll
    for (int s = 0; s < 2; ++s) {
      fah[s] = *(const short8*)&sAh[wr * 32 + s * 16 + fr][fg * 8];
      fal[s] = *(const short8*)&sAl[wr * 32 + s * 16 + fr][fg * 8];
      fbh[s] = *(const short8*)&sBh[wc * 32 + s * 16 + fr][fg * 8];
      fbl[s] = *(const short8*)&sBl[wc * 32 + s * 16 + fr][fg * 8];
    }
#pragma unroll
    for (int i = 0; i < 2; ++i)
#pragma unroll
      for (int j = 0; j < 2; ++j) {
        acc[i][j] = __builtin_amdgcn_mfma_f32_16x16x32_bf16(fah[i], fbh[j], acc[i][j], 0, 0, 0);
        acc[i][j] = __builtin_amdgcn_mfma_f32_16x16x32_bf16(fah[i], fbl[j], acc[i][j], 0, 0, 0);
        acc[i][j] = __builtin_amdgcn_mfma_f32_16x16x32_bf16(fal[i], fbh[j], acc[i][j], 0, 0, 0);
      }
  }

#pragma unroll
  for (int i = 0; i < 2; ++i)
#pragma unroll
    for (int j = 0; j < 2; ++j) {
      int rbase = m0 + wr * 32 + i * 16 + fg * 4;
      int cc = n0 + wc * 32 + j * 16 + fr;
#pragma unroll
      for (int q = 0; q < 4; ++q) {
        int rr = rbase + q;
        size_t idx = (size_t)rr * 512 + cc;
        ushort h, l;
        if (isT) {
          float tn = 2.f * Tprev[idx] - acc[i][j][q];
          Tnext[idx] = tn;
          bsplit(tn, h, l);
          Thn[idx] = h; Tln[idx] = l;
          Tthn[(size_t)cc * 512 + rr] = h; Ttln[(size_t)cc * 512 + rr] = l;
        } else {
          float qn = 2.f * Qprev[idx] - acc[i][j][q];
          Qnext[idx] = qn;
          bsplit(qn, h, l);
          Qhn[idx] = h; Qln[idx] = l;
        }
      }
    }
}

// ---------------------------------------------------------------- MFMA folds: P1=Q*Fm (fp32) ; P2=Q*B1+D21 (h/l) ; P3=Q*B2+D22 (h/l)
__global__ __launch_bounds__(256) void k_foldm(
    const ushort* __restrict__ Qh, const ushort* __restrict__ Ql,
    const ushort* __restrict__ FmTh, const ushort* __restrict__ FmTl,
    const ushort* __restrict__ B1Th, const ushort* __restrict__ B1Tl,
    const ushort* __restrict__ B2Th, const ushort* __restrict__ B2Tl,
    const float* __restrict__ D21, const float* __restrict__ D22,
    float* __restrict__ P1, ushort* __restrict__ P2h, ushort* __restrict__ P2l,
    ushort* __restrict__ P3h, ushort* __restrict__ P3l)
{
  __shared__ ushort sAh[64][40], sAl[64][40], sBh[64][40], sBl[64][40];
  const int z = blockIdx.z;
  const int N = (z == 2) ? 256 : 512;
  const int n0 = blockIdx.x * 64;
  if (n0 >= N) return;
  const ushort* Bh = (z == 0) ? FmTh : (z == 1) ? B1Th : B2Th;
  const ushort* Bl = (z == 0) ? FmTl : (z == 1) ? B1Tl : B2Tl;
  const int tid = threadIdx.x;
  const int m0 = blockIdx.y * 64;
  const int wid = tid >> 6, lane = tid & 63;
  const int wr = wid >> 1, wc = wid & 1;
  const int fr = lane & 15, fg = lane >> 4;
  const int srow = tid >> 2;
  const int sko = (tid & 3) * 8;
  const int K = 512;
  f32x4 acc[2][2] = {};

  uint4 pah = *(const uint4*)(Qh + (size_t)(m0 + srow) * K + sko);
  uint4 pal = *(const uint4*)(Ql + (size_t)(m0 + srow) * K + sko);
  uint4 pbh = *(const uint4*)(Bh + (size_t)(n0 + srow) * K + sko);
  uint4 pbl = *(const uint4*)(Bl + (size_t)(n0 + srow) * K + sko);
  for (int k0 = 0; k0 < K; k0 += 32) {
    __syncthreads();
    *(uint4*)&sAh[srow][sko] = pah;
    *(uint4*)&sAl[srow][sko] = pal;
    *(uint4*)&sBh[srow][sko] = pbh;
    *(uint4*)&sBl[srow][sko] = pbl;
    __syncthreads();
    if (k0 + 32 < K) {
      pah = *(const uint4*)(Qh + (size_t)(m0 + srow) * K + k0 + 32 + sko);
      pal = *(const uint4*)(Ql + (size_t)(m0 + srow) * K + k0 + 32 + sko);
      pbh = *(const uint4*)(Bh + (size_t)(n0 + srow) * K + k0 + 32 + sko);
      pbl = *(const uint4*)(Bl + (size_t)(n0 + srow) * K + k0 + 32 + sko);
    }
    short8 fah[2], fal[2], fbh[2], fbl[2];
#pragma unroll
    for (int s = 0; s < 2; ++s) {
      fah[s] = *(const short8*)&sAh[wr * 32 + s * 16 + fr][fg * 8];
      fal[s] = *(const short8*)&sAl[wr * 32 + s * 16 + fr][fg * 8];
      fbh[s] = *(const short8*)&sBh[wc * 32 + s * 16 + fr][fg * 8];
      fbl[s] = *(const short8*)&sBl[wc * 32 + s * 16 + fr][fg * 8];
    }
#pragma unroll
    for (int i = 0; i < 2; ++i)
#pragma unroll
      for (int j = 0; j < 2; ++j) {
        acc[i][j] = __builtin_amdgcn_mfma_f32_16x16x32_bf16(fah[i], fbh[j], acc[i][j], 0, 0, 0);
        acc[i][j] = __builtin_amdgcn_mfma_f32_16x16x32_bf16(fah[i], fbl[j], acc[i][j], 0, 0, 0);
        acc[i][j] = __builtin_amdgcn_mfma_f32_16x16x32_bf16(fal[i], fbh[j], acc[i][j], 0, 0, 0);
      }
  }

#pragma unroll
  for (int i = 0; i < 2; ++i)
#pragma unroll
    for (int j = 0; j < 2; ++j) {
      int rbase = m0 + wr * 32 + i * 16 + fg * 4;
      int cc = n0 + wc * 32 + j * 16 + fr;
#pragma unroll
      for (int q = 0; q < 4; ++q) {
        int rr = rbase + q;
        float d = acc[i][j][q];
        if (z == 0) {
          P1[(size_t)rr * 512 + cc] = d;
        } else if (z == 1) {
          size_t idx = (size_t)rr * 512 + cc;
          float p = d + D21[idx];
          ushort h, l; bsplit(p, h, l);
          P2h[idx] = h; P2l[idx] = l;
        } else {
          size_t idx = (size_t)rr * 256 + cc;
          float p = d + D22[idx];
          ushort h, l; bsplit(p, h, l);
          P3h[idx] = h; P3l[idx] = l;
        }
      }
    }
}

// ---------------------------------------------------------------- MFMA NT GEMM, split-bf16 3-pass (batch)
template <int NOPS>
__global__ __launch_bounds__(256) void k_ntm(
    const ushort* __restrict__ Ah0, const ushort* __restrict__ Al0,
    const ushort* __restrict__ Bh0, const ushort* __restrict__ Bl0, int K0,
    const ushort* __restrict__ Ah1, const ushort* __restrict__ Al1,
    const ushort* __restrict__ Bh1, const ushort* __restrict__ Bl1, int K1,
    float* __restrict__ C, int ldc)
{
  __shared__ ushort sAh[64][40], sAl[64][40], sBh[64][40], sBl[64][40];
  const int tid = threadIdx.x;
  const int m0 = blockIdx.x * 64, n0 = blockIdx.y * 64;
  const int wid = tid >> 6, lane = tid & 63;
  const int wr = wid >> 1, wc = wid & 1;
  const int fr = lane & 15, fg = lane >> 4;
  const int srow = tid >> 2;
  const int sko = (tid & 3) * 8;
  f32x4 acc[2][2] = {};

#pragma unroll
  for (int op = 0; op < NOPS; ++op) {
    const ushort* Ah = (op == 0) ? Ah0 : Ah1;
    const ushort* Al = (op == 0) ? Al0 : Al1;
    const ushort* Bh = (op == 0) ? Bh0 : Bh1;
    const ushort* Bl = (op == 0) ? Bl0 : Bl1;
    const int K = (op == 0) ? K0 : K1;
    uint4 pah = *(const uint4*)(Ah + (size_t)(m0 + srow) * K + sko);
    uint4 pal = *(const uint4*)(Al + (size_t)(m0 + srow) * K + sko);
    uint4 pbh = *(const uint4*)(Bh + (size_t)(n0 + srow) * K + sko);
    uint4 pbl = *(const uint4*)(Bl + (size_t)(n0 + srow) * K + sko);
    for (int k0 = 0; k0 < K; k0 += 32) {
      __syncthreads();
      *(uint4*)&sAh[srow][sko] = pah;
      *(uint4*)&sAl[srow][sko] = pal;
      *(uint4*)&sBh[srow][sko] = pbh;
      *(uint4*)&sBl[srow][sko] = pbl;
      __syncthreads();
      if (k0 + 32 < K) {
        pah = *(const uint4*)(Ah + (size_t)(m0 + srow) * K + k0 + 32 + sko);
        pal = *(const uint4*)(Al + (size_t)(m0 + srow) * K + k0 + 32 + sko);
        pbh = *(const uint4*)(Bh + (size_t)(n0 + srow) * K + k0 + 32 + sko);
        pbl = *(const uint4*)(Bl + (size_t)(n0 + srow) * K + k0 + 32 + sko);
      }
      short8 fah[2], fal[2], fbh[2], fbl[2];
#pragma unroll
      for (int s = 0; s < 2; ++s) {
        fah[s] = *(const short8*)&sAh[wr * 32 + s * 16 + fr][fg * 8];
        fal[s] = *(const short8*)&sAl[wr * 32 + s * 16 + fr][fg * 8];
        fbh[s] = *(const short8*)&sBh[wc * 32 + s * 16 + fr][fg * 8];
        fbl[s] = *(const short8*)&sBl[wc * 32 + s * 16 + fr][fg * 8];
      }
#pragma unroll
      for (int i = 0; i < 2; ++i)
#pragma unroll
        for (int j = 0; j < 2; ++j) {
          acc[i][j] = __builtin_amdgcn_mfma_f32_16x16x32_bf16(fah[i], fbh[j], acc[i][j], 0, 0, 0);
          acc[i][j] = __builtin_amdgcn_mfma_f32_16x16x32_bf16(fah[i], fbl[j], acc[i][j], 0, 0, 0);
          acc[i][j] = __builtin_amdgcn_mfma_f32_16x16x32_bf16(fal[i], fbh[j], acc[i][j], 0, 0, 0);
        }
    }
  }

#pragma unroll
  for (int i = 0; i < 2; ++i)
#pragma unroll
    for (int j = 0; j < 2; ++j) {
      int rr = m0 + wr * 32 + i * 16 + fg * 4;
      int cc = n0 + wc * 32 + j * 16 + fr;
#pragma unroll
      for (int q = 0; q < 4; ++q)
        C[(size_t)(rr + q) * ldc + cc] = acc[i][j][q];
    }
}

// ---------------------------------------------------------------- flag-gated fp32 NT accumulate (x0 terms)
__global__ __launch_bounds__(256) void k_ntadd(const float* __restrict__ A,
    const float* __restrict__ B, int K, const int* __restrict__ flag,
    float* __restrict__ C, int ldc)
{
  if (*flag == 0) return;
  __shared__ float As[16][68];
  __shared__ float Bs[16][68];
  const int tid = threadIdx.x;
  const int tx = tid & 15, ty = tid >> 4;
  const int m0 = blockIdx.x * 64, n0 = blockIdx.y * 64;
  const int lr = tid >> 2;
  const int lk = (tid & 3) * 4;
  float acc[4][4];
#pragma unroll
  for (int i = 0; i < 4; ++i)
#pragma unroll
    for (int j = 0; j < 4; ++j) acc[i][j] = 0.f;
  float4 av = *(const float4*)(A + (size_t)(m0 + lr) * K + lk);
  float4 bv = *(const float4*)(B + (size_t)(n0 + lr) * K + lk);
  for (int k0 = 0; k0 < K; k0 += 16) {
    __syncthreads();
    As[lk + 0][lr] = av.x; As[lk + 1][lr] = av.y;
    As[lk + 2][lr] = av.z; As[lk + 3][lr] = av.w;
    Bs[lk + 0][lr] = bv.x; Bs[lk + 1][lr] = bv.y;
    Bs[lk + 2][lr] = bv.z; Bs[lk + 3][lr] = bv.w;
    __syncthreads();
    if (k0 + 16 < K) {
      av = *(const float4*)(A + (size_t)(m0 + lr) * K + k0 + 16 + lk);
      bv = *(const float4*)(B + (size_t)(n0 + lr) * K + k0 + 16 + lk);
    }
#pragma unroll
    for (int kk = 0; kk < 16; ++kk) {
      float4 a4 = *(const float4*)&As[kk][4 * ty];
      float4 b4 = *(const float4*)&Bs[kk][4 * tx];
      float ar[4] = {a4.x, a4.y, a4.z, a4.w};
      float br[4] = {b4.x, b4.y, b4.z, b4.w};
#pragma unroll
      for (int i = 0; i < 4; ++i)
#pragma unroll
        for (int j = 0; j < 4; ++j)
          acc[i][j] = fmaf(ar[i], br[j], acc[i][j]);
    }
  }
#pragma unroll
  for (int i = 0; i < 4; ++i) {
    float* p = C + (size_t)(m0 + 4 * ty + i) * ldc + n0 + 4 * tx;
    float4 v = *(float4*)p;
    v.x += acc[i][0]; v.y += acc[i][1]; v.z += acc[i][2]; v.w += acc[i][3];
    *(float4*)p = v;
  }
}

// ---------------------------------------------------------------- blocked tanh scan (v6: 4-group triangle + pipelined MFMA history)
// 512 blocks x 16 rows, 512 threads (8 waves).
// wave 0 (all 64 lanes): serial tanh triangle; lane = r + 16*g; group g owns s[8g..8g+8).
//   Per il: all lanes compute candidate w2, shfl-broadcast from owner group, 8 branchless
//   FMAs/lane (zero multipliers from strict-lower D11 make masking unneeded).
//   Multiplier column double-buffered in registers (LDS latency off the chain).
// waves 1-6: MFMA history partials for S(t+1), K-steps software-pipelined.
// wave 7 : stage doff(t+1,t), dblkT(t+1), ablk(t+1).
// combine: S(t+1) = ablk + sum(shist) + doff * wcur.
__global__ __launch_bounds__(512, 4) void k_scan(const float* __restrict__ a,
    const float* __restrict__ D11,
    const ushort* __restrict__ D11h, const ushort* __restrict__ D11l,
    const float* __restrict__ Lam, ushort* __restrict__ wh, ushort* __restrict__ wl)
{
  __shared__ ushort wth[16][520];     // [row r][step k] bf16-hi of w (+8 pad)
  __shared__ ushort wtl[16][520];     // bf16-lo
  __shared__ float wcur[32][17];      // fp32 w of current block t
  __shared__ float sblk[32][17];      // S(t) for triangle
  __shared__ float shist[6][32][17];  // MFMA hist partials
  __shared__ float dblkT[2][32][33];  // diag block: dblkT[x][y] = D11[blk+y][blk+x]
  __shared__ float doff[32][33];      // off-diag rows block t+1, cols block t
  __shared__ float ablk[32][17];      // a block t+1
  __shared__ float rl2[512];          // 2/Lam
  const int tid = threadIdx.x;
  const int row0 = blockIdx.x * 16;

  rl2[tid] = 2.f / Lam[tid];
  if (tid < 128) {
    int rr = tid >> 3, cq = (tid & 7) * 4;
    float4 v = *(const float4*)(a + (size_t)(row0 + rr) * 512 + cq);
    sblk[cq + 0][rr] = v.x; sblk[cq + 1][rr] = v.y;
    sblk[cq + 2][rr] = v.z; sblk[cq + 3][rr] = v.w;
  } else if (tid < 384) {
    int f = tid - 128;
    int rr = f >> 3, cq = (f & 7) * 4;
    float4 v = *(const float4*)(D11 + (size_t)rr * 512 + cq);
    dblkT[0][cq + 0][rr] = v.x; dblkT[0][cq + 1][rr] = v.y;
    dblkT[0][cq + 2][rr] = v.z; dblkT[0][cq + 3][rr] = v.w;
  }
  __syncthreads();

  const int wv = tid >> 6;
  const int lane = tid & 63;
  const int fr = lane & 15, fg = lane >> 4;

  for (int t = 0; t < 16; ++t) {
    const int c0 = 32 * t;
    const int jend2 = c0 + 32;
    if (wv == 0) {
      // ---- triangle, all 64 lanes: r = fr (batch row), g = fg (j-octet)
      const int r = fr, g = fg;
      const int tb = t & 1;
      float so[8];
#pragma unroll
      for (int k = 0; k < 8; ++k) so[k] = sblk[8 * g + k][r];
      float4 ca = *(const float4*)&dblkT[tb][0][8 * g];
      float4 cb = *(const float4*)&dblkT[tb][0][8 * g + 4];
      float rln = rl2[c0];
#pragma unroll
      for (int il = 0; il < 32; ++il) {
        float4 na, nb; float rlnn;
        if (il < 31) {
          na = *(const float4*)&dblkT[tb][il + 1][8 * g];
          nb = *(const float4*)&dblkT[tb][il + 1][8 * g + 4];
          rlnn = rl2[c0 + il + 1];
        }
        float x2 = so[il & 7] * rln;
        float e = __expf(x2);
        float w2 = 1.f - 2.f * __builtin_amdgcn_rcpf(e + 1.f);
        const int go = il >> 3;
        float w2b = __shfl(w2, r + (go << 4));
        if (g == go) {
          wcur[il][r] = w2b;
          ushort hh, ll; bsplit(w2b, hh, ll);
          wth[r][c0 + il] = hh;
          wtl[r][c0 + il] = ll;
        }
        so[0] = fmaf(ca.x, w2b, so[0]);
        so[1] = fmaf(ca.y, w2b, so[1]);
        so[2] = fmaf(ca.z, w2b, so[2]);
        so[3] = fmaf(ca.w, w2b, so[3]);
        so[4] = fmaf(cb.x, w2b, so[4]);
        so[5] = fmaf(cb.y, w2b, so[5]);
        so[6] = fmaf(cb.z, w2b, so[6]);
        so[7] = fmaf(cb.w, w2b, so[7]);
        ca = na; cb = nb; rln = rlnn;
      }
    } else if (wv <= 6) {
      // ---- MFMA history partials for S(t+1), software-pipelined over K-steps
      if (t < 15) {
        f32x4 acc0 = {}, acc1 = {};
        int s = wv - 1;
        if (s < t) {
          short8 a0h, a0l, a1h, a1l, bh, bl;
          {
            const int jb = 32 * s;
            const size_t ao0 = (size_t)(jend2 + fr) * 512 + jb + fg * 8;
            const size_t ao1 = ao0 + (size_t)16 * 512;
            a0h = *(const short8*)(D11h + ao0);
            a0l = *(const short8*)(D11l + ao0);
            a1h = *(const short8*)(D11h + ao1);
            a1l = *(const short8*)(D11l + ao1);
            bh = *(const short8*)&wth[fr][jb + fg * 8];
            bl = *(const short8*)&wtl[fr][jb + fg * 8];
          }
          for (;;) {
            const int sn = s + 6;
            short8 n0h, n0l, n1h, n1l, nbh, nbl;
            if (sn < t) {
              const int jb = 32 * sn;
              const size_t ao0 = (size_t)(jend2 + fr) * 512 + jb + fg * 8;
              const size_t ao1 = ao0 + (size_t)16 * 512;
              n0h = *(const short8*)(D11h + ao0);
              n0l = *(const short8*)(D11l + ao0);
              n1h = *(const short8*)(D11h + ao1);
              n1l = *(const short8*)(D11l + ao1);
              nbh = *(const short8*)&wth[fr][jb + fg * 8];
              nbl = *(const short8*)&wtl[fr][jb + fg * 8];
            }
            acc0 = __builtin_amdgcn_mfma_f32_16x16x32_bf16(a0h, bh, acc0, 0, 0, 0);
            acc0 = __builtin_amdgcn_mfma_f32_16x16x32_bf16(a0h, bl, acc0, 0, 0, 0);
            acc0 = __builtin_amdgcn_mfma_f32_16x16x32_bf16(a0l, bh, acc0, 0, 0, 0);
            acc1 = __builtin_amdgcn_mfma_f32_16x16x32_bf16(a1h, bh, acc1, 0, 0, 0);
            acc1 = __builtin_amdgcn_mfma_f32_16x16x32_bf16(a1h, bl, acc1, 0, 0, 0);
            acc1 = __builtin_amdgcn_mfma_f32_16x16x32_bf16(a1l, bh, acc1, 0, 0, 0);
            if (sn >= t) break;
            a0h = n0h; a0l = n0l; a1h = n1h; a1l = n1l; bh = nbh; bl = nbl;
            s = sn;
          }
        }
        // D layout: col = lane&15 (batch row r), row = fg*4+q (+16 for tile 1)
#pragma unroll
        for (int q = 0; q < 4; ++q) {
          shist[wv - 1][fg * 4 + q][fr] = acc0[q];
          shist[wv - 1][16 + fg * 4 + q][fr] = acc1[q];
        }
      }
    } else {
      // ---- wave 7: stage next-step operands
      if (t < 15) {
#pragma unroll
        for (int e = 0; e < 4; ++e) {
          int f = lane + 64 * e;
          int rr = f >> 3, cq = (f & 7) * 4;
          float4 v = *(const float4*)(D11 + (size_t)(jend2 + rr) * 512 + c0 + cq);
          doff[rr][cq + 0] = v.x; doff[rr][cq + 1] = v.y;
          doff[rr][cq + 2] = v.z; doff[rr][cq + 3] = v.w;
          float4 v2 = *(const float4*)(D11 + (size_t)(jend2 + rr) * 512 + jend2 + cq);
          dblkT[(t + 1) & 1][cq + 0][rr] = v2.x; dblkT[(t + 1) & 1][cq + 1][rr] = v2.y;
          dblkT[(t + 1) & 1][cq + 2][rr] = v2.z; dblkT[(t + 1) & 1][cq + 3][rr] = v2.w;
        }
#pragma unroll
        for (int e = 0; e < 2; ++e) {
          int f = lane + 64 * e;
          int rr = f >> 3, cq = (f & 7) * 4;
          float4 v = *(const float4*)(a + (size_t)(row0 + rr) * 512 + jend2 + cq);
          ablk[cq + 0][rr] = v.x; ablk[cq + 1][rr] = v.y;
          ablk[cq + 2][rr] = v.z; ablk[cq + 3][rr] = v.w;
        }
      }
    }
    __syncthreads();
    if (t < 15) {
      // ---- combine: S(t+1) = ablk + sum(shist) + doff * wcur
      const int il = tid >> 4, r2 = tid & 15;
      float s = ablk[il][r2];
#pragma unroll
      for (int k = 0; k < 6; ++k) s += shist[k][il][r2];
#pragma unroll 8
      for (int j = 0; j < 32; ++j)
        s = fmaf(doff[il][j], wcur[j][r2], s);
      sblk[il][r2] = s;
      __syncthreads();
    }
  }

  // write out w hi/lo (LDS -> global, uint-packed)
  const int k2 = tid & 255;
  const int rb = tid >> 8;
#pragma unroll
  for (int p = 0; p < 8; ++p) {
    int r = rb * 8 + p;
    size_t off = (size_t)(row0 + r) * 512 + 2 * k2;
    *(uint*)(wh + off) = *(const uint*)&wth[r][2 * k2];
    *(uint*)(wl + off) = *(const uint*)&wtl[r][2 * k2];
  }
}

// ---------------------------------------------------------------- launcher
extern "C" void kernel_launch(void* const* d_in, const int* in_sizes, int n_in,
                              void* d_out, int out_size, void* d_ws, size_t ws_size,
                              hipStream_t stream)
{
  const float* u   = (const float*)d_in[0];   // 8192 x 256
  const float* x0  = (const float*)d_in[1];   // 8192 x 512
  const float* X   = (const float*)d_in[2];   // 1536 x 1536
  const float* Y   = (const float*)d_in[3];   // 512 x 512
  const float* B2  = (const float*)d_in[4];   // 512 x 256
  const float* C2  = (const float*)d_in[5];   // 256 x 512
  const float* D21 = (const float*)d_in[6];   // 256 x 512
  const float* D22 = (const float*)d_in[7];   // 256 x 256
  const float* D12 = (const float*)d_in[8];   // 512 x 256
  float* out = (float*)d_out;
  float* ws = (float*)d_ws;

  float*  E    = ws + 0;
  float*  C1   = ws + 262144;
  float*  D11  = ws + 524288;
  ushort* D11h = (ushort*)(ws + 786432);
  ushort* D11l = (ushort*)(ws + 917504);
  float*  Lam  = ws + 1048576;
  int*    flag = (int*)(ws + 1049088);
  float*  Tf0  = ws + 1049600;
  float*  Tf1  = ws + 1311744;
  float*  Qf0  = ws + 1573888;
  float*  Qf1  = ws + 1704960;
  ushort* Th0  = (ushort*)(ws + 1836032);
  ushort* Tl0  = (ushort*)(ws + 1967104);
  ushort* Tth0 = (ushort*)(ws + 2098176);
  ushort* Ttl0 = (ushort*)(ws + 2229248);
  ushort* Th1  = (ushort*)(ws + 2360320);
  ushort* Tl1  = (ushort*)(ws + 2491392);
  ushort* Tth1 = (ushort*)(ws + 2622464);
  ushort* Ttl1 = (ushort*)(ws + 2753536);
  ushort* Qh0  = (ushort*)(ws + 2884608);
  ushort* Ql0  = (ushort*)(ws + 2950144);
  ushort* Qh1  = (ushort*)(ws + 3015680);
  ushort* Ql1  = (ushort*)(ws + 3081216);
  ushort* FmTh = (ushort*)(ws + 3146752);
  ushort* FmTl = (ushort*)(ws + 3277824);
  ushort* B1Th = (ushort*)(ws + 3408896);
  ushort* B1Tl = (ushort*)(ws + 3539968);
  ushort* B2Th = (ushort*)(ws + 3671040);
  ushort* B2Tl = (ushort*)(ws + 3736576);
  float*  P1   = ws + 3802112;
  ushort* P2h  = (ushort*)(ws + 3933184);
  ushort* P2l  = (ushort*)(ws + 3998720);
  ushort* P3h  = (ushort*)(ws + 4064256);
  ushort* P3l  = (ushort*)(ws + 4097024);
  ushort* D12h = (ushort*)(ws + 4129792);
  ushort* D12l = (ushort*)(ws + 4195328);
  ushort* uh   = (ushort*)(ws + 4260864);
  ushort* ul   = (ushort*)(ws + 5309440);
  float*  abuf = ws + 6358016;
  ushort* wh   = (ushort*)(ws + 10552320);
  ushort* wl   = (ushort*)(ws + 12649472);
  // Xt splits alias the wh/wl region (dead before k_scan writes wh/wl)
  ushort* Xth  = (ushort*)(ws + 10552320);
  ushort* Xtl  = (ushort*)(ws + 11731968);

  hipMemsetAsync(flag, 0, 4, stream);
  k_anynz<<<256, 256, 0, stream>>>(x0, 8192 * 512 / 4, flag);

  // transpose+split X -> Xt hi/lo; B2 -> B2T hi/lo; plain split u, D12
  k_tsplit<<<dim3(48, 48), 256, 0, stream>>>(X, Xth, Xtl, 1536, 1536);
  k_tsplit<<<dim3(8, 16), 256, 0, stream>>>(B2, B2Th, B2Tl, 512, 256);
  k_split2<<<2048, 256, 0, stream>>>(u, uh, ul, 524288, D12, D12h, D12l, 32768);

  // all 6 H-blocks via MFMA (E, C1, D11 fp32+h/l + Lam, FmT h/l, B1T h/l)
  k_xtxm<<<dim3(8, 8, 5), 256, 0, stream>>>(Xth, Xtl, Y, E, C1,
                                            D11, D11h, D11l, Lam,
                                            FmTh, FmTl, B1Th, B1Tl);

  // abuf = u @ D12^T (MFMA); + x0 @ C1^T if flag
  k_ntm<1><<<dim3(128, 8), 256, 0, stream>>>(uh, ul, D12h, D12l, 256,
                                             nullptr, nullptr, nullptr, nullptr, 0,
                                             abuf, 512);
  k_ntadd<<<dim3(128, 8), 256, 0, stream>>>(x0, C1, 512, flag, abuf, 512);

  // Newton-Schulz on (T, Q) via MFMA: 4 x {T,Q} + 1 final Q-only
  // (5 Q-updates total: rho^32 ~ 7e-5 ~ split-bf16 noise floor; iterating further is wasted)
  k_nsinit<<<384, 256, 0, stream>>>(E, C2, Tf0, Th0, Tl0, Tth0, Ttl0, Qf0, Qh0, Ql0);
  ushort *Tha[2] = {Th0, Th1}, *Tla[2] = {Tl0, Tl1};
  ushort *Ttha[2] = {Tth0, Tth1}, *Ttla[2] = {Ttl0, Ttl1};
  ushort *Qha[2] = {Qh0, Qh1}, *Qla[2] = {Ql0, Ql1};
  float *Tfa[2] = {Tf0, Tf1}, *Qfa[2] = {Qf0, Qf1};
  int cur = 0;
  for (int it = 0; it < 4; ++it) {
    int nxt = cur ^ 1;
    k_nsm<true><<<dim3(8, 12), 256, 0, stream>>>(
        Tha[cur], Tla[cur], Ttha[cur], Ttla[cur], Qha[cur], Qla[cur],
        Tfa[cur], Qfa[cur],
        Tfa[nxt], Tha[nxt], Tla[nxt], Ttha[nxt], Ttla[nxt],
        Qfa[nxt], Qha[nxt], Qla[nxt]);
    cur = nxt;
  }
  int nxt = cur ^ 1;
  k_nsm<false><<<dim3(8, 4), 256, 0, stream>>>(
      Tha[cur], Tla[cur], Ttha[cur], Ttla[cur], Qha[cur], Qla[cur],
      Tfa[cur], Qfa[cur],
      Tfa[nxt], Tha[nxt], Tla[nxt], Ttha[nxt], Ttla[nxt],
      Qfa[nxt], Qha[nxt], Qla[nxt]);
  ushort* Qh = Qha[nxt];
  ushort* Ql = Qla[nxt];

  // folds: P1 fp32, P2/P3 hi/lo (MFMA)
  k_foldm<<<dim3(8, 4, 3), 256, 0, stream>>>(Qh, Ql, FmTh, FmTl, B1Th, B1Tl,
                                             B2Th, B2Tl, D21, D22,
                                             P1, P2h, P2l, P3h, P3l);

  // scan -> w (bf16 hi/lo), history via MFMA
  k_scan<<<512, 512, 0, stream>>>(abuf, D11, D11h, D11l, Lam, wh, wl);

  // y = w @ P2^T + u @ P3^T (MFMA); + x0 @ P1^T if flag
  k_ntm<2><<<dim3(128, 4), 256, 0, stream>>>(wh, wl, P2h, P2l, 512,
                                             uh, ul, P3h, P3l, 256,
                                             out, 256);
  k_ntadd<<<dim3(128, 4), 256, 0, stream>>>(x0, P1, 512, flag, out, 256);
}